// Round 7
// baseline (922.871 us; speedup 1.0000x reference)
//
#include <hip/hip_runtime.h>
#include <math.h>

#define HEADS 8
#define HC 256
#define NREL 3
#define NEG 0.2f
#define MAXDEG 128   // max in-degree; E=160k over N=10k dst -> mean 16, max ~45. 128 is hugely safe.
#define PCHUNK 8     // chunk-blocks per graph in the pool kernel

typedef float vfloat4 __attribute__((ext_vector_type(4)));  // native vec for nontemporal builtins

__device__ __forceinline__ float warp32_reduce(float p) {
#pragma unroll
    for (int off = 16; off > 0; off >>= 1) p += __shfl_down(p, off, 32);
    return p;
}

// ---- CSR build -------------------------------------------------------------

__global__ void k_init(int* deg, int* fill, int nnodes) {
    int i = blockIdx.x * blockDim.x + threadIdx.x;
    if (i < nnodes) { deg[i] = 0; fill[i] = 0; }
}

__global__ void k_deg(const int* __restrict__ ei, int* deg, int nedges) {
    int e = blockIdx.x * blockDim.x + threadIdx.x;
    if (e < nedges) atomicAdd(&deg[ei[nedges + e]], 1);
}

// single-block exclusive scan over nnodes degrees -> rowptr[n+1]
__global__ void k_scan(const int* __restrict__ deg, int* rowptr, int n) {
    __shared__ int ss[1024];
    int tid = threadIdx.x;
    int per = (n + 1023) >> 10;
    int b = tid * per;
    int s = 0;
    for (int i = 0; i < per; i++) { int idx = b + i; if (idx < n) s += deg[idx]; }
    ss[tid] = s;
    __syncthreads();
    for (int off = 1; off < 1024; off <<= 1) {
        int v = (tid >= off) ? ss[tid - off] : 0;
        __syncthreads();
        ss[tid] += v;
        __syncthreads();
    }
    int run = (tid == 0) ? 0 : ss[tid - 1];
    for (int i = 0; i < per; i++) {
        int idx = b + i;
        if (idx < n) { rowptr[idx] = run; run += deg[idx]; }
    }
    if (tid == 0) rowptr[n] = ss[1023];
}

__global__ void k_scatter(const int* __restrict__ ei, const int* __restrict__ et,
                          const float* __restrict__ ea, const int* __restrict__ rowptr,
                          int* fill, int* csr_pack, float* csr_ae, int nedges) {
    int e = blockIdx.x * blockDim.x + threadIdx.x;
    if (e >= nedges) return;
    int dst = ei[nedges + e];
    int pos = atomicAdd(&fill[dst], 1);
    int slot = rowptr[dst] + pos;
    csr_pack[slot] = (ei[e] << 2) | (et[e] & 3);
    csr_ae[slot] = ea[e];
}

// ---- per-layer small precompute --------------------------------------------
// wqk[i][r*8+h]      = w[r,i,:] @ q[:,h]   (cols 0..23)
// wqk[i][24+r*8+h]   = w[r,i,:] @ k[:,h]   (cols 24..47)
// wee[h]             = we @ e[:,h]
__global__ void k_prep(const float* __restrict__ w, const float* __restrict__ q,
                       const float* __restrict__ kk, const float* __restrict__ e,
                       const float* __restrict__ we, float* wqk, float* wee, int IN) {
    int tid = threadIdx.x;
    int ri = blockIdx.x;  // r*IN + i
    int r = ri / IN, i = ri % IN;
    int h = tid >> 5, lane = tid & 31;
    const float* wrow = w + (size_t)ri * HC;
    float p = 0.f;
    for (int o = lane; o < HC; o += 32) p += wrow[o] * q[o * HEADS + h];
    p = warp32_reduce(p);
    if (lane == 0) wqk[i * 48 + r * 8 + h] = p;
    p = 0.f;
    for (int o = lane; o < HC; o += 32) p += wrow[o] * kk[o * HEADS + h];
    p = warp32_reduce(p);
    if (lane == 0) wqk[i * 48 + 24 + r * 8 + h] = p;
    if (blockIdx.x == 0 && tid < HEADS) {
        float s = 0.f;
        for (int o = 0; o < HC; o++) s += we[o] * e[o * HEADS + tid];
        wee[tid] = s;
    }
}

// ---- skinny GEMM for qdot/kdot: [nnodes x K] @ [K x 48] --------------------
// BM=64 (157 blocks), register double-buffered staging.
template <int K>
__global__ __launch_bounds__(256) void k_qk(const float* __restrict__ xin,
                                            const float* __restrict__ wqk,
                                            float* __restrict__ qdot,
                                            float* __restrict__ kdot, int nnodes) {
    constexpr int BM = 64, BK = 32;
    __shared__ float xs[BK][BM];   // transposed x tile
    __shared__ float wt[BK][48];
    int n0 = blockIdx.x * BM;
    int t = threadIdx.x;
    int tx = t & 15, ty = t >> 4;
    int m0 = ty * 4, c0 = tx * 3;
    float acc[4][3] = {};

    int sm = t & 63;           // x row within tile
    int sf = t >> 6;           // x float4-chunk base (0..3); second chunk sf+4
    int gn = n0 + sm;
    bool xok = gn < nnodes;
    const float* xbase = xin + (size_t)gn * K;

    float4 px[2];
    float pq[6];
    auto load_x = [&](int k0) {
#pragma unroll
        for (int j = 0; j < 2; ++j) {
            int fc = sf + 4 * j;
            px[j] = xok ? *(const float4*)(xbase + k0 + 4 * fc)
                        : make_float4(0.f, 0.f, 0.f, 0.f);
        }
    };
    auto load_q = [&](int k0) {
#pragma unroll
        for (int i = 0; i < 6; ++i) {
            int idx = t + 256 * i;
            int kk = idx / 48, c = idx - kk * 48;
            pq[i] = wqk[(size_t)(k0 + kk) * 48 + c];
        }
    };
    auto stage = [&]() {
#pragma unroll
        for (int j = 0; j < 2; ++j) {
            int fc = sf + 4 * j;
            xs[4 * fc + 0][sm] = px[j].x;
            xs[4 * fc + 1][sm] = px[j].y;
            xs[4 * fc + 2][sm] = px[j].z;
            xs[4 * fc + 3][sm] = px[j].w;
        }
#pragma unroll
        for (int i = 0; i < 6; ++i) {
            int idx = t + 256 * i;
            int kk = idx / 48, c = idx - kk * 48;
            wt[kk][c] = pq[i];
        }
    };

    load_x(0); load_q(0);
    for (int k0 = 0; k0 < K; k0 += BK) {
        stage();
        __syncthreads();
        if (k0 + BK < K) { load_x(k0 + BK); load_q(k0 + BK); }
#pragma unroll
        for (int kk = 0; kk < BK; ++kk) {
            float b0 = wt[kk][c0], b1 = wt[kk][c0 + 1], b2 = wt[kk][c0 + 2];
            float4 a0 = *(const float4*)&xs[kk][m0];
            float am[4] = {a0.x, a0.y, a0.z, a0.w};
#pragma unroll
            for (int i = 0; i < 4; i++) {
                acc[i][0] += am[i] * b0;
                acc[i][1] += am[i] * b1;
                acc[i][2] += am[i] * b2;
            }
        }
        __syncthreads();
    }
#pragma unroll
    for (int i = 0; i < 4; ++i) {
        int n = n0 + m0 + i;
        if (n < nnodes) {
#pragma unroll
            for (int j = 0; j < 3; ++j) {
                int c = c0 + j;
                if (c < 24) qdot[n * 24 + c] = acc[i][j];
                else        kdot[n * 24 + (c - 24)] = acc[i][j];
            }
        }
    }
}

// ---- tiled fp32 GEMM: xw[n,r,:] = x[n,:] @ w[r]  -------------------------
// BM=64 x BN=128, BK=32 (948 blocks -> ~3.7/CU), register double-buffered
// staging so next tile's global loads drain behind the MAC loop. XCD swizzle:
// all 6 (c-half, rel) blocks of a row-tile share id%8 -> same XCD L2.
template <int K>
__global__ __launch_bounds__(256, 4) void k_gemm(const float* __restrict__ xin,
                                                 const float* __restrict__ w,
                                                 float* __restrict__ xw,
                                                 int nnodes, int nrowt) {
    constexpr int BM = 64, BN = 128, BK = 32;
    __shared__ float xs[BK][BM];   // transposed x tile: xs[k][m]
    __shared__ float wt[BK][BN];   // w tile: wt[k][c]
    int id = blockIdx.x;
    int hi = id / 48;
    int rem = id - hi * 48;
    int cr = rem >> 3;                 // 0..5 = (r<<1)|chalf
    int rowt = hi * 8 + (rem & 7);
    if (rowt >= nrowt) return;
    int r = cr >> 1;
    int c1 = (cr & 1) * BN;
    int n0 = rowt * BM;
    int t = threadIdx.x;
    int tx = t & 15, ty = t >> 4;
    int m0 = ty * 4;
    int c0a = tx * 4, c0b = 64 + tx * 4;
    float acc[4][8] = {};
    const float* wr = w + (size_t)r * K * HC;

    int sm = t & 63;           // x row within tile
    int sf = t >> 6;           // x float4-chunk base (0..3); second chunk sf+4
    int gn = n0 + sm;
    bool xok = gn < nnodes;
    const float* xbase = xin + (size_t)gn * K;

    float4 px[2], pw[4];
    auto load_x = [&](int k0) {
#pragma unroll
        for (int j = 0; j < 2; ++j) {
            int fc = sf + 4 * j;
            px[j] = xok ? *(const float4*)(xbase + k0 + 4 * fc)
                        : make_float4(0.f, 0.f, 0.f, 0.f);
        }
    };
    auto load_w = [&](int k0) {
#pragma unroll
        for (int it = 0; it < 4; ++it) {
            int fidx = t + 256 * it;
            int kk = fidx >> 5;
            int c4 = (fidx & 31) << 2;
            pw[it] = *(const float4*)(wr + (size_t)(k0 + kk) * HC + c1 + c4);
        }
    };
    auto stage = [&]() {
#pragma unroll
        for (int j = 0; j < 2; ++j) {
            int fc = sf + 4 * j;
            xs[4 * fc + 0][sm] = px[j].x;
            xs[4 * fc + 1][sm] = px[j].y;
            xs[4 * fc + 2][sm] = px[j].z;
            xs[4 * fc + 3][sm] = px[j].w;
        }
#pragma unroll
        for (int it = 0; it < 4; ++it) {
            int fidx = t + 256 * it;
            int kk = fidx >> 5;
            int c4 = (fidx & 31) << 2;
            *(float4*)&wt[kk][c4] = pw[it];
        }
    };

    load_x(0); load_w(0);
    for (int k0 = 0; k0 < K; k0 += BK) {
        stage();
        __syncthreads();
        if (k0 + BK < K) { load_x(k0 + BK); load_w(k0 + BK); }
#pragma unroll
        for (int kk = 0; kk < BK; ++kk) {
            float4 a0 = *(const float4*)&xs[kk][m0];
            float4 b0 = *(const float4*)&wt[kk][c0a];
            float4 b1 = *(const float4*)&wt[kk][c0b];
            float am[4] = {a0.x, a0.y, a0.z, a0.w};
            float bn[8] = {b0.x, b0.y, b0.z, b0.w, b1.x, b1.y, b1.z, b1.w};
#pragma unroll
            for (int i = 0; i < 4; i++)
#pragma unroll
                for (int j = 0; j < 8; j++) acc[i][j] += am[i] * bn[j];
        }
        __syncthreads();
    }
#pragma unroll
    for (int i = 0; i < 4; ++i) {
        int n = n0 + m0 + i;
        if (n < nnodes) {
            float* base = xw + ((size_t)n * NREL + r) * HC + c1;
            vfloat4 v0 = {acc[i][0], acc[i][1], acc[i][2], acc[i][3]};
            vfloat4 v1 = {acc[i][4], acc[i][5], acc[i][6], acc[i][7]};
            __builtin_nontemporal_store(v0, (vfloat4*)(base + c0a));
            __builtin_nontemporal_store(v1, (vfloat4*)(base + c0b));
        }
    }
}

// ---- per-dst-node attention softmax + aggregation + bias + relu ----
__global__ void k_agg(const float* __restrict__ xw, const float* __restrict__ qdot,
                      const float* __restrict__ kdot, const int* __restrict__ rowptr,
                      const int* __restrict__ csr_pack, const float* __restrict__ csr_ae,
                      const float* __restrict__ wee, const float* __restrict__ bias,
                      float* __restrict__ hout, int nnodes) {
    __shared__ float salpha[MAXDEG * HEADS];
    __shared__ int spack[MAXDEG];
    __shared__ float sqd[NREL * HEADS];
    __shared__ float sinv[HEADS];
    __shared__ float swee[HEADS];
    int n = blockIdx.x;
    int tid = threadIdx.x;
    int beg = rowptr[n];
    int deg = rowptr[n + 1] - beg;
    if (deg > MAXDEG) deg = MAXDEG;
    if (tid < NREL * HEADS) sqd[tid] = qdot[n * 24 + tid];
    if (tid < HEADS) swee[tid] = wee[tid];
    __syncthreads();
    for (int base = 0; base < deg; base += 32) {
        int d = base + (tid >> 3);
        int h = tid & 7;
        if (d < deg) {
            int pk = csr_pack[beg + d];
            float ae = csr_ae[beg + d];
            int s = pk >> 2, t = pk & 3;
            if (h == 0) spack[d] = pk;
            float a = sqd[t * 8 + h] + kdot[s * 24 + t * 8 + h] + ae * swee[h];
            salpha[d * 8 + h] = (a > 0.f) ? a : NEG * a;
        }
    }
    __syncthreads();
    if (tid < HEADS) {
        int h = tid;
        float m = -INFINITY;
        for (int d = 0; d < deg; d++) m = fmaxf(m, salpha[d * 8 + h]);
        float s = 0.f;
        for (int d = 0; d < deg; d++) {
            float ex = expf(salpha[d * 8 + h] - m);
            salpha[d * 8 + h] = ex;
            s += ex;
        }
        sinv[h] = 1.f / (s + 1e-16f);
    }
    __syncthreads();
    int h = tid >> 5;
    float acc = 0.f;
    for (int d = 0; d < deg; ++d) {
        int pk = spack[d];
        int s = pk >> 2, t = pk & 3;
        acc += salpha[d * 8 + h] * xw[((size_t)s * NREL + t) * HC + tid];
    }
    acc *= sinv[h];
    float v = acc + bias[tid];
    hout[(size_t)n * HC + tid] = (v > 0.f) ? v : 0.f;
}

// ---- final linear + tanh + mean-pool (atomic-free) -------------------------
__global__ __launch_bounds__(256) void k_pool2(const float* __restrict__ h3,
                                               const float* __restrict__ wlin,
                                               const float* __restrict__ blin,
                                               const int* __restrict__ batch,
                                               float* __restrict__ partials,
                                               int* __restrict__ gcnt, int nnodes) {
    int g = blockIdx.x / PCHUNK, chunk = blockIdx.x % PCHUNK;
    __shared__ int sb[2];
    if (threadIdx.x < 2) {
        int target = g + threadIdx.x;
        int lo = 0, hi = nnodes;
        while (lo < hi) { int mid = (lo + hi) >> 1; if (batch[mid] < target) lo = mid + 1; else hi = mid; }
        sb[threadIdx.x] = lo;
    }
    __syncthreads();
    int beg = sb[0], end = sb[1];
    int t = threadIdx.x;
    int w = t >> 6, lane = t & 63;
    int h = lane & 7, grp = lane >> 3;
    float rw[32];
#pragma unroll
    for (int k = 0; k < 8; ++k)
#pragma unroll
        for (int j = 0; j < 4; ++j)
            rw[k * 4 + j] = wlin[(grp * 4 + j + 32 * k) * HEADS + h];
    float bl = blin[h];
    float acc = 0.f;
    int wg = chunk * 4 + w;   // 0..31
    for (int n = beg + wg; n < end; n += PCHUNK * 4) {
        const float* row = h3 + (size_t)n * HC;
        float dot = 0.f;
#pragma unroll
        for (int k = 0; k < 8; ++k) {
            float4 v = *(const float4*)&row[grp * 4 + 32 * k];
            dot += v.x * rw[k * 4] + v.y * rw[k * 4 + 1] + v.z * rw[k * 4 + 2] + v.w * rw[k * 4 + 3];
        }
        dot += __shfl_xor(dot, 8, 64);
        dot += __shfl_xor(dot, 16, 64);
        dot += __shfl_xor(dot, 32, 64);
        acc += tanhf(dot + bl);
    }
    __shared__ float sacc[4][HEADS];
    if (lane < HEADS) sacc[w][h] = acc;
    __syncthreads();
    if (t < HEADS) {
        float s = sacc[0][t] + sacc[1][t] + sacc[2][t] + sacc[3][t];
        partials[(size_t)blockIdx.x * HEADS + t] = s;
    }
    if (t == 0 && chunk == 0) gcnt[g] = end - beg;
}

__global__ void k_div(const float* __restrict__ partials, const int* __restrict__ gcnt,
                      float* __restrict__ out, int ngraph) {
    int t = threadIdx.x;
    if (t < ngraph * HEADS) {
        int g = t >> 3, h = t & 7;
        float s = 0.f;
        for (int c = 0; c < PCHUNK; ++c) s += partials[(size_t)(g * PCHUNK + c) * HEADS + h];
        out[t] = s / fmaxf((float)gcnt[g], 1.f);
    }
}

// ---------------------------------------------------------------------------

extern "C" void kernel_launch(void* const* d_in, const int* in_sizes, int n_in,
                              void* d_out, int out_size, void* d_ws, size_t ws_size,
                              hipStream_t stream) {
    const float* x    = (const float*)d_in[0];
    const int*   ei   = (const int*)d_in[1];
    const int*   et   = (const int*)d_in[2];
    const float* ea   = (const float*)d_in[3];
    const int*   batch = (const int*)d_in[4];
    const float* W[3]  = {(const float*)d_in[5],  (const float*)d_in[11], (const float*)d_in[17]};
    const float* Q[3]  = {(const float*)d_in[6],  (const float*)d_in[12], (const float*)d_in[18]};
    const float* K[3]  = {(const float*)d_in[7],  (const float*)d_in[13], (const float*)d_in[19]};
    const float* Em[3] = {(const float*)d_in[8],  (const float*)d_in[14], (const float*)d_in[20]};
    const float* WE[3] = {(const float*)d_in[9],  (const float*)d_in[15], (const float*)d_in[21]};
    const float* B[3]  = {(const float*)d_in[10], (const float*)d_in[16], (const float*)d_in[22]};
    const float* wlin = (const float*)d_in[23];
    const float* blin = (const float*)d_in[24];

    int nnodes = in_sizes[0] / 32;
    int nedges = in_sizes[2];
    int ngraph = 16;

    char* ws = (char*)d_ws;
    size_t off = 0;
    auto alloc = [&](size_t bytes) -> void* {
        void* p = ws + off;
        off = (off + bytes + 255) & ~(size_t)255;
        return p;
    };
    int*   deg      = (int*)alloc((size_t)nnodes * 4);
    int*   fill     = (int*)alloc((size_t)nnodes * 4);
    int*   rowptr   = (int*)alloc((size_t)(nnodes + 1) * 4);
    int*   csr_pack = (int*)alloc((size_t)nedges * 4);
    float* csr_ae   = (float*)alloc((size_t)nedges * 4);
    float* xw       = (float*)alloc((size_t)nnodes * NREL * HC * 4);
    float* qdot     = (float*)alloc((size_t)nnodes * NREL * HEADS * 4);
    float* kdot     = (float*)alloc((size_t)nnodes * NREL * HEADS * 4);
    float* ha       = (float*)alloc((size_t)nnodes * HC * 4);
    float* hb       = (float*)alloc((size_t)nnodes * HC * 4);
    float* wqk      = (float*)alloc((size_t)HC * 48 * 4);
    float* wee      = (float*)alloc((size_t)HEADS * 4);
    float* partials = (float*)alloc((size_t)ngraph * PCHUNK * HEADS * 4);
    int*   gcnt     = (int*)alloc((size_t)ngraph * 4);
    (void)ws_size; (void)n_in; (void)out_size;

    // CSR build (edges are fixed across layers)
    k_init<<<(nnodes + 255) / 256, 256, 0, stream>>>(deg, fill, nnodes);
    k_deg<<<(nedges + 255) / 256, 256, 0, stream>>>(ei, deg, nedges);
    k_scan<<<1, 1024, 0, stream>>>(deg, rowptr, nnodes);
    k_scatter<<<(nedges + 255) / 256, 256, 0, stream>>>(ei, et, ea, rowptr, fill, csr_pack, csr_ae, nedges);

    int nrowt = (nnodes + 63) / 64;          // BM=64 row tiles
    int ggemm = ((nrowt + 7) / 8) * 48;      // XCD-swizzled 1-D grid
    int gqk = nrowt;

    // ---- layer 1 (IN=32): x -> ha ----
    k_prep<<<NREL * 32, 256, 0, stream>>>(W[0], Q[0], K[0], Em[0], WE[0], wqk, wee, 32);
    k_qk<32><<<gqk, 256, 0, stream>>>(x, wqk, qdot, kdot, nnodes);
    k_gemm<32><<<ggemm, 256, 0, stream>>>(x, W[0], xw, nnodes, nrowt);
    k_agg<<<nnodes, 256, 0, stream>>>(xw, qdot, kdot, rowptr, csr_pack, csr_ae, wee, B[0], ha, nnodes);

    // ---- layer 2 (IN=256): ha -> hb ----
    k_prep<<<NREL * HC, 256, 0, stream>>>(W[1], Q[1], K[1], Em[1], WE[1], wqk, wee, HC);
    k_qk<HC><<<gqk, 256, 0, stream>>>(ha, wqk, qdot, kdot, nnodes);
    k_gemm<HC><<<ggemm, 256, 0, stream>>>(ha, W[1], xw, nnodes, nrowt);
    k_agg<<<nnodes, 256, 0, stream>>>(xw, qdot, kdot, rowptr, csr_pack, csr_ae, wee, B[1], hb, nnodes);

    // ---- layer 3 (IN=256): hb -> ha ----
    k_prep<<<NREL * HC, 256, 0, stream>>>(W[2], Q[2], K[2], Em[2], WE[2], wqk, wee, HC);
    k_qk<HC><<<gqk, 256, 0, stream>>>(hb, wqk, qdot, kdot, nnodes);
    k_gemm<HC><<<ggemm, 256, 0, stream>>>(hb, W[2], xw, nnodes, nrowt);
    k_agg<<<nnodes, 256, 0, stream>>>(xw, qdot, kdot, rowptr, csr_pack, csr_ae, wee, B[2], ha, nnodes);

    // ---- head: linear + tanh + mean pool (atomic-free) ----
    k_pool2<<<ngraph * PCHUNK, 256, 0, stream>>>(ha, wlin, blin, batch, partials, gcnt, nnodes);
    k_div<<<1, 128, 0, stream>>>(partials, gcnt, (float*)d_out, ngraph);
}

// Round 8
// 752.540 us; speedup vs baseline: 1.2263x; 1.2263x over previous
//
#include <hip/hip_runtime.h>
#include <math.h>

#define HEADS 8
#define HC 256
#define NREL 3
#define NEG 0.2f
#define MAXDEG 128   // max in-degree; E=160k over N=10k dst -> mean 16, max ~45. 128 is hugely safe.
#define PCHUNK 8     // chunk-blocks per graph in the pool kernel

typedef float vfloat4 __attribute__((ext_vector_type(4)));  // native vec for nontemporal builtins

__device__ __forceinline__ float warp32_reduce(float p) {
#pragma unroll
    for (int off = 16; off > 0; off >>= 1) p += __shfl_down(p, off, 32);
    return p;
}

// ---- CSR build -------------------------------------------------------------

__global__ void k_init(int* deg, int* fill, int nnodes) {
    int i = blockIdx.x * blockDim.x + threadIdx.x;
    if (i < nnodes) { deg[i] = 0; fill[i] = 0; }
}

__global__ void k_deg(const int* __restrict__ ei, int* deg, int nedges) {
    int e = blockIdx.x * blockDim.x + threadIdx.x;
    if (e < nedges) atomicAdd(&deg[ei[nedges + e]], 1);
}

// single-block exclusive scan over nnodes degrees -> rowptr[n+1]
__global__ void k_scan(const int* __restrict__ deg, int* rowptr, int n) {
    __shared__ int ss[1024];
    int tid = threadIdx.x;
    int per = (n + 1023) >> 10;
    int b = tid * per;
    int s = 0;
    for (int i = 0; i < per; i++) { int idx = b + i; if (idx < n) s += deg[idx]; }
    ss[tid] = s;
    __syncthreads();
    for (int off = 1; off < 1024; off <<= 1) {
        int v = (tid >= off) ? ss[tid - off] : 0;
        __syncthreads();
        ss[tid] += v;
        __syncthreads();
    }
    int run = (tid == 0) ? 0 : ss[tid - 1];
    for (int i = 0; i < per; i++) {
        int idx = b + i;
        if (idx < n) { rowptr[idx] = run; run += deg[idx]; }
    }
    if (tid == 0) rowptr[n] = ss[1023];
}

__global__ void k_scatter(const int* __restrict__ ei, const int* __restrict__ et,
                          const float* __restrict__ ea, const int* __restrict__ rowptr,
                          int* fill, int* csr_pack, float* csr_ae, int nedges) {
    int e = blockIdx.x * blockDim.x + threadIdx.x;
    if (e >= nedges) return;
    int dst = ei[nedges + e];
    int pos = atomicAdd(&fill[dst], 1);
    int slot = rowptr[dst] + pos;
    csr_pack[slot] = (ei[e] << 2) | (et[e] & 3);
    csr_ae[slot] = ea[e];
}

// ---- per-layer small precompute --------------------------------------------
// wqk[i][r*8+h]      = w[r,i,:] @ q[:,h]   (cols 0..23)
// wqk[i][24+r*8+h]   = w[r,i,:] @ k[:,h]   (cols 24..47)
// wee[h]             = we @ e[:,h]
__global__ void k_prep(const float* __restrict__ w, const float* __restrict__ q,
                       const float* __restrict__ kk, const float* __restrict__ e,
                       const float* __restrict__ we, float* wqk, float* wee, int IN) {
    int tid = threadIdx.x;
    int ri = blockIdx.x;  // r*IN + i
    int r = ri / IN, i = ri % IN;
    int h = tid >> 5, lane = tid & 31;
    const float* wrow = w + (size_t)ri * HC;
    float p = 0.f;
    for (int o = lane; o < HC; o += 32) p += wrow[o] * q[o * HEADS + h];
    p = warp32_reduce(p);
    if (lane == 0) wqk[i * 48 + r * 8 + h] = p;
    p = 0.f;
    for (int o = lane; o < HC; o += 32) p += wrow[o] * kk[o * HEADS + h];
    p = warp32_reduce(p);
    if (lane == 0) wqk[i * 48 + 24 + r * 8 + h] = p;
    if (blockIdx.x == 0 && tid < HEADS) {
        float s = 0.f;
        for (int o = 0; o < HC; o++) s += we[o] * e[o * HEADS + tid];
        wee[tid] = s;
    }
}

// ---- skinny GEMM for qdot/kdot: [nnodes x K] @ [K x 48] --------------------
template <int K>
__global__ __launch_bounds__(256) void k_qk(const float* __restrict__ xin,
                                            const float* __restrict__ wqk,
                                            float* __restrict__ qdot,
                                            float* __restrict__ kdot, int nnodes) {
    constexpr int BM = 128, BK = 32;
    __shared__ float xs[BK][BM];   // transposed x tile
    __shared__ float wt[BK][48];
    int n0 = blockIdx.x * BM;
    int t = threadIdx.x;
    int tx = t & 15, ty = t >> 4;
    int m0 = ty * 8, c0 = tx * 3;
    float acc[8][3];
#pragma unroll
    for (int i = 0; i < 8; i++)
#pragma unroll
        for (int j = 0; j < 3; j++) acc[i][j] = 0.f;
    int sm = t >> 1;
    int skq = (t & 1) * 16;
    for (int k0 = 0; k0 < K; k0 += BK) {
        int gn = n0 + sm;
        const float* xrow = xin + (size_t)gn * K + k0 + skq;
#pragma unroll
        for (int j = 0; j < 4; ++j) {
            float4 v = (gn < nnodes) ? *(const float4*)(xrow + 4 * j)
                                     : make_float4(0.f, 0.f, 0.f, 0.f);
            xs[skq + 4 * j + 0][sm] = v.x;
            xs[skq + 4 * j + 1][sm] = v.y;
            xs[skq + 4 * j + 2][sm] = v.z;
            xs[skq + 4 * j + 3][sm] = v.w;
        }
        for (int idx = t; idx < BK * 48; idx += 256) {
            int kk = idx / 48, c = idx % 48;
            wt[kk][c] = wqk[(size_t)(k0 + kk) * 48 + c];
        }
        __syncthreads();
#pragma unroll
        for (int kk = 0; kk < BK; ++kk) {
            float b0 = wt[kk][c0], b1 = wt[kk][c0 + 1], b2 = wt[kk][c0 + 2];
            float4 a0 = *(const float4*)&xs[kk][m0];
            float4 a1 = *(const float4*)&xs[kk][m0 + 4];
            float am[8] = {a0.x, a0.y, a0.z, a0.w, a1.x, a1.y, a1.z, a1.w};
#pragma unroll
            for (int i = 0; i < 8; i++) {
                acc[i][0] += am[i] * b0;
                acc[i][1] += am[i] * b1;
                acc[i][2] += am[i] * b2;
            }
        }
        __syncthreads();
    }
#pragma unroll
    for (int i = 0; i < 8; ++i) {
        int n = n0 + m0 + i;
        if (n < nnodes) {
#pragma unroll
            for (int j = 0; j < 3; ++j) {
                int c = c0 + j;
                if (c < 24) qdot[n * 24 + c] = acc[i][j];
                else        kdot[n * 24 + (c - 24)] = acc[i][j];
            }
        }
    }
}

// ---- tiled fp32 GEMM: xw[n,r,:] = x[n,:] @ w[r]  -------------------------
// 128x128x32 tile (round-5 config) + register double-buffered staging:
// next K-tile's global loads issue right after the barrier and drain during
// the ~4096-cycle MAC loop. __launch_bounds__(256,2) -> up to 256 VGPRs, no
// spill (acc 64 + px 16 + pw 16 + addr ~= 115). XCD swizzle: all 6
// (c-half, rel) blocks of a row-tile share id%8 -> same XCD L2.
template <int K>
__global__ __launch_bounds__(256, 2) void k_gemm(const float* __restrict__ xin,
                                                 const float* __restrict__ w,
                                                 float* __restrict__ xw,
                                                 int nnodes, int nrowt) {
    constexpr int BM = 128, BN = 128, BK = 32;
    __shared__ float xs[BK][BM];   // transposed x tile: xs[k][m]
    __shared__ float wt[BK][BN];   // w tile: wt[k][c]
    int id = blockIdx.x;
    int hi = id / 48;
    int rem = id - hi * 48;
    int cr = rem >> 3;                 // 0..5 = (r<<1)|chalf
    int rowt = hi * 8 + (rem & 7);
    if (rowt >= nrowt) return;
    int r = cr >> 1;
    int c1 = (cr & 1) * BN;
    int n0 = rowt * BM;
    int t = threadIdx.x;
    int tx = t & 15, ty = t >> 4;
    int m0 = ty * 8;
    int c0a = tx * 4, c0b = 64 + tx * 4;
    float acc[8][8];
#pragma unroll
    for (int i = 0; i < 8; i++)
#pragma unroll
        for (int j = 0; j < 8; j++) acc[i][j] = 0.f;
    const float* wr = w + (size_t)r * K * HC;

    int sm = t >> 1;              // x staging: node within tile (2 thr/row)
    int skq = (t & 1) * 16;       // x staging: k offset (16 floats)
    int gn = n0 + sm;
    bool xok = gn < nnodes;
    const float* xbase = xin + (size_t)gn * K + skq;

    float4 px[4], pw[4];
    auto load_x = [&](int k0) {
#pragma unroll
        for (int j = 0; j < 4; ++j)
            px[j] = xok ? *(const float4*)(xbase + k0 + 4 * j)
                        : make_float4(0.f, 0.f, 0.f, 0.f);
    };
    auto load_w = [&](int k0) {
#pragma unroll
        for (int it = 0; it < 4; ++it) {
            int fidx = t + 256 * it;
            int kk = fidx >> 5;
            int c4 = (fidx & 31) << 2;
            pw[it] = *(const float4*)(wr + (size_t)(k0 + kk) * HC + c1 + c4);
        }
    };
    auto stage = [&]() {
#pragma unroll
        for (int j = 0; j < 4; ++j) {
            xs[skq + 4 * j + 0][sm] = px[j].x;
            xs[skq + 4 * j + 1][sm] = px[j].y;
            xs[skq + 4 * j + 2][sm] = px[j].z;
            xs[skq + 4 * j + 3][sm] = px[j].w;
        }
#pragma unroll
        for (int it = 0; it < 4; ++it) {
            int fidx = t + 256 * it;
            int kk = fidx >> 5;
            int c4 = (fidx & 31) << 2;
            *(float4*)&wt[kk][c4] = pw[it];
        }
    };

    load_x(0); load_w(0);
    for (int k0 = 0; k0 < K; k0 += BK) {
        stage();
        __syncthreads();
        if (k0 + BK < K) { load_x(k0 + BK); load_w(k0 + BK); }
#pragma unroll
        for (int kk = 0; kk < BK; ++kk) {
            float4 a0 = *(const float4*)&xs[kk][m0];
            float4 a1 = *(const float4*)&xs[kk][m0 + 4];
            float4 b0 = *(const float4*)&wt[kk][c0a];
            float4 b1 = *(const float4*)&wt[kk][c0b];
            float am[8] = {a0.x, a0.y, a0.z, a0.w, a1.x, a1.y, a1.z, a1.w};
            float bn[8] = {b0.x, b0.y, b0.z, b0.w, b1.x, b1.y, b1.z, b1.w};
#pragma unroll
            for (int i = 0; i < 8; i++)
#pragma unroll
                for (int j = 0; j < 8; j++) acc[i][j] += am[i] * bn[j];
        }
        __syncthreads();
    }
#pragma unroll
    for (int i = 0; i < 8; ++i) {
        int n = n0 + m0 + i;
        if (n < nnodes) {
            float* base = xw + ((size_t)n * NREL + r) * HC + c1;
            vfloat4 v0 = {acc[i][0], acc[i][1], acc[i][2], acc[i][3]};
            vfloat4 v1 = {acc[i][4], acc[i][5], acc[i][6], acc[i][7]};
            __builtin_nontemporal_store(v0, (vfloat4*)(base + c0a));
            __builtin_nontemporal_store(v1, (vfloat4*)(base + c0b));
        }
    }
}

// ---- per-dst-node attention softmax + aggregation + bias + relu ----
__global__ void k_agg(const float* __restrict__ xw, const float* __restrict__ qdot,
                      const float* __restrict__ kdot, const int* __restrict__ rowptr,
                      const int* __restrict__ csr_pack, const float* __restrict__ csr_ae,
                      const float* __restrict__ wee, const float* __restrict__ bias,
                      float* __restrict__ hout, int nnodes) {
    __shared__ float salpha[MAXDEG * HEADS];
    __shared__ int spack[MAXDEG];
    __shared__ float sqd[NREL * HEADS];
    __shared__ float sinv[HEADS];
    __shared__ float swee[HEADS];
    int n = blockIdx.x;
    int tid = threadIdx.x;
    int beg = rowptr[n];
    int deg = rowptr[n + 1] - beg;
    if (deg > MAXDEG) deg = MAXDEG;
    if (tid < NREL * HEADS) sqd[tid] = qdot[n * 24 + tid];
    if (tid < HEADS) swee[tid] = wee[tid];
    __syncthreads();
    for (int base = 0; base < deg; base += 32) {
        int d = base + (tid >> 3);
        int h = tid & 7;
        if (d < deg) {
            int pk = csr_pack[beg + d];
            float ae = csr_ae[beg + d];
            int s = pk >> 2, t = pk & 3;
            if (h == 0) spack[d] = pk;
            float a = sqd[t * 8 + h] + kdot[s * 24 + t * 8 + h] + ae * swee[h];
            salpha[d * 8 + h] = (a > 0.f) ? a : NEG * a;
        }
    }
    __syncthreads();
    if (tid < HEADS) {
        int h = tid;
        float m = -INFINITY;
        for (int d = 0; d < deg; d++) m = fmaxf(m, salpha[d * 8 + h]);
        float s = 0.f;
        for (int d = 0; d < deg; d++) {
            float ex = expf(salpha[d * 8 + h] - m);
            salpha[d * 8 + h] = ex;
            s += ex;
        }
        sinv[h] = 1.f / (s + 1e-16f);
    }
    __syncthreads();
    int h = tid >> 5;
    float acc = 0.f;
    for (int d = 0; d < deg; ++d) {
        int pk = spack[d];
        int s = pk >> 2, t = pk & 3;
        acc += salpha[d * 8 + h] * xw[((size_t)s * NREL + t) * HC + tid];
    }
    acc *= sinv[h];
    float v = acc + bias[tid];
    hout[(size_t)n * HC + tid] = (v > 0.f) ? v : 0.f;
}

// ---- final linear + tanh + mean-pool (atomic-free) -------------------------
__global__ __launch_bounds__(256) void k_pool2(const float* __restrict__ h3,
                                               const float* __restrict__ wlin,
                                               const float* __restrict__ blin,
                                               const int* __restrict__ batch,
                                               float* __restrict__ partials,
                                               int* __restrict__ gcnt, int nnodes) {
    int g = blockIdx.x / PCHUNK, chunk = blockIdx.x % PCHUNK;
    __shared__ int sb[2];
    if (threadIdx.x < 2) {
        int target = g + threadIdx.x;
        int lo = 0, hi = nnodes;
        while (lo < hi) { int mid = (lo + hi) >> 1; if (batch[mid] < target) lo = mid + 1; else hi = mid; }
        sb[threadIdx.x] = lo;
    }
    __syncthreads();
    int beg = sb[0], end = sb[1];
    int t = threadIdx.x;
    int w = t >> 6, lane = t & 63;
    int h = lane & 7, grp = lane >> 3;
    float rw[32];
#pragma unroll
    for (int k = 0; k < 8; ++k)
#pragma unroll
        for (int j = 0; j < 4; ++j)
            rw[k * 4 + j] = wlin[(grp * 4 + j + 32 * k) * HEADS + h];
    float bl = blin[h];
    float acc = 0.f;
    int wg = chunk * 4 + w;   // 0..31
    for (int n = beg + wg; n < end; n += PCHUNK * 4) {
        const float* row = h3 + (size_t)n * HC;
        float dot = 0.f;
#pragma unroll
        for (int k = 0; k < 8; ++k) {
            float4 v = *(const float4*)&row[grp * 4 + 32 * k];
            dot += v.x * rw[k * 4] + v.y * rw[k * 4 + 1] + v.z * rw[k * 4 + 2] + v.w * rw[k * 4 + 3];
        }
        dot += __shfl_xor(dot, 8, 64);
        dot += __shfl_xor(dot, 16, 64);
        dot += __shfl_xor(dot, 32, 64);
        acc += tanhf(dot + bl);
    }
    __shared__ float sacc[4][HEADS];
    if (lane < HEADS) sacc[w][h] = acc;
    __syncthreads();
    if (t < HEADS) {
        float s = sacc[0][t] + sacc[1][t] + sacc[2][t] + sacc[3][t];
        partials[(size_t)blockIdx.x * HEADS + t] = s;
    }
    if (t == 0 && chunk == 0) gcnt[g] = end - beg;
}

__global__ void k_div(const float* __restrict__ partials, const int* __restrict__ gcnt,
                      float* __restrict__ out, int ngraph) {
    int t = threadIdx.x;
    if (t < ngraph * HEADS) {
        int g = t >> 3, h = t & 7;
        float s = 0.f;
        for (int c = 0; c < PCHUNK; ++c) s += partials[(size_t)(g * PCHUNK + c) * HEADS + h];
        out[t] = s / fmaxf((float)gcnt[g], 1.f);
    }
}

// ---------------------------------------------------------------------------

extern "C" void kernel_launch(void* const* d_in, const int* in_sizes, int n_in,
                              void* d_out, int out_size, void* d_ws, size_t ws_size,
                              hipStream_t stream) {
    const float* x    = (const float*)d_in[0];
    const int*   ei   = (const int*)d_in[1];
    const int*   et   = (const int*)d_in[2];
    const float* ea   = (const float*)d_in[3];
    const int*   batch = (const int*)d_in[4];
    const float* W[3]  = {(const float*)d_in[5],  (const float*)d_in[11], (const float*)d_in[17]};
    const float* Q[3]  = {(const float*)d_in[6],  (const float*)d_in[12], (const float*)d_in[18]};
    const float* K[3]  = {(const float*)d_in[7],  (const float*)d_in[13], (const float*)d_in[19]};
    const float* Em[3] = {(const float*)d_in[8],  (const float*)d_in[14], (const float*)d_in[20]};
    const float* WE[3] = {(const float*)d_in[9],  (const float*)d_in[15], (const float*)d_in[21]};
    const float* B[3]  = {(const float*)d_in[10], (const float*)d_in[16], (const float*)d_in[22]};
    const float* wlin = (const float*)d_in[23];
    const float* blin = (const float*)d_in[24];

    int nnodes = in_sizes[0] / 32;
    int nedges = in_sizes[2];
    int ngraph = 16;

    char* ws = (char*)d_ws;
    size_t off = 0;
    auto alloc = [&](size_t bytes) -> void* {
        void* p = ws + off;
        off = (off + bytes + 255) & ~(size_t)255;
        return p;
    };
    int*   deg      = (int*)alloc((size_t)nnodes * 4);
    int*   fill     = (int*)alloc((size_t)nnodes * 4);
    int*   rowptr   = (int*)alloc((size_t)(nnodes + 1) * 4);
    int*   csr_pack = (int*)alloc((size_t)nedges * 4);
    float* csr_ae   = (float*)alloc((size_t)nedges * 4);
    float* xw       = (float*)alloc((size_t)nnodes * NREL * HC * 4);
    float* qdot     = (float*)alloc((size_t)nnodes * NREL * HEADS * 4);
    float* kdot     = (float*)alloc((size_t)nnodes * NREL * HEADS * 4);
    float* ha       = (float*)alloc((size_t)nnodes * HC * 4);
    float* hb       = (float*)alloc((size_t)nnodes * HC * 4);
    float* wqk      = (float*)alloc((size_t)HC * 48 * 4);
    float* wee      = (float*)alloc((size_t)HEADS * 4);
    float* partials = (float*)alloc((size_t)ngraph * PCHUNK * HEADS * 4);
    int*   gcnt     = (int*)alloc((size_t)ngraph * 4);
    (void)ws_size; (void)n_in; (void)out_size;

    // CSR build (edges are fixed across layers)
    k_init<<<(nnodes + 255) / 256, 256, 0, stream>>>(deg, fill, nnodes);
    k_deg<<<(nedges + 255) / 256, 256, 0, stream>>>(ei, deg, nedges);
    k_scan<<<1, 1024, 0, stream>>>(deg, rowptr, nnodes);
    k_scatter<<<(nedges + 255) / 256, 256, 0, stream>>>(ei, et, ea, rowptr, fill, csr_pack, csr_ae, nedges);

    int nrowt = (nnodes + 127) / 128;        // BM=128 row tiles
    int ggemm = ((nrowt + 7) / 8) * 48;      // XCD-swizzled 1-D grid
    int gqk = nrowt;

    // ---- layer 1 (IN=32): x -> ha ----
    k_prep<<<NREL * 32, 256, 0, stream>>>(W[0], Q[0], K[0], Em[0], WE[0], wqk, wee, 32);
    k_qk<32><<<gqk, 256, 0, stream>>>(x, wqk, qdot, kdot, nnodes);
    k_gemm<32><<<ggemm, 256, 0, stream>>>(x, W[0], xw, nnodes, nrowt);
    k_agg<<<nnodes, 256, 0, stream>>>(xw, qdot, kdot, rowptr, csr_pack, csr_ae, wee, B[0], ha, nnodes);

    // ---- layer 2 (IN=256): ha -> hb ----
    k_prep<<<NREL * HC, 256, 0, stream>>>(W[1], Q[1], K[1], Em[1], WE[1], wqk, wee, HC);
    k_qk<HC><<<gqk, 256, 0, stream>>>(ha, wqk, qdot, kdot, nnodes);
    k_gemm<HC><<<ggemm, 256, 0, stream>>>(ha, W[1], xw, nnodes, nrowt);
    k_agg<<<nnodes, 256, 0, stream>>>(xw, qdot, kdot, rowptr, csr_pack, csr_ae, wee, B[1], hb, nnodes);

    // ---- layer 3 (IN=256): hb -> ha ----
    k_prep<<<NREL * HC, 256, 0, stream>>>(W[2], Q[2], K[2], Em[2], WE[2], wqk, wee, HC);
    k_qk<HC><<<gqk, 256, 0, stream>>>(hb, wqk, qdot, kdot, nnodes);
    k_gemm<HC><<<ggemm, 256, 0, stream>>>(hb, W[2], xw, nnodes, nrowt);
    k_agg<<<nnodes, 256, 0, stream>>>(xw, qdot, kdot, rowptr, csr_pack, csr_ae, wee, B[2], ha, nnodes);

    // ---- head: linear + tanh + mean pool (atomic-free) ----
    k_pool2<<<ngraph * PCHUNK, 256, 0, stream>>>(ha, wlin, blin, batch, partials, gcnt, nnodes);
    k_div<<<1, 128, 0, stream>>>(partials, gcnt, (float*)d_out, ngraph);
}

// Round 9
// 735.576 us; speedup vs baseline: 1.2546x; 1.0231x over previous
//
#include <hip/hip_runtime.h>
#include <math.h>

#define HEADS 8
#define HC 256
#define NREL 3
#define NEG 0.2f
#define MAXDEG 128   // max in-degree; E=160k over N=10k dst -> mean 16, max ~45. 128 is hugely safe.
#define PCHUNK 8     // chunk-blocks per graph in the pool kernel

typedef float vfloat4 __attribute__((ext_vector_type(4)));  // native vec for nontemporal builtins

__device__ __forceinline__ float warp32_reduce(float p) {
#pragma unroll
    for (int off = 16; off > 0; off >>= 1) p += __shfl_down(p, off, 32);
    return p;
}

// ---- CSR build -------------------------------------------------------------

__global__ void k_init(int* deg, int* fill, int nnodes) {
    int i = blockIdx.x * blockDim.x + threadIdx.x;
    if (i < nnodes) { deg[i] = 0; fill[i] = 0; }
}

__global__ void k_deg(const int* __restrict__ ei, int* deg, int nedges) {
    int e = blockIdx.x * blockDim.x + threadIdx.x;
    if (e < nedges) atomicAdd(&deg[ei[nedges + e]], 1);
}

// single-block exclusive scan over nnodes degrees -> rowptr[n+1]
__global__ void k_scan(const int* __restrict__ deg, int* rowptr, int n) {
    __shared__ int ss[1024];
    int tid = threadIdx.x;
    int per = (n + 1023) >> 10;
    int b = tid * per;
    int s = 0;
    for (int i = 0; i < per; i++) { int idx = b + i; if (idx < n) s += deg[idx]; }
    ss[tid] = s;
    __syncthreads();
    for (int off = 1; off < 1024; off <<= 1) {
        int v = (tid >= off) ? ss[tid - off] : 0;
        __syncthreads();
        ss[tid] += v;
        __syncthreads();
    }
    int run = (tid == 0) ? 0 : ss[tid - 1];
    for (int i = 0; i < per; i++) {
        int idx = b + i;
        if (idx < n) { rowptr[idx] = run; run += deg[idx]; }
    }
    if (tid == 0) rowptr[n] = ss[1023];
}

__global__ void k_scatter(const int* __restrict__ ei, const int* __restrict__ et,
                          const float* __restrict__ ea, const int* __restrict__ rowptr,
                          int* fill, int* csr_pack, float* csr_ae, int nedges) {
    int e = blockIdx.x * blockDim.x + threadIdx.x;
    if (e >= nedges) return;
    int dst = ei[nedges + e];
    int pos = atomicAdd(&fill[dst], 1);
    int slot = rowptr[dst] + pos;
    csr_pack[slot] = (ei[e] << 2) | (et[e] & 3);
    csr_ae[slot] = ea[e];
}

// ---- per-layer small precompute --------------------------------------------
// wqk[i][r*8+h]      = w[r,i,:] @ q[:,h]   (cols 0..23)
// wqk[i][24+r*8+h]   = w[r,i,:] @ k[:,h]   (cols 24..47)
// wee[h]             = we @ e[:,h]
__global__ void k_prep(const float* __restrict__ w, const float* __restrict__ q,
                       const float* __restrict__ kk, const float* __restrict__ e,
                       const float* __restrict__ we, float* wqk, float* wee, int IN) {
    int tid = threadIdx.x;
    int ri = blockIdx.x;  // r*IN + i
    int r = ri / IN, i = ri % IN;
    int h = tid >> 5, lane = tid & 31;
    const float* wrow = w + (size_t)ri * HC;
    float p = 0.f;
    for (int o = lane; o < HC; o += 32) p += wrow[o] * q[o * HEADS + h];
    p = warp32_reduce(p);
    if (lane == 0) wqk[i * 48 + r * 8 + h] = p;
    p = 0.f;
    for (int o = lane; o < HC; o += 32) p += wrow[o] * kk[o * HEADS + h];
    p = warp32_reduce(p);
    if (lane == 0) wqk[i * 48 + 24 + r * 8 + h] = p;
    if (blockIdx.x == 0 && tid < HEADS) {
        float s = 0.f;
        for (int o = 0; o < HC; o++) s += we[o] * e[o * HEADS + tid];
        wee[tid] = s;
    }
}

// ---- skinny GEMM for qdot/kdot: [nnodes x K] @ [K x 48] --------------------
template <int K>
__global__ __launch_bounds__(256) void k_qk(const float* __restrict__ xin,
                                            const float* __restrict__ wqk,
                                            float* __restrict__ qdot,
                                            float* __restrict__ kdot, int nnodes) {
    constexpr int BM = 128, BK = 32;
    __shared__ float xs[BK][BM];   // transposed x tile
    __shared__ float wt[BK][48];
    int n0 = blockIdx.x * BM;
    int t = threadIdx.x;
    int tx = t & 15, ty = t >> 4;
    int m0 = ty * 8, c0 = tx * 3;
    float acc[8][3];
#pragma unroll
    for (int i = 0; i < 8; i++)
#pragma unroll
        for (int j = 0; j < 3; j++) acc[i][j] = 0.f;
    int sm = t >> 1;
    int skq = (t & 1) * 16;
    for (int k0 = 0; k0 < K; k0 += BK) {
        int gn = n0 + sm;
        const float* xrow = xin + (size_t)gn * K + k0 + skq;
#pragma unroll
        for (int j = 0; j < 4; ++j) {
            float4 v = (gn < nnodes) ? *(const float4*)(xrow + 4 * j)
                                     : make_float4(0.f, 0.f, 0.f, 0.f);
            xs[skq + 4 * j + 0][sm] = v.x;
            xs[skq + 4 * j + 1][sm] = v.y;
            xs[skq + 4 * j + 2][sm] = v.z;
            xs[skq + 4 * j + 3][sm] = v.w;
        }
        for (int idx = t; idx < BK * 48; idx += 256) {
            int kk = idx / 48, c = idx % 48;
            wt[kk][c] = wqk[(size_t)(k0 + kk) * 48 + c];
        }
        __syncthreads();
#pragma unroll
        for (int kk = 0; kk < BK; ++kk) {
            float b0 = wt[kk][c0], b1 = wt[kk][c0 + 1], b2 = wt[kk][c0 + 2];
            float4 a0 = *(const float4*)&xs[kk][m0];
            float4 a1 = *(const float4*)&xs[kk][m0 + 4];
            float am[8] = {a0.x, a0.y, a0.z, a0.w, a1.x, a1.y, a1.z, a1.w};
#pragma unroll
            for (int i = 0; i < 8; i++) {
                acc[i][0] += am[i] * b0;
                acc[i][1] += am[i] * b1;
                acc[i][2] += am[i] * b2;
            }
        }
        __syncthreads();
    }
#pragma unroll
    for (int i = 0; i < 8; ++i) {
        int n = n0 + m0 + i;
        if (n < nnodes) {
#pragma unroll
            for (int j = 0; j < 3; ++j) {
                int c = c0 + j;
                if (c < 24) qdot[n * 24 + c] = acc[i][j];
                else        kdot[n * 24 + (c - 24)] = acc[i][j];
            }
        }
    }
}

// ---- tiled fp32 GEMM: xw[n,r,:] = x[n,:] @ w[r]  -------------------------
// BM=64 x BN=128 x BK=32: 960 blocks -> ~3.75 blocks/CU (~3.75 waves/SIMD)
// for latency hiding; round-7's BM=64 failed only because launch_bounds(256,4)
// forced 64 VGPRs -> scratch spill. Here launch_bounds(256,2) gives a 256-reg
// cap (est ~96 used, no spill). Register double-buffered staging; XCD swizzle:
// all 6 (c-half, rel) blocks of a row-tile share id%8 -> same XCD L2.
template <int K>
__global__ __launch_bounds__(256, 2) void k_gemm(const float* __restrict__ xin,
                                                 const float* __restrict__ w,
                                                 float* __restrict__ xw,
                                                 int nnodes, int nrowt) {
    constexpr int BM = 64, BN = 128, BK = 32;
    __shared__ float xs[BK][BM];   // transposed x tile: xs[k][m]
    __shared__ float wt[BK][BN];   // w tile: wt[k][c]
    int id = blockIdx.x;
    int hi = id / 48;
    int rem = id - hi * 48;
    int cr = rem >> 3;                 // 0..5 = (r<<1)|chalf
    int rowt = hi * 8 + (rem & 7);
    if (rowt >= nrowt) return;
    int r = cr >> 1;
    int c1 = (cr & 1) * BN;
    int n0 = rowt * BM;
    int t = threadIdx.x;
    int tx = t & 15, ty = t >> 4;
    int m0 = ty * 4;
    int c0a = tx * 4, c0b = 64 + tx * 4;
    float acc[4][8];
#pragma unroll
    for (int i = 0; i < 4; i++)
#pragma unroll
        for (int j = 0; j < 8; j++) acc[i][j] = 0.f;
    const float* wr = w + (size_t)r * K * HC;

    int sm = t >> 2;              // x staging: node within tile (4 thr/row)
    int skq = (t & 3) * 8;        // x staging: k offset (8 floats = 2 float4)
    int gn = n0 + sm;
    bool xok = gn < nnodes;
    const float* xbase = xin + (size_t)gn * K + skq;

    float4 px[2], pw[4];
    auto load_x = [&](int k0) {
#pragma unroll
        for (int j = 0; j < 2; ++j)
            px[j] = xok ? *(const float4*)(xbase + k0 + 4 * j)
                        : make_float4(0.f, 0.f, 0.f, 0.f);
    };
    auto load_w = [&](int k0) {
#pragma unroll
        for (int it = 0; it < 4; ++it) {
            int fidx = t + 256 * it;
            int kk = fidx >> 5;
            int c4 = (fidx & 31) << 2;
            pw[it] = *(const float4*)(wr + (size_t)(k0 + kk) * HC + c1 + c4);
        }
    };
    auto stage = [&]() {
#pragma unroll
        for (int j = 0; j < 2; ++j) {
            xs[skq + 4 * j + 0][sm] = px[j].x;
            xs[skq + 4 * j + 1][sm] = px[j].y;
            xs[skq + 4 * j + 2][sm] = px[j].z;
            xs[skq + 4 * j + 3][sm] = px[j].w;
        }
#pragma unroll
        for (int it = 0; it < 4; ++it) {
            int fidx = t + 256 * it;
            int kk = fidx >> 5;
            int c4 = (fidx & 31) << 2;
            *(float4*)&wt[kk][c4] = pw[it];
        }
    };

    load_x(0); load_w(0);
    for (int k0 = 0; k0 < K; k0 += BK) {
        stage();
        __syncthreads();
        if (k0 + BK < K) { load_x(k0 + BK); load_w(k0 + BK); }
#pragma unroll
        for (int kk = 0; kk < BK; ++kk) {
            float4 a0 = *(const float4*)&xs[kk][m0];
            float4 b0 = *(const float4*)&wt[kk][c0a];
            float4 b1 = *(const float4*)&wt[kk][c0b];
            float am[4] = {a0.x, a0.y, a0.z, a0.w};
            float bn[8] = {b0.x, b0.y, b0.z, b0.w, b1.x, b1.y, b1.z, b1.w};
#pragma unroll
            for (int i = 0; i < 4; i++)
#pragma unroll
                for (int j = 0; j < 8; j++) acc[i][j] += am[i] * bn[j];
        }
        __syncthreads();
    }
#pragma unroll
    for (int i = 0; i < 4; ++i) {
        int n = n0 + m0 + i;
        if (n < nnodes) {
            float* base = xw + ((size_t)n * NREL + r) * HC + c1;
            vfloat4 v0 = {acc[i][0], acc[i][1], acc[i][2], acc[i][3]};
            vfloat4 v1 = {acc[i][4], acc[i][5], acc[i][6], acc[i][7]};
            __builtin_nontemporal_store(v0, (vfloat4*)(base + c0a));
            __builtin_nontemporal_store(v1, (vfloat4*)(base + c0b));
        }
    }
}

// ---- per-dst-node attention softmax + aggregation + bias + relu ----
__global__ void k_agg(const float* __restrict__ xw, const float* __restrict__ qdot,
                      const float* __restrict__ kdot, const int* __restrict__ rowptr,
                      const int* __restrict__ csr_pack, const float* __restrict__ csr_ae,
                      const float* __restrict__ wee, const float* __restrict__ bias,
                      float* __restrict__ hout, int nnodes) {
    __shared__ float salpha[MAXDEG * HEADS];
    __shared__ int spack[MAXDEG];
    __shared__ float sqd[NREL * HEADS];
    __shared__ float sinv[HEADS];
    __shared__ float swee[HEADS];
    int n = blockIdx.x;
    int tid = threadIdx.x;
    int beg = rowptr[n];
    int deg = rowptr[n + 1] - beg;
    if (deg > MAXDEG) deg = MAXDEG;
    if (tid < NREL * HEADS) sqd[tid] = qdot[n * 24 + tid];
    if (tid < HEADS) swee[tid] = wee[tid];
    __syncthreads();
    for (int base = 0; base < deg; base += 32) {
        int d = base + (tid >> 3);
        int h = tid & 7;
        if (d < deg) {
            int pk = csr_pack[beg + d];
            float ae = csr_ae[beg + d];
            int s = pk >> 2, t = pk & 3;
            if (h == 0) spack[d] = pk;
            float a = sqd[t * 8 + h] + kdot[s * 24 + t * 8 + h] + ae * swee[h];
            salpha[d * 8 + h] = (a > 0.f) ? a : NEG * a;
        }
    }
    __syncthreads();
    if (tid < HEADS) {
        int h = tid;
        float m = -INFINITY;
        for (int d = 0; d < deg; d++) m = fmaxf(m, salpha[d * 8 + h]);
        float s = 0.f;
        for (int d = 0; d < deg; d++) {
            float ex = expf(salpha[d * 8 + h] - m);
            salpha[d * 8 + h] = ex;
            s += ex;
        }
        sinv[h] = 1.f / (s + 1e-16f);
    }
    __syncthreads();
    int h = tid >> 5;
    float acc = 0.f;
    for (int d = 0; d < deg; ++d) {
        int pk = spack[d];
        int s = pk >> 2, t = pk & 3;
        acc += salpha[d * 8 + h] * xw[((size_t)s * NREL + t) * HC + tid];
    }
    acc *= sinv[h];
    float v = acc + bias[tid];
    hout[(size_t)n * HC + tid] = (v > 0.f) ? v : 0.f;
}

// ---- final linear + tanh + mean-pool (atomic-free) -------------------------
__global__ __launch_bounds__(256) void k_pool2(const float* __restrict__ h3,
                                               const float* __restrict__ wlin,
                                               const float* __restrict__ blin,
                                               const int* __restrict__ batch,
                                               float* __restrict__ partials,
                                               int* __restrict__ gcnt, int nnodes) {
    int g = blockIdx.x / PCHUNK, chunk = blockIdx.x % PCHUNK;
    __shared__ int sb[2];
    if (threadIdx.x < 2) {
        int target = g + threadIdx.x;
        int lo = 0, hi = nnodes;
        while (lo < hi) { int mid = (lo + hi) >> 1; if (batch[mid] < target) lo = mid + 1; else hi = mid; }
        sb[threadIdx.x] = lo;
    }
    __syncthreads();
    int beg = sb[0], end = sb[1];
    int t = threadIdx.x;
    int w = t >> 6, lane = t & 63;
    int h = lane & 7, grp = lane >> 3;
    float rw[32];
#pragma unroll
    for (int k = 0; k < 8; ++k)
#pragma unroll
        for (int j = 0; j < 4; ++j)
            rw[k * 4 + j] = wlin[(grp * 4 + j + 32 * k) * HEADS + h];
    float bl = blin[h];
    float acc = 0.f;
    int wg = chunk * 4 + w;   // 0..31
    for (int n = beg + wg; n < end; n += PCHUNK * 4) {
        const float* row = h3 + (size_t)n * HC;
        float dot = 0.f;
#pragma unroll
        for (int k = 0; k < 8; ++k) {
            float4 v = *(const float4*)&row[grp * 4 + 32 * k];
            dot += v.x * rw[k * 4] + v.y * rw[k * 4 + 1] + v.z * rw[k * 4 + 2] + v.w * rw[k * 4 + 3];
        }
        dot += __shfl_xor(dot, 8, 64);
        dot += __shfl_xor(dot, 16, 64);
        dot += __shfl_xor(dot, 32, 64);
        acc += tanhf(dot + bl);
    }
    __shared__ float sacc[4][HEADS];
    if (lane < HEADS) sacc[w][h] = acc;
    __syncthreads();
    if (t < HEADS) {
        float s = sacc[0][t] + sacc[1][t] + sacc[2][t] + sacc[3][t];
        partials[(size_t)blockIdx.x * HEADS + t] = s;
    }
    if (t == 0 && chunk == 0) gcnt[g] = end - beg;
}

__global__ void k_div(const float* __restrict__ partials, const int* __restrict__ gcnt,
                      float* __restrict__ out, int ngraph) {
    int t = threadIdx.x;
    if (t < ngraph * HEADS) {
        int g = t >> 3, h = t & 7;
        float s = 0.f;
        for (int c = 0; c < PCHUNK; ++c) s += partials[(size_t)(g * PCHUNK + c) * HEADS + h];
        out[t] = s / fmaxf((float)gcnt[g], 1.f);
    }
}

// ---------------------------------------------------------------------------

extern "C" void kernel_launch(void* const* d_in, const int* in_sizes, int n_in,
                              void* d_out, int out_size, void* d_ws, size_t ws_size,
                              hipStream_t stream) {
    const float* x    = (const float*)d_in[0];
    const int*   ei   = (const int*)d_in[1];
    const int*   et   = (const int*)d_in[2];
    const float* ea   = (const float*)d_in[3];
    const int*   batch = (const int*)d_in[4];
    const float* W[3]  = {(const float*)d_in[5],  (const float*)d_in[11], (const float*)d_in[17]};
    const float* Q[3]  = {(const float*)d_in[6],  (const float*)d_in[12], (const float*)d_in[18]};
    const float* K[3]  = {(const float*)d_in[7],  (const float*)d_in[13], (const float*)d_in[19]};
    const float* Em[3] = {(const float*)d_in[8],  (const float*)d_in[14], (const float*)d_in[20]};
    const float* WE[3] = {(const float*)d_in[9],  (const float*)d_in[15], (const float*)d_in[21]};
    const float* B[3]  = {(const float*)d_in[10], (const float*)d_in[16], (const float*)d_in[22]};
    const float* wlin = (const float*)d_in[23];
    const float* blin = (const float*)d_in[24];

    int nnodes = in_sizes[0] / 32;
    int nedges = in_sizes[2];
    int ngraph = 16;

    char* ws = (char*)d_ws;
    size_t off = 0;
    auto alloc = [&](size_t bytes) -> void* {
        void* p = ws + off;
        off = (off + bytes + 255) & ~(size_t)255;
        return p;
    };
    int*   deg      = (int*)alloc((size_t)nnodes * 4);
    int*   fill     = (int*)alloc((size_t)nnodes * 4);
    int*   rowptr   = (int*)alloc((size_t)(nnodes + 1) * 4);
    int*   csr_pack = (int*)alloc((size_t)nedges * 4);
    float* csr_ae   = (float*)alloc((size_t)nedges * 4);
    float* xw       = (float*)alloc((size_t)nnodes * NREL * HC * 4);
    float* qdot     = (float*)alloc((size_t)nnodes * NREL * HEADS * 4);
    float* kdot     = (float*)alloc((size_t)nnodes * NREL * HEADS * 4);
    float* ha       = (float*)alloc((size_t)nnodes * HC * 4);
    float* hb       = (float*)alloc((size_t)nnodes * HC * 4);
    float* wqk      = (float*)alloc((size_t)HC * 48 * 4);
    float* wee      = (float*)alloc((size_t)HEADS * 4);
    float* partials = (float*)alloc((size_t)ngraph * PCHUNK * HEADS * 4);
    int*   gcnt     = (int*)alloc((size_t)ngraph * 4);
    (void)ws_size; (void)n_in; (void)out_size;

    // CSR build (edges are fixed across layers)
    k_init<<<(nnodes + 255) / 256, 256, 0, stream>>>(deg, fill, nnodes);
    k_deg<<<(nedges + 255) / 256, 256, 0, stream>>>(ei, deg, nedges);
    k_scan<<<1, 1024, 0, stream>>>(deg, rowptr, nnodes);
    k_scatter<<<(nedges + 255) / 256, 256, 0, stream>>>(ei, et, ea, rowptr, fill, csr_pack, csr_ae, nedges);

    int nrowt = (nnodes + 63) / 64;          // BM=64 row tiles
    int ggemm = ((nrowt + 7) / 8) * 48;      // XCD-swizzled 1-D grid
    int gqk = (nnodes + 127) / 128;

    // ---- layer 1 (IN=32): x -> ha ----
    k_prep<<<NREL * 32, 256, 0, stream>>>(W[0], Q[0], K[0], Em[0], WE[0], wqk, wee, 32);
    k_qk<32><<<gqk, 256, 0, stream>>>(x, wqk, qdot, kdot, nnodes);
    k_gemm<32><<<ggemm, 256, 0, stream>>>(x, W[0], xw, nnodes, nrowt);
    k_agg<<<nnodes, 256, 0, stream>>>(xw, qdot, kdot, rowptr, csr_pack, csr_ae, wee, B[0], ha, nnodes);

    // ---- layer 2 (IN=256): ha -> hb ----
    k_prep<<<NREL * HC, 256, 0, stream>>>(W[1], Q[1], K[1], Em[1], WE[1], wqk, wee, HC);
    k_qk<HC><<<gqk, 256, 0, stream>>>(ha, wqk, qdot, kdot, nnodes);
    k_gemm<HC><<<ggemm, 256, 0, stream>>>(ha, W[1], xw, nnodes, nrowt);
    k_agg<<<nnodes, 256, 0, stream>>>(xw, qdot, kdot, rowptr, csr_pack, csr_ae, wee, B[1], hb, nnodes);

    // ---- layer 3 (IN=256): hb -> ha ----
    k_prep<<<NREL * HC, 256, 0, stream>>>(W[2], Q[2], K[2], Em[2], WE[2], wqk, wee, HC);
    k_qk<HC><<<gqk, 256, 0, stream>>>(hb, wqk, qdot, kdot, nnodes);
    k_gemm<HC><<<ggemm, 256, 0, stream>>>(hb, W[2], xw, nnodes, nrowt);
    k_agg<<<nnodes, 256, 0, stream>>>(xw, qdot, kdot, rowptr, csr_pack, csr_ae, wee, B[2], ha, nnodes);

    // ---- head: linear + tanh + mean pool (atomic-free) ----
    k_pool2<<<ngraph * PCHUNK, 256, 0, stream>>>(ha, wlin, blin, batch, partials, gcnt, nnodes);
    k_div<<<1, 128, 0, stream>>>(partials, gcnt, (float*)d_out, ngraph);
}

// Round 10
// 680.034 us; speedup vs baseline: 1.3571x; 1.0817x over previous
//
#include <hip/hip_runtime.h>
#include <math.h>

#define HEADS 8
#define HC 256
#define NREL 3
#define NEG 0.2f
#define MAXDEG 128   // max in-degree; E=160k over N=10k dst -> mean 16, max ~45. 128 is hugely safe.
#define PCHUNK 8     // chunk-blocks per graph in the pool kernel

typedef float vfloat4 __attribute__((ext_vector_type(4)));  // native vec for nontemporal builtins

__device__ __forceinline__ float warp32_reduce(float p) {
#pragma unroll
    for (int off = 16; off > 0; off >>= 1) p += __shfl_down(p, off, 32);
    return p;
}

// ---- CSR build -------------------------------------------------------------

__global__ void k_init(int* deg, int* fill, int nnodes) {
    int i = blockIdx.x * blockDim.x + threadIdx.x;
    if (i < nnodes) { deg[i] = 0; fill[i] = 0; }
}

__global__ void k_deg(const int* __restrict__ ei, int* deg, int nedges) {
    int e = blockIdx.x * blockDim.x + threadIdx.x;
    if (e < nedges) atomicAdd(&deg[ei[nedges + e]], 1);
}

// single-block exclusive scan over nnodes degrees -> rowptr[n+1]
__global__ void k_scan(const int* __restrict__ deg, int* rowptr, int n) {
    __shared__ int ss[1024];
    int tid = threadIdx.x;
    int per = (n + 1023) >> 10;
    int b = tid * per;
    int s = 0;
    for (int i = 0; i < per; i++) { int idx = b + i; if (idx < n) s += deg[idx]; }
    ss[tid] = s;
    __syncthreads();
    for (int off = 1; off < 1024; off <<= 1) {
        int v = (tid >= off) ? ss[tid - off] : 0;
        __syncthreads();
        ss[tid] += v;
        __syncthreads();
    }
    int run = (tid == 0) ? 0 : ss[tid - 1];
    for (int i = 0; i < per; i++) {
        int idx = b + i;
        if (idx < n) { rowptr[idx] = run; run += deg[idx]; }
    }
    if (tid == 0) rowptr[n] = ss[1023];
}

__global__ void k_scatter(const int* __restrict__ ei, const int* __restrict__ et,
                          const float* __restrict__ ea, const int* __restrict__ rowptr,
                          int* fill, int* csr_pack, float* csr_ae, int nedges) {
    int e = blockIdx.x * blockDim.x + threadIdx.x;
    if (e >= nedges) return;
    int dst = ei[nedges + e];
    int pos = atomicAdd(&fill[dst], 1);
    int slot = rowptr[dst] + pos;
    csr_pack[slot] = (ei[e] << 2) | (et[e] & 3);
    csr_ae[slot] = ea[e];
}

// ---- per-layer small precompute --------------------------------------------
// wqk[i][r*8+h]      = w[r,i,:] @ q[:,h]   (cols 0..23)
// wqk[i][24+r*8+h]   = w[r,i,:] @ k[:,h]   (cols 24..47)
// wee[h]             = we @ e[:,h]
__global__ void k_prep(const float* __restrict__ w, const float* __restrict__ q,
                       const float* __restrict__ kk, const float* __restrict__ e,
                       const float* __restrict__ we, float* wqk, float* wee, int IN) {
    int tid = threadIdx.x;
    int ri = blockIdx.x;  // r*IN + i
    int r = ri / IN, i = ri % IN;
    int h = tid >> 5, lane = tid & 31;
    const float* wrow = w + (size_t)ri * HC;
    float p = 0.f;
    for (int o = lane; o < HC; o += 32) p += wrow[o] * q[o * HEADS + h];
    p = warp32_reduce(p);
    if (lane == 0) wqk[i * 48 + r * 8 + h] = p;
    p = 0.f;
    for (int o = lane; o < HC; o += 32) p += wrow[o] * kk[o * HEADS + h];
    p = warp32_reduce(p);
    if (lane == 0) wqk[i * 48 + 24 + r * 8 + h] = p;
    if (blockIdx.x == 0 && tid < HEADS) {
        float s = 0.f;
        for (int o = 0; o < HC; o++) s += we[o] * e[o * HEADS + tid];
        wee[tid] = s;
    }
}

// ---- skinny GEMM for qdot/kdot: [nnodes x K] @ [K x 48] --------------------
template <int K>
__global__ __launch_bounds__(256) void k_qk(const float* __restrict__ xin,
                                            const float* __restrict__ wqk,
                                            float* __restrict__ qdot,
                                            float* __restrict__ kdot, int nnodes) {
    constexpr int BM = 128, BK = 32;
    __shared__ float xs[BK][BM];   // transposed x tile
    __shared__ float wt[BK][48];
    int n0 = blockIdx.x * BM;
    int t = threadIdx.x;
    int tx = t & 15, ty = t >> 4;
    int m0 = ty * 8, c0 = tx * 3;
    float acc[8][3];
#pragma unroll
    for (int i = 0; i < 8; i++)
#pragma unroll
        for (int j = 0; j < 3; j++) acc[i][j] = 0.f;
    int sm = t >> 1;
    int skq = (t & 1) * 16;
    for (int k0 = 0; k0 < K; k0 += BK) {
        int gn = n0 + sm;
        const float* xrow = xin + (size_t)gn * K + k0 + skq;
#pragma unroll
        for (int j = 0; j < 4; ++j) {
            float4 v = (gn < nnodes) ? *(const float4*)(xrow + 4 * j)
                                     : make_float4(0.f, 0.f, 0.f, 0.f);
            xs[skq + 4 * j + 0][sm] = v.x;
            xs[skq + 4 * j + 1][sm] = v.y;
            xs[skq + 4 * j + 2][sm] = v.z;
            xs[skq + 4 * j + 3][sm] = v.w;
        }
        for (int idx = t; idx < BK * 48; idx += 256) {
            int kk = idx / 48, c = idx % 48;
            wt[kk][c] = wqk[(size_t)(k0 + kk) * 48 + c];
        }
        __syncthreads();
#pragma unroll
        for (int kk = 0; kk < BK; ++kk) {
            float b0 = wt[kk][c0], b1 = wt[kk][c0 + 1], b2 = wt[kk][c0 + 2];
            float4 a0 = *(const float4*)&xs[kk][m0];
            float4 a1 = *(const float4*)&xs[kk][m0 + 4];
            float am[8] = {a0.x, a0.y, a0.z, a0.w, a1.x, a1.y, a1.z, a1.w};
#pragma unroll
            for (int i = 0; i < 8; i++) {
                acc[i][0] += am[i] * b0;
                acc[i][1] += am[i] * b1;
                acc[i][2] += am[i] * b2;
            }
        }
        __syncthreads();
    }
#pragma unroll
    for (int i = 0; i < 8; ++i) {
        int n = n0 + m0 + i;
        if (n < nnodes) {
#pragma unroll
            for (int j = 0; j < 3; ++j) {
                int c = c0 + j;
                if (c < 24) qdot[n * 24 + c] = acc[i][j];
                else        kdot[n * 24 + (c - 24)] = acc[i][j];
            }
        }
    }
}

// ---- tiled fp32 GEMM: xw[n,r,:] = x[n,:] @ w[r]  -------------------------
// EXACT round-5 config (best measured: bench 687): 128x128x32 tile, grid
// dim3(79,2,3) -> consecutive blocks share one W tile (L2 reuse), low-conflict
// B-fragments wt[kk][tx*4] / wt[kk][64+tx*4], flat coalesced W staging,
// nontemporal xw stores. No swizzle / no prefetch (measured neutral-negative).
template <int K>
__global__ __launch_bounds__(256, 2) void k_gemm(const float* __restrict__ xin,
                                                 const float* __restrict__ w,
                                                 float* __restrict__ xw, int nnodes) {
    constexpr int BM = 128, BN = 128, BK = 32;
    __shared__ float xs[BK][BM];   // transposed x tile: xs[k][m]
    __shared__ float wt[BK][BN];   // w tile: wt[k][c]
    int r = blockIdx.z;
    int n0 = blockIdx.x * BM;
    int c1 = blockIdx.y * BN;
    int t = threadIdx.x;
    int tx = t & 15, ty = t >> 4;
    int m0 = ty * 8;
    int c0a = tx * 4, c0b = 64 + tx * 4;
    float acc[8][8];
#pragma unroll
    for (int i = 0; i < 8; i++)
#pragma unroll
        for (int j = 0; j < 8; j++) acc[i][j] = 0.f;
    const float* wr = w + (size_t)r * K * HC;
    int sm = t >> 1;              // x staging: node within tile
    int skq = (t & 1) * 16;       // x staging: k offset (16 floats = 4 float4)

    for (int k0 = 0; k0 < K; k0 += BK) {
        int gn = n0 + sm;
        const float* xrow = xin + (size_t)gn * K + k0 + skq;
#pragma unroll
        for (int j = 0; j < 4; ++j) {
            float4 v = (gn < nnodes) ? *(const float4*)(xrow + 4 * j)
                                     : make_float4(0.f, 0.f, 0.f, 0.f);
            xs[skq + 4 * j + 0][sm] = v.x;
            xs[skq + 4 * j + 1][sm] = v.y;
            xs[skq + 4 * j + 2][sm] = v.z;
            xs[skq + 4 * j + 3][sm] = v.w;
        }
        // flat coalesced staging of the 32x128 W tile (float4 granularity)
#pragma unroll
        for (int it = 0; it < 4; ++it) {
            int fidx = t + 256 * it;         // 0..1023
            int kk = fidx >> 5;
            int c4 = (fidx & 31) << 2;
            *(float4*)&wt[kk][c4] = *(const float4*)(wr + (size_t)(k0 + kk) * HC + c1 + c4);
        }
        __syncthreads();
#pragma unroll
        for (int kk = 0; kk < BK; ++kk) {
            float4 a0 = *(const float4*)&xs[kk][m0];
            float4 a1 = *(const float4*)&xs[kk][m0 + 4];
            float4 b0 = *(const float4*)&wt[kk][c0a];
            float4 b1 = *(const float4*)&wt[kk][c0b];
            float am[8] = {a0.x, a0.y, a0.z, a0.w, a1.x, a1.y, a1.z, a1.w};
            float bn[8] = {b0.x, b0.y, b0.z, b0.w, b1.x, b1.y, b1.z, b1.w};
#pragma unroll
            for (int i = 0; i < 8; i++)
#pragma unroll
                for (int j = 0; j < 8; j++) acc[i][j] += am[i] * bn[j];
        }
        __syncthreads();
    }
#pragma unroll
    for (int i = 0; i < 8; ++i) {
        int n = n0 + m0 + i;
        if (n < nnodes) {
            float* base = xw + ((size_t)n * NREL + r) * HC + c1;
            vfloat4 v0 = {acc[i][0], acc[i][1], acc[i][2], acc[i][3]};
            vfloat4 v1 = {acc[i][4], acc[i][5], acc[i][6], acc[i][7]};
            __builtin_nontemporal_store(v0, (vfloat4*)(base + c0a));
            __builtin_nontemporal_store(v1, (vfloat4*)(base + c0b));
        }
    }
}

// ---- per-dst-node attention softmax + aggregation + bias + relu ----
// Phase 3 unrolled x4 with all four gather addresses issued before the FMAs
// (4 outstanding LLC/L2 loads per wave instead of ~1 in the dynamic loop).
__global__ void k_agg(const float* __restrict__ xw, const float* __restrict__ qdot,
                      const float* __restrict__ kdot, const int* __restrict__ rowptr,
                      const int* __restrict__ csr_pack, const float* __restrict__ csr_ae,
                      const float* __restrict__ wee, const float* __restrict__ bias,
                      float* __restrict__ hout, int nnodes) {
    __shared__ float salpha[MAXDEG * HEADS];
    __shared__ int spack[MAXDEG];
    __shared__ float sqd[NREL * HEADS];
    __shared__ float sinv[HEADS];
    __shared__ float swee[HEADS];
    int n = blockIdx.x;
    int tid = threadIdx.x;
    int beg = rowptr[n];
    int deg = rowptr[n + 1] - beg;
    if (deg > MAXDEG) deg = MAXDEG;
    if (tid < NREL * HEADS) sqd[tid] = qdot[n * 24 + tid];
    if (tid < HEADS) swee[tid] = wee[tid];
    __syncthreads();
    for (int base = 0; base < deg; base += 32) {
        int d = base + (tid >> 3);
        int h = tid & 7;
        if (d < deg) {
            int pk = csr_pack[beg + d];
            float ae = csr_ae[beg + d];
            int s = pk >> 2, t = pk & 3;
            if (h == 0) spack[d] = pk;
            float a = sqd[t * 8 + h] + kdot[s * 24 + t * 8 + h] + ae * swee[h];
            salpha[d * 8 + h] = (a > 0.f) ? a : NEG * a;
        }
    }
    __syncthreads();
    if (tid < HEADS) {
        int h = tid;
        float m = -INFINITY;
        for (int d = 0; d < deg; d++) m = fmaxf(m, salpha[d * 8 + h]);
        float s = 0.f;
        for (int d = 0; d < deg; d++) {
            float ex = expf(salpha[d * 8 + h] - m);
            salpha[d * 8 + h] = ex;
            s += ex;
        }
        sinv[h] = 1.f / (s + 1e-16f);
    }
    __syncthreads();
    int h = tid >> 5;
    float acc = 0.f;
    int d = 0;
    for (; d + 4 <= deg; d += 4) {
        int pk0 = spack[d + 0], pk1 = spack[d + 1];
        int pk2 = spack[d + 2], pk3 = spack[d + 3];
        const float* r0 = xw + ((size_t)(pk0 >> 2) * NREL + (pk0 & 3)) * HC + tid;
        const float* r1 = xw + ((size_t)(pk1 >> 2) * NREL + (pk1 & 3)) * HC + tid;
        const float* r2 = xw + ((size_t)(pk2 >> 2) * NREL + (pk2 & 3)) * HC + tid;
        const float* r3 = xw + ((size_t)(pk3 >> 2) * NREL + (pk3 & 3)) * HC + tid;
        float v0 = *r0, v1 = *r1, v2 = *r2, v3 = *r3;
        acc += salpha[(d + 0) * 8 + h] * v0;
        acc += salpha[(d + 1) * 8 + h] * v1;
        acc += salpha[(d + 2) * 8 + h] * v2;
        acc += salpha[(d + 3) * 8 + h] * v3;
    }
    for (; d < deg; ++d) {
        int pk = spack[d];
        acc += salpha[d * 8 + h] * xw[((size_t)(pk >> 2) * NREL + (pk & 3)) * HC + tid];
    }
    acc *= sinv[h];
    float v = acc + bias[tid];
    hout[(size_t)n * HC + tid] = (v > 0.f) ? v : 0.f;
}

// ---- final linear + tanh + mean-pool (atomic-free) -------------------------
__global__ __launch_bounds__(256) void k_pool2(const float* __restrict__ h3,
                                               const float* __restrict__ wlin,
                                               const float* __restrict__ blin,
                                               const int* __restrict__ batch,
                                               float* __restrict__ partials,
                                               int* __restrict__ gcnt, int nnodes) {
    int g = blockIdx.x / PCHUNK, chunk = blockIdx.x % PCHUNK;
    __shared__ int sb[2];
    if (threadIdx.x < 2) {
        int target = g + threadIdx.x;
        int lo = 0, hi = nnodes;
        while (lo < hi) { int mid = (lo + hi) >> 1; if (batch[mid] < target) lo = mid + 1; else hi = mid; }
        sb[threadIdx.x] = lo;
    }
    __syncthreads();
    int beg = sb[0], end = sb[1];
    int t = threadIdx.x;
    int w = t >> 6, lane = t & 63;
    int h = lane & 7, grp = lane >> 3;
    float rw[32];
#pragma unroll
    for (int k = 0; k < 8; ++k)
#pragma unroll
        for (int j = 0; j < 4; ++j)
            rw[k * 4 + j] = wlin[(grp * 4 + j + 32 * k) * HEADS + h];
    float bl = blin[h];
    float acc = 0.f;
    int wg = chunk * 4 + w;   // 0..31
    for (int n = beg + wg; n < end; n += PCHUNK * 4) {
        const float* row = h3 + (size_t)n * HC;
        float dot = 0.f;
#pragma unroll
        for (int k = 0; k < 8; ++k) {
            float4 v = *(const float4*)&row[grp * 4 + 32 * k];
            dot += v.x * rw[k * 4] + v.y * rw[k * 4 + 1] + v.z * rw[k * 4 + 2] + v.w * rw[k * 4 + 3];
        }
        dot += __shfl_xor(dot, 8, 64);
        dot += __shfl_xor(dot, 16, 64);
        dot += __shfl_xor(dot, 32, 64);
        acc += tanhf(dot + bl);
    }
    __shared__ float sacc[4][HEADS];
    if (lane < HEADS) sacc[w][h] = acc;
    __syncthreads();
    if (t < HEADS) {
        float s = sacc[0][t] + sacc[1][t] + sacc[2][t] + sacc[3][t];
        partials[(size_t)blockIdx.x * HEADS + t] = s;
    }
    if (t == 0 && chunk == 0) gcnt[g] = end - beg;
}

__global__ void k_div(const float* __restrict__ partials, const int* __restrict__ gcnt,
                      float* __restrict__ out, int ngraph) {
    int t = threadIdx.x;
    if (t < ngraph * HEADS) {
        int g = t >> 3, h = t & 7;
        float s = 0.f;
        for (int c = 0; c < PCHUNK; ++c) s += partials[(size_t)(g * PCHUNK + c) * HEADS + h];
        out[t] = s / fmaxf((float)gcnt[g], 1.f);
    }
}

// ---------------------------------------------------------------------------

extern "C" void kernel_launch(void* const* d_in, const int* in_sizes, int n_in,
                              void* d_out, int out_size, void* d_ws, size_t ws_size,
                              hipStream_t stream) {
    const float* x    = (const float*)d_in[0];
    const int*   ei   = (const int*)d_in[1];
    const int*   et   = (const int*)d_in[2];
    const float* ea   = (const float*)d_in[3];
    const int*   batch = (const int*)d_in[4];
    const float* W[3]  = {(const float*)d_in[5],  (const float*)d_in[11], (const float*)d_in[17]};
    const float* Q[3]  = {(const float*)d_in[6],  (const float*)d_in[12], (const float*)d_in[18]};
    const float* K[3]  = {(const float*)d_in[7],  (const float*)d_in[13], (const float*)d_in[19]};
    const float* Em[3] = {(const float*)d_in[8],  (const float*)d_in[14], (const float*)d_in[20]};
    const float* WE[3] = {(const float*)d_in[9],  (const float*)d_in[15], (const float*)d_in[21]};
    const float* B[3]  = {(const float*)d_in[10], (const float*)d_in[16], (const float*)d_in[22]};
    const float* wlin = (const float*)d_in[23];
    const float* blin = (const float*)d_in[24];

    int nnodes = in_sizes[0] / 32;
    int nedges = in_sizes[2];
    int ngraph = 16;

    char* ws = (char*)d_ws;
    size_t off = 0;
    auto alloc = [&](size_t bytes) -> void* {
        void* p = ws + off;
        off = (off + bytes + 255) & ~(size_t)255;
        return p;
    };
    int*   deg      = (int*)alloc((size_t)nnodes * 4);
    int*   fill     = (int*)alloc((size_t)nnodes * 4);
    int*   rowptr   = (int*)alloc((size_t)(nnodes + 1) * 4);
    int*   csr_pack = (int*)alloc((size_t)nedges * 4);
    float* csr_ae   = (float*)alloc((size_t)nedges * 4);
    float* xw       = (float*)alloc((size_t)nnodes * NREL * HC * 4);
    float* qdot     = (float*)alloc((size_t)nnodes * NREL * HEADS * 4);
    float* kdot     = (float*)alloc((size_t)nnodes * NREL * HEADS * 4);
    float* ha       = (float*)alloc((size_t)nnodes * HC * 4);
    float* hb       = (float*)alloc((size_t)nnodes * HC * 4);
    float* wqk      = (float*)alloc((size_t)HC * 48 * 4);
    float* wee      = (float*)alloc((size_t)HEADS * 4);
    float* partials = (float*)alloc((size_t)ngraph * PCHUNK * HEADS * 4);
    int*   gcnt     = (int*)alloc((size_t)ngraph * 4);
    (void)ws_size; (void)n_in; (void)out_size;

    // CSR build (edges are fixed across layers)
    k_init<<<(nnodes + 255) / 256, 256, 0, stream>>>(deg, fill, nnodes);
    k_deg<<<(nedges + 255) / 256, 256, 0, stream>>>(ei, deg, nedges);
    k_scan<<<1, 1024, 0, stream>>>(deg, rowptr, nnodes);
    k_scatter<<<(nedges + 255) / 256, 256, 0, stream>>>(ei, et, ea, rowptr, fill, csr_pack, csr_ae, nedges);

    dim3 ggemm((nnodes + 127) / 128, HC / 128, NREL);
    int gqk = (nnodes + 127) / 128;

    // ---- layer 1 (IN=32): x -> ha ----
    k_prep<<<NREL * 32, 256, 0, stream>>>(W[0], Q[0], K[0], Em[0], WE[0], wqk, wee, 32);
    k_qk<32><<<gqk, 256, 0, stream>>>(x, wqk, qdot, kdot, nnodes);
    k_gemm<32><<<ggemm, 256, 0, stream>>>(x, W[0], xw, nnodes);
    k_agg<<<nnodes, 256, 0, stream>>>(xw, qdot, kdot, rowptr, csr_pack, csr_ae, wee, B[0], ha, nnodes);

    // ---- layer 2 (IN=256): ha -> hb ----
    k_prep<<<NREL * HC, 256, 0, stream>>>(W[1], Q[1], K[1], Em[1], WE[1], wqk, wee, HC);
    k_qk<HC><<<gqk, 256, 0, stream>>>(ha, wqk, qdot, kdot, nnodes);
    k_gemm<HC><<<ggemm, 256, 0, stream>>>(ha, W[1], xw, nnodes);
    k_agg<<<nnodes, 256, 0, stream>>>(xw, qdot, kdot, rowptr, csr_pack, csr_ae, wee, B[1], hb, nnodes);

    // ---- layer 3 (IN=256): hb -> ha ----
    k_prep<<<NREL * HC, 256, 0, stream>>>(W[2], Q[2], K[2], Em[2], WE[2], wqk, wee, HC);
    k_qk<HC><<<gqk, 256, 0, stream>>>(hb, wqk, qdot, kdot, nnodes);
    k_gemm<HC><<<ggemm, 256, 0, stream>>>(hb, W[2], xw, nnodes);
    k_agg<<<nnodes, 256, 0, stream>>>(xw, qdot, kdot, rowptr, csr_pack, csr_ae, wee, B[2], ha, nnodes);

    // ---- head: linear + tanh + mean pool (atomic-free) ----
    k_pool2<<<ngraph * PCHUNK, 256, 0, stream>>>(ha, wlin, blin, batch, partials, gcnt, nnodes);
    k_div<<<1, 128, 0, stream>>>(partials, gcnt, (float*)d_out, ngraph);
}

// Round 11
// 564.318 us; speedup vs baseline: 1.6354x; 1.2051x over previous
//
#include <hip/hip_runtime.h>
#include <math.h>

#define HEADS 8
#define HC 256
#define NREL 3
#define NEG 0.2f
#define MAXDEG 128   // max in-degree; E=160k over N=10k dst -> mean 16, max ~45. 128 is hugely safe.
#define PCHUNK 8     // chunk-blocks per graph in the pool kernel

typedef float vfloat4 __attribute__((ext_vector_type(4)));  // native vec for nontemporal builtins
typedef short b16x8 __attribute__((ext_vector_type(8)));    // 8 bf16 (4 VGPRs) MFMA A/B frag
typedef float f32x4 __attribute__((ext_vector_type(4)));    // MFMA C/D frag

__device__ __forceinline__ float warp32_reduce(float p) {
#pragma unroll
    for (int off = 16; off > 0; off >>= 1) p += __shfl_down(p, off, 32);
    return p;
}

// fp32 -> bf16 split helpers (round-to-nearest-even)
__device__ __forceinline__ unsigned short f2bf(float f) {
    unsigned u = __float_as_uint(f);
    unsigned r = (u + 0x7FFFu + ((u >> 16) & 1u)) >> 16;
    return (unsigned short)r;
}
__device__ __forceinline__ float bf2f(unsigned short b) {
    return __uint_as_float(((unsigned)b) << 16);
}

// ---- CSR build -------------------------------------------------------------

__global__ void k_init(int* deg, int* fill, int nnodes) {
    int i = blockIdx.x * blockDim.x + threadIdx.x;
    if (i < nnodes) { deg[i] = 0; fill[i] = 0; }
}

__global__ void k_deg(const int* __restrict__ ei, int* deg, int nedges) {
    int e = blockIdx.x * blockDim.x + threadIdx.x;
    if (e < nedges) atomicAdd(&deg[ei[nedges + e]], 1);
}

// single-block exclusive scan over nnodes degrees -> rowptr[n+1]
__global__ void k_scan(const int* __restrict__ deg, int* rowptr, int n) {
    __shared__ int ss[1024];
    int tid = threadIdx.x;
    int per = (n + 1023) >> 10;
    int b = tid * per;
    int s = 0;
    for (int i = 0; i < per; i++) { int idx = b + i; if (idx < n) s += deg[idx]; }
    ss[tid] = s;
    __syncthreads();
    for (int off = 1; off < 1024; off <<= 1) {
        int v = (tid >= off) ? ss[tid - off] : 0;
        __syncthreads();
        ss[tid] += v;
        __syncthreads();
    }
    int run = (tid == 0) ? 0 : ss[tid - 1];
    for (int i = 0; i < per; i++) {
        int idx = b + i;
        if (idx < n) { rowptr[idx] = run; run += deg[idx]; }
    }
    if (tid == 0) rowptr[n] = ss[1023];
}

__global__ void k_scatter(const int* __restrict__ ei, const int* __restrict__ et,
                          const float* __restrict__ ea, const int* __restrict__ rowptr,
                          int* fill, int* csr_pack, float* csr_ae, int nedges) {
    int e = blockIdx.x * blockDim.x + threadIdx.x;
    if (e >= nedges) return;
    int dst = ei[nedges + e];
    int pos = atomicAdd(&fill[dst], 1);
    int slot = rowptr[dst] + pos;
    csr_pack[slot] = (ei[e] << 2) | (et[e] & 3);
    csr_ae[slot] = ea[e];
}

// ---- fp32 -> split-bf16 conversion -----------------------------------------

__global__ void k_cvt(const float* __restrict__ in, unsigned short* __restrict__ hi,
                      unsigned short* __restrict__ lo, int n) {
    int i = blockIdx.x * 256 + threadIdx.x;
    if (i < n) {
        float f = in[i];
        unsigned short h = f2bf(f);
        hi[i] = h;
        lo[i] = f2bf(f - bf2f(h));
    }
}

// W [r][k][c] fp32 -> transposed split-bf16 [r][c][k]. grid = NREL*K blocks, 256 thr (c).
__global__ void k_cvtw(const float* __restrict__ w, unsigned short* __restrict__ whi,
                       unsigned short* __restrict__ wlo, int K) {
    int b = blockIdx.x;
    int r = b / K, k = b - r * K;
    int c = threadIdx.x;
    float f = w[((size_t)r * K + k) * HC + c];
    unsigned short h = f2bf(f);
    size_t o = ((size_t)r * HC + c) * K + k;
    whi[o] = h;
    wlo[o] = f2bf(f - bf2f(h));
}

// ---- per-layer small precompute --------------------------------------------
// wqk[i][r*8+h]      = w[r,i,:] @ q[:,h]   (cols 0..23)
// wqk[i][24+r*8+h]   = w[r,i,:] @ k[:,h]   (cols 24..47)
// wee[h]             = we @ e[:,h]
__global__ void k_prep(const float* __restrict__ w, const float* __restrict__ q,
                       const float* __restrict__ kk, const float* __restrict__ e,
                       const float* __restrict__ we, float* wqk, float* wee, int IN) {
    int tid = threadIdx.x;
    int ri = blockIdx.x;  // r*IN + i
    int r = ri / IN, i = ri % IN;
    int h = tid >> 5, lane = tid & 31;
    const float* wrow = w + (size_t)ri * HC;
    float p = 0.f;
    for (int o = lane; o < HC; o += 32) p += wrow[o] * q[o * HEADS + h];
    p = warp32_reduce(p);
    if (lane == 0) wqk[i * 48 + r * 8 + h] = p;
    p = 0.f;
    for (int o = lane; o < HC; o += 32) p += wrow[o] * kk[o * HEADS + h];
    p = warp32_reduce(p);
    if (lane == 0) wqk[i * 48 + 24 + r * 8 + h] = p;
    if (blockIdx.x == 0 && tid < HEADS) {
        float s = 0.f;
        for (int o = 0; o < HC; o++) s += we[o] * e[o * HEADS + tid];
        wee[tid] = s;
    }
}

// ---- skinny GEMM for qdot/kdot: [nnodes x K] @ [K x 48] --------------------
template <int K>
__global__ __launch_bounds__(256) void k_qk(const float* __restrict__ xin,
                                            const float* __restrict__ wqk,
                                            float* __restrict__ qdot,
                                            float* __restrict__ kdot, int nnodes) {
    constexpr int BM = 128, BK = 32;
    __shared__ float xs[BK][BM];   // transposed x tile
    __shared__ float wt[BK][48];
    int n0 = blockIdx.x * BM;
    int t = threadIdx.x;
    int tx = t & 15, ty = t >> 4;
    int m0 = ty * 8, c0 = tx * 3;
    float acc[8][3];
#pragma unroll
    for (int i = 0; i < 8; i++)
#pragma unroll
        for (int j = 0; j < 3; j++) acc[i][j] = 0.f;
    int sm = t >> 1;
    int skq = (t & 1) * 16;
    for (int k0 = 0; k0 < K; k0 += BK) {
        int gn = n0 + sm;
        const float* xrow = xin + (size_t)gn * K + k0 + skq;
#pragma unroll
        for (int j = 0; j < 4; ++j) {
            float4 v = (gn < nnodes) ? *(const float4*)(xrow + 4 * j)
                                     : make_float4(0.f, 0.f, 0.f, 0.f);
            xs[skq + 4 * j + 0][sm] = v.x;
            xs[skq + 4 * j + 1][sm] = v.y;
            xs[skq + 4 * j + 2][sm] = v.z;
            xs[skq + 4 * j + 3][sm] = v.w;
        }
        for (int idx = t; idx < BK * 48; idx += 256) {
            int kk = idx / 48, c = idx % 48;
            wt[kk][c] = wqk[(size_t)(k0 + kk) * 48 + c];
        }
        __syncthreads();
#pragma unroll
        for (int kk = 0; kk < BK; ++kk) {
            float b0 = wt[kk][c0], b1 = wt[kk][c0 + 1], b2 = wt[kk][c0 + 2];
            float4 a0 = *(const float4*)&xs[kk][m0];
            float4 a1 = *(const float4*)&xs[kk][m0 + 4];
            float am[8] = {a0.x, a0.y, a0.z, a0.w, a1.x, a1.y, a1.z, a1.w};
#pragma unroll
            for (int i = 0; i < 8; i++) {
                acc[i][0] += am[i] * b0;
                acc[i][1] += am[i] * b1;
                acc[i][2] += am[i] * b2;
            }
        }
        __syncthreads();
    }
#pragma unroll
    for (int i = 0; i < 8; ++i) {
        int n = n0 + m0 + i;
        if (n < nnodes) {
#pragma unroll
            for (int j = 0; j < 3; ++j) {
                int c = c0 + j;
                if (c < 24) qdot[n * 24 + c] = acc[i][j];
                else        kdot[n * 24 + (c - 24)] = acc[i][j];
            }
        }
    }
}

// ---- split-bf16 MFMA GEMM: xw[n,r,:] = x[n,:] @ w[r] -----------------------
// x pre-split into (xhi,xlo) bf16 row-major [n][K]; W pre-split+transposed to
// [r][c][K]. Each lane's MFMA fragment (8 consecutive k) is ONE 16 B global
// load in exactly the HW A/B layout -> no LDS, no barriers. hi*hi + lo*hi +
// hi*lo (lo*lo dropped, ~2^-18 rel). Block = 16 nodes x 4 waves x 64 cols.
// Layouts per m89/m120: A[m=lane&15][k=quad*8+j]; B[k=quad*8+j][n=lane&15];
// D: col=lane&15, row=quad*4+reg.
template <int K>
__global__ __launch_bounds__(256) void k_mfma(const unsigned short* __restrict__ xhi,
                                              const unsigned short* __restrict__ xlo,
                                              const unsigned short* __restrict__ whi,
                                              const unsigned short* __restrict__ wlo,
                                              float* __restrict__ xw, int nnodes) {
    int n0 = blockIdx.x * 16;
    int r = blockIdx.y;
    int t = threadIdx.x;
    int wv = t >> 6, lane = t & 63;
    int q = lane >> 4, m = lane & 15;
    int c0 = wv * 64;
    const unsigned short* xhp = xhi + (size_t)(n0 + m) * K + q * 8;
    const unsigned short* xlp = xlo + (size_t)(n0 + m) * K + q * 8;
    const unsigned short* whr = whi + (size_t)r * HC * K;
    const unsigned short* wlr = wlo + (size_t)r * HC * K;
    f32x4 acc[4] = {};
    for (int k0 = 0; k0 < K; k0 += 32) {
        b16x8 ah = *(const b16x8*)(xhp + k0);
        b16x8 al = *(const b16x8*)(xlp + k0);
#pragma unroll
        for (int s = 0; s < 4; ++s) {
            int c = c0 + s * 16 + m;
            b16x8 vbh = *(const b16x8*)(whr + (size_t)c * K + k0 + q * 8);
            b16x8 vbl = *(const b16x8*)(wlr + (size_t)c * K + k0 + q * 8);
            acc[s] = __builtin_amdgcn_mfma_f32_16x16x32_bf16(ah, vbh, acc[s], 0, 0, 0);
            acc[s] = __builtin_amdgcn_mfma_f32_16x16x32_bf16(al, vbh, acc[s], 0, 0, 0);
            acc[s] = __builtin_amdgcn_mfma_f32_16x16x32_bf16(ah, vbl, acc[s], 0, 0, 0);
        }
    }
#pragma unroll
    for (int s = 0; s < 4; ++s) {
        int c = c0 + s * 16 + m;
#pragma unroll
        for (int g = 0; g < 4; ++g) {
            int n = n0 + q * 4 + g;
            if (n < nnodes) xw[((size_t)n * NREL + r) * HC + c] = acc[s][g];
        }
    }
}

// ---- per-dst-node attention softmax + aggregation + bias + relu ----
// Phase 3 unrolled x4 (4 outstanding gathers). Epilogue also emits the
// split-bf16 copy of the output for the next layer's MFMA.
__global__ void k_agg(const float* __restrict__ xw, const float* __restrict__ qdot,
                      const float* __restrict__ kdot, const int* __restrict__ rowptr,
                      const int* __restrict__ csr_pack, const float* __restrict__ csr_ae,
                      const float* __restrict__ wee, const float* __restrict__ bias,
                      float* __restrict__ hout, unsigned short* __restrict__ houthi,
                      unsigned short* __restrict__ houtlo, int nnodes) {
    __shared__ float salpha[MAXDEG * HEADS];
    __shared__ int spack[MAXDEG];
    __shared__ float sqd[NREL * HEADS];
    __shared__ float sinv[HEADS];
    __shared__ float swee[HEADS];
    int n = blockIdx.x;
    int tid = threadIdx.x;
    int beg = rowptr[n];
    int deg = rowptr[n + 1] - beg;
    if (deg > MAXDEG) deg = MAXDEG;
    if (tid < NREL * HEADS) sqd[tid] = qdot[n * 24 + tid];
    if (tid < HEADS) swee[tid] = wee[tid];
    __syncthreads();
    for (int base = 0; base < deg; base += 32) {
        int d = base + (tid >> 3);
        int h = tid & 7;
        if (d < deg) {
            int pk = csr_pack[beg + d];
            float ae = csr_ae[beg + d];
            int s = pk >> 2, t = pk & 3;
            if (h == 0) spack[d] = pk;
            float a = sqd[t * 8 + h] + kdot[s * 24 + t * 8 + h] + ae * swee[h];
            salpha[d * 8 + h] = (a > 0.f) ? a : NEG * a;
        }
    }
    __syncthreads();
    if (tid < HEADS) {
        int h = tid;
        float m = -INFINITY;
        for (int d = 0; d < deg; d++) m = fmaxf(m, salpha[d * 8 + h]);
        float s = 0.f;
        for (int d = 0; d < deg; d++) {
            float ex = expf(salpha[d * 8 + h] - m);
            salpha[d * 8 + h] = ex;
            s += ex;
        }
        sinv[h] = 1.f / (s + 1e-16f);
    }
    __syncthreads();
    int h = tid >> 5;
    float acc = 0.f;
    int d = 0;
    for (; d + 4 <= deg; d += 4) {
        int pk0 = spack[d + 0], pk1 = spack[d + 1];
        int pk2 = spack[d + 2], pk3 = spack[d + 3];
        const float* r0 = xw + ((size_t)(pk0 >> 2) * NREL + (pk0 & 3)) * HC + tid;
        const float* r1 = xw + ((size_t)(pk1 >> 2) * NREL + (pk1 & 3)) * HC + tid;
        const float* r2 = xw + ((size_t)(pk2 >> 2) * NREL + (pk2 & 3)) * HC + tid;
        const float* r3 = xw + ((size_t)(pk3 >> 2) * NREL + (pk3 & 3)) * HC + tid;
        float v0 = *r0, v1 = *r1, v2 = *r2, v3 = *r3;
        acc += salpha[(d + 0) * 8 + h] * v0;
        acc += salpha[(d + 1) * 8 + h] * v1;
        acc += salpha[(d + 2) * 8 + h] * v2;
        acc += salpha[(d + 3) * 8 + h] * v3;
    }
    for (; d < deg; ++d) {
        int pk = spack[d];
        acc += salpha[d * 8 + h] * xw[((size_t)(pk >> 2) * NREL + (pk & 3)) * HC + tid];
    }
    acc *= sinv[h];
    float v = acc + bias[tid];
    v = (v > 0.f) ? v : 0.f;
    size_t o = (size_t)n * HC + tid;
    hout[o] = v;
    unsigned short hh = f2bf(v);
    houthi[o] = hh;
    houtlo[o] = f2bf(v - bf2f(hh));
}

// ---- final linear + tanh + mean-pool (atomic-free) -------------------------
__global__ __launch_bounds__(256) void k_pool2(const float* __restrict__ h3,
                                               const float* __restrict__ wlin,
                                               const float* __restrict__ blin,
                                               const int* __restrict__ batch,
                                               float* __restrict__ partials,
                                               int* __restrict__ gcnt, int nnodes) {
    int g = blockIdx.x / PCHUNK, chunk = blockIdx.x % PCHUNK;
    __shared__ int sb[2];
    if (threadIdx.x < 2) {
        int target = g + threadIdx.x;
        int lo = 0, hi = nnodes;
        while (lo < hi) { int mid = (lo + hi) >> 1; if (batch[mid] < target) lo = mid + 1; else hi = mid; }
        sb[threadIdx.x] = lo;
    }
    __syncthreads();
    int beg = sb[0], end = sb[1];
    int t = threadIdx.x;
    int w = t >> 6, lane = t & 63;
    int h = lane & 7, grp = lane >> 3;
    float rw[32];
#pragma unroll
    for (int k = 0; k < 8; ++k)
#pragma unroll
        for (int j = 0; j < 4; ++j)
            rw[k * 4 + j] = wlin[(grp * 4 + j + 32 * k) * HEADS + h];
    float bl = blin[h];
    float acc = 0.f;
    int wg = chunk * 4 + w;   // 0..31
    for (int n = beg + wg; n < end; n += PCHUNK * 4) {
        const float* row = h3 + (size_t)n * HC;
        float dot = 0.f;
#pragma unroll
        for (int k = 0; k < 8; ++k) {
            float4 v = *(const float4*)&row[grp * 4 + 32 * k];
            dot += v.x * rw[k * 4] + v.y * rw[k * 4 + 1] + v.z * rw[k * 4 + 2] + v.w * rw[k * 4 + 3];
        }
        dot += __shfl_xor(dot, 8, 64);
        dot += __shfl_xor(dot, 16, 64);
        dot += __shfl_xor(dot, 32, 64);
        acc += tanhf(dot + bl);
    }
    __shared__ float sacc[4][HEADS];
    if (lane < HEADS) sacc[w][h] = acc;
    __syncthreads();
    if (t < HEADS) {
        float s = sacc[0][t] + sacc[1][t] + sacc[2][t] + sacc[3][t];
        partials[(size_t)blockIdx.x * HEADS + t] = s;
    }
    if (t == 0 && chunk == 0) gcnt[g] = end - beg;
}

__global__ void k_div(const float* __restrict__ partials, const int* __restrict__ gcnt,
                      float* __restrict__ out, int ngraph) {
    int t = threadIdx.x;
    if (t < ngraph * HEADS) {
        int g = t >> 3, h = t & 7;
        float s = 0.f;
        for (int c = 0; c < PCHUNK; ++c) s += partials[(size_t)(g * PCHUNK + c) * HEADS + h];
        out[t] = s / fmaxf((float)gcnt[g], 1.f);
    }
}

// ---------------------------------------------------------------------------

extern "C" void kernel_launch(void* const* d_in, const int* in_sizes, int n_in,
                              void* d_out, int out_size, void* d_ws, size_t ws_size,
                              hipStream_t stream) {
    const float* x    = (const float*)d_in[0];
    const int*   ei   = (const int*)d_in[1];
    const int*   et   = (const int*)d_in[2];
    const float* ea   = (const float*)d_in[3];
    const int*   batch = (const int*)d_in[4];
    const float* W[3]  = {(const float*)d_in[5],  (const float*)d_in[11], (const float*)d_in[17]};
    const float* Q[3]  = {(const float*)d_in[6],  (const float*)d_in[12], (const float*)d_in[18]};
    const float* K[3]  = {(const float*)d_in[7],  (const float*)d_in[13], (const float*)d_in[19]};
    const float* Em[3] = {(const float*)d_in[8],  (const float*)d_in[14], (const float*)d_in[20]};
    const float* WE[3] = {(const float*)d_in[9],  (const float*)d_in[15], (const float*)d_in[21]};
    const float* B[3]  = {(const float*)d_in[10], (const float*)d_in[16], (const float*)d_in[22]};
    const float* wlin = (const float*)d_in[23];
    const float* blin = (const float*)d_in[24];

    int nnodes = in_sizes[0] / 32;
    int nedges = in_sizes[2];
    int ngraph = 16;
    int npad = (nnodes + 15) & ~15;

    char* ws = (char*)d_ws;
    size_t off = 0;
    auto alloc = [&](size_t bytes) -> void* {
        void* p = ws + off;
        off = (off + bytes + 255) & ~(size_t)255;
        return p;
    };
    int*   deg      = (int*)alloc((size_t)nnodes * 4);
    int*   fill     = (int*)alloc((size_t)nnodes * 4);
    int*   rowptr   = (int*)alloc((size_t)(nnodes + 1) * 4);
    int*   csr_pack = (int*)alloc((size_t)nedges * 4);
    float* csr_ae   = (float*)alloc((size_t)nedges * 4);
    float* xw       = (float*)alloc((size_t)npad * NREL * HC * 4);
    float* qdot     = (float*)alloc((size_t)nnodes * NREL * HEADS * 4);
    float* kdot     = (float*)alloc((size_t)nnodes * NREL * HEADS * 4);
    float* ha       = (float*)alloc((size_t)nnodes * HC * 4);
    float* hb       = (float*)alloc((size_t)nnodes * HC * 4);
    float* wqk      = (float*)alloc((size_t)HC * 48 * 4);
    float* wee      = (float*)alloc((size_t)HEADS * 4);
    float* partials = (float*)alloc((size_t)ngraph * PCHUNK * HEADS * 4);
    int*   gcnt     = (int*)alloc((size_t)ngraph * 4);
    unsigned short* x1hi = (unsigned short*)alloc((size_t)npad * 32 * 2);
    unsigned short* x1lo = (unsigned short*)alloc((size_t)npad * 32 * 2);
    unsigned short* hahi = (unsigned short*)alloc((size_t)npad * HC * 2);
    unsigned short* halo = (unsigned short*)alloc((size_t)npad * HC * 2);
    unsigned short* hbhi = (unsigned short*)alloc((size_t)npad * HC * 2);
    unsigned short* hblo = (unsigned short*)alloc((size_t)npad * HC * 2);
    unsigned short* wt1hi = (unsigned short*)alloc((size_t)NREL * HC * 32 * 2);
    unsigned short* wt1lo = (unsigned short*)alloc((size_t)NREL * HC * 32 * 2);
    unsigned short* wt2hi = (unsigned short*)alloc((size_t)NREL * HC * HC * 2);
    unsigned short* wt2lo = (unsigned short*)alloc((size_t)NREL * HC * HC * 2);
    unsigned short* wt3hi = (unsigned short*)alloc((size_t)NREL * HC * HC * 2);
    unsigned short* wt3lo = (unsigned short*)alloc((size_t)NREL * HC * HC * 2);
    (void)ws_size; (void)n_in; (void)out_size;

    // CSR build (edges are fixed across layers)
    k_init<<<(nnodes + 255) / 256, 256, 0, stream>>>(deg, fill, nnodes);
    k_deg<<<(nedges + 255) / 256, 256, 0, stream>>>(ei, deg, nedges);
    k_scan<<<1, 1024, 0, stream>>>(deg, rowptr, nnodes);
    k_scatter<<<(nedges + 255) / 256, 256, 0, stream>>>(ei, et, ea, rowptr, fill, csr_pack, csr_ae, nedges);

    // split-bf16 conversions (x once; W transposed+split once per layer)
    k_cvt<<<(nnodes * 32 + 255) / 256, 256, 0, stream>>>(x, x1hi, x1lo, nnodes * 32);
    k_cvtw<<<NREL * 32, 256, 0, stream>>>(W[0], wt1hi, wt1lo, 32);
    k_cvtw<<<NREL * HC, 256, 0, stream>>>(W[1], wt2hi, wt2lo, HC);
    k_cvtw<<<NREL * HC, 256, 0, stream>>>(W[2], wt3hi, wt3lo, HC);

    dim3 gmfma((nnodes + 15) / 16, NREL);
    int gqk = (nnodes + 127) / 128;

    // ---- layer 1 (IN=32): x -> ha ----
    k_prep<<<NREL * 32, 256, 0, stream>>>(W[0], Q[0], K[0], Em[0], WE[0], wqk, wee, 32);
    k_qk<32><<<gqk, 256, 0, stream>>>(x, wqk, qdot, kdot, nnodes);
    k_mfma<32><<<gmfma, 256, 0, stream>>>(x1hi, x1lo, wt1hi, wt1lo, xw, nnodes);
    k_agg<<<nnodes, 256, 0, stream>>>(xw, qdot, kdot, rowptr, csr_pack, csr_ae, wee, B[0], ha, hahi, halo, nnodes);

    // ---- layer 2 (IN=256): ha -> hb ----
    k_prep<<<NREL * HC, 256, 0, stream>>>(W[1], Q[1], K[1], Em[1], WE[1], wqk, wee, HC);
    k_qk<HC><<<gqk, 256, 0, stream>>>(ha, wqk, qdot, kdot, nnodes);
    k_mfma<HC><<<gmfma, 256, 0, stream>>>(hahi, halo, wt2hi, wt2lo, xw, nnodes);
    k_agg<<<nnodes, 256, 0, stream>>>(xw, qdot, kdot, rowptr, csr_pack, csr_ae, wee, B[1], hb, hbhi, hblo, nnodes);

    // ---- layer 3 (IN=256): hb -> ha ----
    k_prep<<<NREL * HC, 256, 0, stream>>>(W[2], Q[2], K[2], Em[2], WE[2], wqk, wee, HC);
    k_qk<HC><<<gqk, 256, 0, stream>>>(hb, wqk, qdot, kdot, nnodes);
    k_mfma<HC><<<gmfma, 256, 0, stream>>>(hbhi, hblo, wt3hi, wt3lo, xw, nnodes);
    k_agg<<<nnodes, 256, 0, stream>>>(xw, qdot, kdot, rowptr, csr_pack, csr_ae, wee, B[2], ha, hahi, halo, nnodes);

    // ---- head: linear + tanh + mean pool (atomic-free) ----
    k_pool2<<<ngraph * PCHUNK, 256, 0, stream>>>(ha, wlin, blin, batch, partials, gcnt, nnodes);
    k_div<<<1, 128, 0, stream>>>(partials, gcnt, (float*)d_out, ngraph);
}

// Round 12
// 471.989 us; speedup vs baseline: 1.9553x; 1.1956x over previous
//
#include <hip/hip_runtime.h>
#include <math.h>

#define HEADS 8
#define HC 256
#define NREL 3
#define NEG 0.2f
#define MAXDEG 128   // max in-degree; E=160k over N=10k dst -> mean 16, max ~45. 128 is hugely safe.
#define PCHUNK 8     // chunk-blocks per graph in the pool kernel

typedef float vfloat4 __attribute__((ext_vector_type(4)));  // native vec for nontemporal builtins
typedef short b16x8 __attribute__((ext_vector_type(8)));    // 8 bf16 (4 VGPRs) MFMA A/B frag
typedef float f32x4 __attribute__((ext_vector_type(4)));    // MFMA C/D frag

__device__ __forceinline__ float warp32_reduce(float p) {
#pragma unroll
    for (int off = 16; off > 0; off >>= 1) p += __shfl_down(p, off, 32);
    return p;
}

// fp32 -> bf16 split helpers (round-to-nearest-even)
__device__ __forceinline__ unsigned short f2bf(float f) {
    unsigned u = __float_as_uint(f);
    unsigned r = (u + 0x7FFFu + ((u >> 16) & 1u)) >> 16;
    return (unsigned short)r;
}
__device__ __forceinline__ float bf2f(unsigned short b) {
    return __uint_as_float(((unsigned)b) << 16);
}

// ---- CSR build -------------------------------------------------------------

__global__ void k_init(int* deg, int* fill, int nnodes) {
    int i = blockIdx.x * blockDim.x + threadIdx.x;
    if (i < nnodes) { deg[i] = 0; fill[i] = 0; }
}

__global__ void k_deg(const int* __restrict__ ei, int* deg, int nedges) {
    int e = blockIdx.x * blockDim.x + threadIdx.x;
    if (e < nedges) atomicAdd(&deg[ei[nedges + e]], 1);
}

// single-block exclusive scan over nnodes degrees -> rowptr[n+1]
__global__ void k_scan(const int* __restrict__ deg, int* rowptr, int n) {
    __shared__ int ss[1024];
    int tid = threadIdx.x;
    int per = (n + 1023) >> 10;
    int b = tid * per;
    int s = 0;
    for (int i = 0; i < per; i++) { int idx = b + i; if (idx < n) s += deg[idx]; }
    ss[tid] = s;
    __syncthreads();
    for (int off = 1; off < 1024; off <<= 1) {
        int v = (tid >= off) ? ss[tid - off] : 0;
        __syncthreads();
        ss[tid] += v;
        __syncthreads();
    }
    int run = (tid == 0) ? 0 : ss[tid - 1];
    for (int i = 0; i < per; i++) {
        int idx = b + i;
        if (idx < n) { rowptr[idx] = run; run += deg[idx]; }
    }
    if (tid == 0) rowptr[n] = ss[1023];
}

__global__ void k_scatter(const int* __restrict__ ei, const int* __restrict__ et,
                          const float* __restrict__ ea, const int* __restrict__ rowptr,
                          int* fill, int* csr_pack, float* csr_ae, int nedges) {
    int e = blockIdx.x * blockDim.x + threadIdx.x;
    if (e >= nedges) return;
    int dst = ei[nedges + e];
    int pos = atomicAdd(&fill[dst], 1);
    int slot = rowptr[dst] + pos;
    csr_pack[slot] = (ei[e] << 2) | (et[e] & 3);
    csr_ae[slot] = ea[e];
}

// ---- packed-layout conversions ---------------------------------------------
// MFMA 16x16x32 fragment layouts (m89/m120-verified): lane = q*16+m holds
// A[m][k=kb*32+q*8+j] / B[k][c=ct*16+m] for j=0..7. We pre-pack operands so
// each wave fragment is ONE contiguous 1KB load: addr = ((tile*KB+kb)*64+lane)*8+j.

// layer-1 x (K=32) -> packed split-bf16 A
__global__ void k_packa(const float* __restrict__ x, unsigned short* __restrict__ hi,
                        unsigned short* __restrict__ lo, int nnodes) {
    int i = blockIdx.x * 256 + threadIdx.x;   // n*32 + k
    if (i >= nnodes * 32) return;
    int n = i >> 5, k = i & 31;
    float f = x[i];
    unsigned short h = f2bf(f);
    int ntile = n >> 4, m = n & 15;
    int q = (k >> 3) & 3, j = k & 7;          // kb = 0 (K=32)
    size_t o = ((size_t)ntile * 64 + q * 16 + m) * 8 + j;
    hi[o] = h;
    lo[o] = f2bf(f - bf2f(h));
}

// W [r][k][c] fp32 -> packed split-bf16 B: [r][ct][kb][lane][8]
__global__ void k_cvtw(const float* __restrict__ w, unsigned short* __restrict__ whi,
                       unsigned short* __restrict__ wlo, int K) {
    int b = blockIdx.x;       // r*K + k
    int r = b / K, k = b - r * K;
    int c = threadIdx.x;
    float f = w[((size_t)r * K + k) * HC + c];
    unsigned short h = f2bf(f);
    int ct = c >> 4, mc = c & 15;
    int kb = k >> 5, q = (k >> 3) & 3, j = k & 7;
    size_t o = ((((size_t)r * (HC / 16) + ct) * (K / 32) + kb) * 64 + q * 16 + mc) * 8 + j;
    whi[o] = h;
    wlo[o] = f2bf(f - bf2f(h));
}

// ---- per-layer small precompute --------------------------------------------
__global__ void k_prep(const float* __restrict__ w, const float* __restrict__ q,
                       const float* __restrict__ kk, const float* __restrict__ e,
                       const float* __restrict__ we, float* wqk, float* wee, int IN) {
    int tid = threadIdx.x;
    int ri = blockIdx.x;  // r*IN + i
    int r = ri / IN, i = ri % IN;
    int h = tid >> 5, lane = tid & 31;
    const float* wrow = w + (size_t)ri * HC;
    float p = 0.f;
    for (int o = lane; o < HC; o += 32) p += wrow[o] * q[o * HEADS + h];
    p = warp32_reduce(p);
    if (lane == 0) wqk[i * 48 + r * 8 + h] = p;
    p = 0.f;
    for (int o = lane; o < HC; o += 32) p += wrow[o] * kk[o * HEADS + h];
    p = warp32_reduce(p);
    if (lane == 0) wqk[i * 48 + 24 + r * 8 + h] = p;
    if (blockIdx.x == 0 && tid < HEADS) {
        float s = 0.f;
        for (int o = 0; o < HC; o++) s += we[o] * e[o * HEADS + tid];
        wee[tid] = s;
    }
}

// ---- skinny GEMM for qdot/kdot: [nnodes x K] @ [K x 48] --------------------
template <int K>
__global__ __launch_bounds__(256) void k_qk(const float* __restrict__ xin,
                                            const float* __restrict__ wqk,
                                            float* __restrict__ qdot,
                                            float* __restrict__ kdot, int nnodes) {
    constexpr int BM = 128, BK = 32;
    __shared__ float xs[BK][BM];   // transposed x tile
    __shared__ float wt[BK][48];
    int n0 = blockIdx.x * BM;
    int t = threadIdx.x;
    int tx = t & 15, ty = t >> 4;
    int m0 = ty * 8, c0 = tx * 3;
    float acc[8][3];
#pragma unroll
    for (int i = 0; i < 8; i++)
#pragma unroll
        for (int j = 0; j < 3; j++) acc[i][j] = 0.f;
    int sm = t >> 1;
    int skq = (t & 1) * 16;
    for (int k0 = 0; k0 < K; k0 += BK) {
        int gn = n0 + sm;
        const float* xrow = xin + (size_t)gn * K + k0 + skq;
#pragma unroll
        for (int j = 0; j < 4; ++j) {
            float4 v = (gn < nnodes) ? *(const float4*)(xrow + 4 * j)
                                     : make_float4(0.f, 0.f, 0.f, 0.f);
            xs[skq + 4 * j + 0][sm] = v.x;
            xs[skq + 4 * j + 1][sm] = v.y;
            xs[skq + 4 * j + 2][sm] = v.z;
            xs[skq + 4 * j + 3][sm] = v.w;
        }
        for (int idx = t; idx < BK * 48; idx += 256) {
            int kk = idx / 48, c = idx % 48;
            wt[kk][c] = wqk[(size_t)(k0 + kk) * 48 + c];
        }
        __syncthreads();
#pragma unroll
        for (int kk = 0; kk < BK; ++kk) {
            float b0 = wt[kk][c0], b1 = wt[kk][c0 + 1], b2 = wt[kk][c0 + 2];
            float4 a0 = *(const float4*)&xs[kk][m0];
            float4 a1 = *(const float4*)&xs[kk][m0 + 4];
            float am[8] = {a0.x, a0.y, a0.z, a0.w, a1.x, a1.y, a1.z, a1.w};
#pragma unroll
            for (int i = 0; i < 8; i++) {
                acc[i][0] += am[i] * b0;
                acc[i][1] += am[i] * b1;
                acc[i][2] += am[i] * b2;
            }
        }
        __syncthreads();
    }
#pragma unroll
    for (int i = 0; i < 8; ++i) {
        int n = n0 + m0 + i;
        if (n < nnodes) {
#pragma unroll
            for (int j = 0; j < 3; ++j) {
                int c = c0 + j;
                if (c < 24) qdot[n * 24 + c] = acc[i][j];
                else        kdot[n * 24 + (c - 24)] = acc[i][j];
            }
        }
    }
}

// ---- split-bf16 MFMA GEMM on packed operands -------------------------------
// All A/B fragment loads are contiguous 1KB wave-loads (lane*16B). No LDS, no
// barriers. hi*hi + lo*hi + hi*lo (lo*lo dropped, ~2^-18 rel).
template <int K>
__global__ __launch_bounds__(256) void k_mfma(const unsigned short* __restrict__ pahi,
                                              const unsigned short* __restrict__ palo,
                                              const unsigned short* __restrict__ pbhi,
                                              const unsigned short* __restrict__ pblo,
                                              float* __restrict__ xw, int nnodes) {
    constexpr int KB = K / 32;
    int nt = blockIdx.x;           // 16-node tile
    int r = blockIdx.y;
    int t = threadIdx.x;
    int wv = t >> 6, lane = t & 63;
    int q = lane >> 4, m = lane & 15;
    const unsigned short* pa_hi = pahi + ((size_t)nt * KB * 64 + lane) * 8;
    const unsigned short* pa_lo = palo + ((size_t)nt * KB * 64 + lane) * 8;
    const unsigned short* pb_hi = pbhi + (((size_t)r * (HC / 16) + wv * 4) * KB * 64 + lane) * 8;
    const unsigned short* pb_lo = pblo + (((size_t)r * (HC / 16) + wv * 4) * KB * 64 + lane) * 8;
    f32x4 acc[4] = {};
    for (int kb = 0; kb < KB; ++kb) {
        b16x8 ah = *(const b16x8*)(pa_hi + (size_t)kb * 512);
        b16x8 al = *(const b16x8*)(pa_lo + (size_t)kb * 512);
#pragma unroll
        for (int s = 0; s < 4; ++s) {
            b16x8 vbh = *(const b16x8*)(pb_hi + (size_t)(s * KB + kb) * 512);
            b16x8 vbl = *(const b16x8*)(pb_lo + (size_t)(s * KB + kb) * 512);
            acc[s] = __builtin_amdgcn_mfma_f32_16x16x32_bf16(ah, vbh, acc[s], 0, 0, 0);
            acc[s] = __builtin_amdgcn_mfma_f32_16x16x32_bf16(al, vbh, acc[s], 0, 0, 0);
            acc[s] = __builtin_amdgcn_mfma_f32_16x16x32_bf16(ah, vbl, acc[s], 0, 0, 0);
        }
    }
    int n0 = nt * 16;
    int c0 = wv * 64;
#pragma unroll
    for (int s = 0; s < 4; ++s) {
        int c = c0 + s * 16 + m;
#pragma unroll
        for (int g = 0; g < 4; ++g) {
            int n = n0 + q * 4 + g;
            if (n < nnodes) xw[((size_t)n * NREL + r) * HC + c] = acc[s][g];
        }
    }
}

// ---- per-dst-node attention softmax + aggregation + bias + relu ----
// Phase 3 unrolled x4. Epilogue emits fp32 output + packed split-bf16 A for
// the next layer's MFMA (K=256 layout: kb=tid>>5, q=(tid>>3)&3, j=tid&7).
__global__ void k_agg(const float* __restrict__ xw, const float* __restrict__ qdot,
                      const float* __restrict__ kdot, const int* __restrict__ rowptr,
                      const int* __restrict__ csr_pack, const float* __restrict__ csr_ae,
                      const float* __restrict__ wee, const float* __restrict__ bias,
                      float* __restrict__ hout, unsigned short* __restrict__ houthi,
                      unsigned short* __restrict__ houtlo, int nnodes) {
    __shared__ float salpha[MAXDEG * HEADS];
    __shared__ int spack[MAXDEG];
    __shared__ float sqd[NREL * HEADS];
    __shared__ float sinv[HEADS];
    __shared__ float swee[HEADS];
    int n = blockIdx.x;
    int tid = threadIdx.x;
    int beg = rowptr[n];
    int deg = rowptr[n + 1] - beg;
    if (deg > MAXDEG) deg = MAXDEG;
    if (tid < NREL * HEADS) sqd[tid] = qdot[n * 24 + tid];
    if (tid < HEADS) swee[tid] = wee[tid];
    __syncthreads();
    for (int base = 0; base < deg; base += 32) {
        int d = base + (tid >> 3);
        int h = tid & 7;
        if (d < deg) {
            int pk = csr_pack[beg + d];
            float ae = csr_ae[beg + d];
            int s = pk >> 2, t = pk & 3;
            if (h == 0) spack[d] = pk;
            float a = sqd[t * 8 + h] + kdot[s * 24 + t * 8 + h] + ae * swee[h];
            salpha[d * 8 + h] = (a > 0.f) ? a : NEG * a;
        }
    }
    __syncthreads();
    if (tid < HEADS) {
        int h = tid;
        float m = -INFINITY;
        for (int d = 0; d < deg; d++) m = fmaxf(m, salpha[d * 8 + h]);
        float s = 0.f;
        for (int d = 0; d < deg; d++) {
            float ex = expf(salpha[d * 8 + h] - m);
            salpha[d * 8 + h] = ex;
            s += ex;
        }
        sinv[h] = 1.f / (s + 1e-16f);
    }
    __syncthreads();
    int h = tid >> 5;
    float acc = 0.f;
    int d = 0;
    for (; d + 4 <= deg; d += 4) {
        int pk0 = spack[d + 0], pk1 = spack[d + 1];
        int pk2 = spack[d + 2], pk3 = spack[d + 3];
        const float* r0 = xw + ((size_t)(pk0 >> 2) * NREL + (pk0 & 3)) * HC + tid;
        const float* r1 = xw + ((size_t)(pk1 >> 2) * NREL + (pk1 & 3)) * HC + tid;
        const float* r2 = xw + ((size_t)(pk2 >> 2) * NREL + (pk2 & 3)) * HC + tid;
        const float* r3 = xw + ((size_t)(pk3 >> 2) * NREL + (pk3 & 3)) * HC + tid;
        float v0 = *r0, v1 = *r1, v2 = *r2, v3 = *r3;
        acc += salpha[(d + 0) * 8 + h] * v0;
        acc += salpha[(d + 1) * 8 + h] * v1;
        acc += salpha[(d + 2) * 8 + h] * v2;
        acc += salpha[(d + 3) * 8 + h] * v3;
    }
    for (; d < deg; ++d) {
        int pk = spack[d];
        acc += salpha[d * 8 + h] * xw[((size_t)(pk >> 2) * NREL + (pk & 3)) * HC + tid];
    }
    acc *= sinv[h];
    float v = acc + bias[tid];
    v = (v > 0.f) ? v : 0.f;
    hout[(size_t)n * HC + tid] = v;
    // packed split-bf16 A write for next layer (K=256 -> KB=8)
    unsigned short hh = f2bf(v);
    int ntile = n >> 4, mm = n & 15;
    int kb = tid >> 5, q = (tid >> 3) & 3, j = tid & 7;
    size_t o2 = ((((size_t)ntile * 8 + kb) * 64) + q * 16 + mm) * 8 + j;
    houthi[o2] = hh;
    houtlo[o2] = f2bf(v - bf2f(hh));
}

// ---- final linear + tanh + mean-pool (atomic-free) -------------------------
__global__ __launch_bounds__(256) void k_pool2(const float* __restrict__ h3,
                                               const float* __restrict__ wlin,
                                               const float* __restrict__ blin,
                                               const int* __restrict__ batch,
                                               float* __restrict__ partials,
                                               int* __restrict__ gcnt, int nnodes) {
    int g = blockIdx.x / PCHUNK, chunk = blockIdx.x % PCHUNK;
    __shared__ int sb[2];
    if (threadIdx.x < 2) {
        int target = g + threadIdx.x;
        int lo = 0, hi = nnodes;
        while (lo < hi) { int mid = (lo + hi) >> 1; if (batch[mid] < target) lo = mid + 1; else hi = mid; }
        sb[threadIdx.x] = lo;
    }
    __syncthreads();
    int beg = sb[0], end = sb[1];
    int t = threadIdx.x;
    int w = t >> 6, lane = t & 63;
    int h = lane & 7, grp = lane >> 3;
    float rw[32];
#pragma unroll
    for (int k = 0; k < 8; ++k)
#pragma unroll
        for (int j = 0; j < 4; ++j)
            rw[k * 4 + j] = wlin[(grp * 4 + j + 32 * k) * HEADS + h];
    float bl = blin[h];
    float acc = 0.f;
    int wg = chunk * 4 + w;   // 0..31
    for (int n = beg + wg; n < end; n += PCHUNK * 4) {
        const float* row = h3 + (size_t)n * HC;
        float dot = 0.f;
#pragma unroll
        for (int k = 0; k < 8; ++k) {
            float4 v = *(const float4*)&row[grp * 4 + 32 * k];
            dot += v.x * rw[k * 4] + v.y * rw[k * 4 + 1] + v.z * rw[k * 4 + 2] + v.w * rw[k * 4 + 3];
        }
        dot += __shfl_xor(dot, 8, 64);
        dot += __shfl_xor(dot, 16, 64);
        dot += __shfl_xor(dot, 32, 64);
        acc += tanhf(dot + bl);
    }
    __shared__ float sacc[4][HEADS];
    if (lane < HEADS) sacc[w][h] = acc;
    __syncthreads();
    if (t < HEADS) {
        float s = sacc[0][t] + sacc[1][t] + sacc[2][t] + sacc[3][t];
        partials[(size_t)blockIdx.x * HEADS + t] = s;
    }
    if (t == 0 && chunk == 0) gcnt[g] = end - beg;
}

__global__ void k_div(const float* __restrict__ partials, const int* __restrict__ gcnt,
                      float* __restrict__ out, int ngraph) {
    int t = threadIdx.x;
    if (t < ngraph * HEADS) {
        int g = t >> 3, h = t & 7;
        float s = 0.f;
        for (int c = 0; c < PCHUNK; ++c) s += partials[(size_t)(g * PCHUNK + c) * HEADS + h];
        out[t] = s / fmaxf((float)gcnt[g], 1.f);
    }
}

// ---------------------------------------------------------------------------

extern "C" void kernel_launch(void* const* d_in, const int* in_sizes, int n_in,
                              void* d_out, int out_size, void* d_ws, size_t ws_size,
                              hipStream_t stream) {
    const float* x    = (const float*)d_in[0];
    const int*   ei   = (const int*)d_in[1];
    const int*   et   = (const int*)d_in[2];
    const float* ea   = (const float*)d_in[3];
    const int*   batch = (const int*)d_in[4];
    const float* W[3]  = {(const float*)d_in[5],  (const float*)d_in[11], (const float*)d_in[17]};
    const float* Q[3]  = {(const float*)d_in[6],  (const float*)d_in[12], (const float*)d_in[18]};
    const float* K[3]  = {(const float*)d_in[7],  (const float*)d_in[13], (const float*)d_in[19]};
    const float* Em[3] = {(const float*)d_in[8],  (const float*)d_in[14], (const float*)d_in[20]};
    const float* WE[3] = {(const float*)d_in[9],  (const float*)d_in[15], (const float*)d_in[21]};
    const float* B[3]  = {(const float*)d_in[10], (const float*)d_in[16], (const float*)d_in[22]};
    const float* wlin = (const float*)d_in[23];
    const float* blin = (const float*)d_in[24];

    int nnodes = in_sizes[0] / 32;
    int nedges = in_sizes[2];
    int ngraph = 16;
    int npad = (nnodes + 15) & ~15;

    char* ws = (char*)d_ws;
    size_t off = 0;
    auto alloc = [&](size_t bytes) -> void* {
        void* p = ws + off;
        off = (off + bytes + 255) & ~(size_t)255;
        return p;
    };
    int*   deg      = (int*)alloc((size_t)nnodes * 4);
    int*   fill     = (int*)alloc((size_t)nnodes * 4);
    int*   rowptr   = (int*)alloc((size_t)(nnodes + 1) * 4);
    int*   csr_pack = (int*)alloc((size_t)nedges * 4);
    float* csr_ae   = (float*)alloc((size_t)nedges * 4);
    float* xw       = (float*)alloc((size_t)npad * NREL * HC * 4);
    float* qdot     = (float*)alloc((size_t)nnodes * NREL * HEADS * 4);
    float* kdot     = (float*)alloc((size_t)nnodes * NREL * HEADS * 4);
    float* ha       = (float*)alloc((size_t)nnodes * HC * 4);
    float* hb       = (float*)alloc((size_t)nnodes * HC * 4);
    float* wqk      = (float*)alloc((size_t)HC * 48 * 4);
    float* wee      = (float*)alloc((size_t)HEADS * 4);
    float* partials = (float*)alloc((size_t)ngraph * PCHUNK * HEADS * 4);
    int*   gcnt     = (int*)alloc((size_t)ngraph * 4);
    unsigned short* x1hi = (unsigned short*)alloc((size_t)npad * 32 * 2);
    unsigned short* x1lo = (unsigned short*)alloc((size_t)npad * 32 * 2);
    unsigned short* hahi = (unsigned short*)alloc((size_t)npad * HC * 2);
    unsigned short* halo = (unsigned short*)alloc((size_t)npad * HC * 2);
    unsigned short* hbhi = (unsigned short*)alloc((size_t)npad * HC * 2);
    unsigned short* hblo = (unsigned short*)alloc((size_t)npad * HC * 2);
    unsigned short* wt1hi = (unsigned short*)alloc((size_t)NREL * HC * 32 * 2);
    unsigned short* wt1lo = (unsigned short*)alloc((size_t)NREL * HC * 32 * 2);
    unsigned short* wt2hi = (unsigned short*)alloc((size_t)NREL * HC * HC * 2);
    unsigned short* wt2lo = (unsigned short*)alloc((size_t)NREL * HC * HC * 2);
    unsigned short* wt3hi = (unsigned short*)alloc((size_t)NREL * HC * HC * 2);
    unsigned short* wt3lo = (unsigned short*)alloc((size_t)NREL * HC * HC * 2);
    (void)ws_size; (void)n_in; (void)out_size;

    // CSR build (edges are fixed across layers)
    k_init<<<(nnodes + 255) / 256, 256, 0, stream>>>(deg, fill, nnodes);
    k_deg<<<(nedges + 255) / 256, 256, 0, stream>>>(ei, deg, nedges);
    k_scan<<<1, 1024, 0, stream>>>(deg, rowptr, nnodes);
    k_scatter<<<(nedges + 255) / 256, 256, 0, stream>>>(ei, et, ea, rowptr, fill, csr_pack, csr_ae, nedges);

    // packed split-bf16 conversions (x once; W once per layer)
    k_packa<<<(nnodes * 32 + 255) / 256, 256, 0, stream>>>(x, x1hi, x1lo, nnodes);
    k_cvtw<<<NREL * 32, 256, 0, stream>>>(W[0], wt1hi, wt1lo, 32);
    k_cvtw<<<NREL * HC, 256, 0, stream>>>(W[1], wt2hi, wt2lo, HC);
    k_cvtw<<<NREL * HC, 256, 0, stream>>>(W[2], wt3hi, wt3lo, HC);

    dim3 gmfma((nnodes + 15) / 16, NREL);
    int gqk = (nnodes + 127) / 128;

    // ---- layer 1 (IN=32): x -> ha ----
    k_prep<<<NREL * 32, 256, 0, stream>>>(W[0], Q[0], K[0], Em[0], WE[0], wqk, wee, 32);
    k_qk<32><<<gqk, 256, 0, stream>>>(x, wqk, qdot, kdot, nnodes);
    k_mfma<32><<<gmfma, 256, 0, stream>>>(x1hi, x1lo, wt1hi, wt1lo, xw, nnodes);
    k_agg<<<nnodes, 256, 0, stream>>>(xw, qdot, kdot, rowptr, csr_pack, csr_ae, wee, B[0], ha, hahi, halo, nnodes);

    // ---- layer 2 (IN=256): ha -> hb ----
    k_prep<<<NREL * HC, 256, 0, stream>>>(W[1], Q[1], K[1], Em[1], WE[1], wqk, wee, HC);
    k_qk<HC><<<gqk, 256, 0, stream>>>(ha, wqk, qdot, kdot, nnodes);
    k_mfma<HC><<<gmfma, 256, 0, stream>>>(hahi, halo, wt2hi, wt2lo, xw, nnodes);
    k_agg<<<nnodes, 256, 0, stream>>>(xw, qdot, kdot, rowptr, csr_pack, csr_ae, wee, B[1], hb, hbhi, hblo, nnodes);

    // ---- layer 3 (IN=256): hb -> ha ----
    k_prep<<<NREL * HC, 256, 0, stream>>>(W[2], Q[2], K[2], Em[2], WE[2], wqk, wee, HC);
    k_qk<HC><<<gqk, 256, 0, stream>>>(hb, wqk, qdot, kdot, nnodes);
    k_mfma<HC><<<gmfma, 256, 0, stream>>>(hbhi, hblo, wt3hi, wt3lo, xw, nnodes);
    k_agg<<<nnodes, 256, 0, stream>>>(xw, qdot, kdot, rowptr, csr_pack, csr_ae, wee, B[2], ha, hahi, halo, nnodes);

    // ---- head: linear + tanh + mean pool (atomic-free) ----
    k_pool2<<<ngraph * PCHUNK, 256, 0, stream>>>(ha, wlin, blin, batch, partials, gcnt, nnodes);
    k_div<<<1, 128, 0, stream>>>(partials, gcnt, (float*)d_out, ngraph);
}

// Round 13
// 469.286 us; speedup vs baseline: 1.9665x; 1.0058x over previous
//
#include <hip/hip_runtime.h>
#include <math.h>

#define HEADS 8
#define HC 256
#define NREL 3
#define NEG 0.2f
#define MAXDEG 128   // max in-degree; E=160k over N=10k dst -> mean 16, max ~45. 128 is hugely safe.
#define PCHUNK 8     // chunk-blocks per graph in the pool kernel

typedef float vfloat4 __attribute__((ext_vector_type(4)));  // native vec for nontemporal builtins
typedef short b16x8 __attribute__((ext_vector_type(8)));    // 8 bf16 (4 VGPRs) MFMA A/B frag
typedef float f32x4 __attribute__((ext_vector_type(4)));    // MFMA C/D frag

__device__ __forceinline__ float warp32_reduce(float p) {
#pragma unroll
    for (int off = 16; off > 0; off >>= 1) p += __shfl_down(p, off, 32);
    return p;
}

// fp32 -> bf16 split helpers (round-to-nearest-even)
__device__ __forceinline__ unsigned short f2bf(float f) {
    unsigned u = __float_as_uint(f);
    unsigned r = (u + 0x7FFFu + ((u >> 16) & 1u)) >> 16;
    return (unsigned short)r;
}
__device__ __forceinline__ float bf2f(unsigned short b) {
    return __uint_as_float(((unsigned)b) << 16);
}

// ---- CSR build -------------------------------------------------------------

__global__ void k_init(int* deg, int* fill, int nnodes) {
    int i = blockIdx.x * blockDim.x + threadIdx.x;
    if (i < nnodes) { deg[i] = 0; fill[i] = 0; }
}

__global__ void k_deg(const int* __restrict__ ei, int* deg, int nedges) {
    int e = blockIdx.x * blockDim.x + threadIdx.x;
    if (e < nedges) atomicAdd(&deg[ei[nedges + e]], 1);
}

// single-block exclusive scan over nnodes degrees -> rowptr[n+1]
__global__ void k_scan(const int* __restrict__ deg, int* rowptr, int n) {
    __shared__ int ss[1024];
    int tid = threadIdx.x;
    int per = (n + 1023) >> 10;
    int b = tid * per;
    int s = 0;
    for (int i = 0; i < per; i++) { int idx = b + i; if (idx < n) s += deg[idx]; }
    ss[tid] = s;
    __syncthreads();
    for (int off = 1; off < 1024; off <<= 1) {
        int v = (tid >= off) ? ss[tid - off] : 0;
        __syncthreads();
        ss[tid] += v;
        __syncthreads();
    }
    int run = (tid == 0) ? 0 : ss[tid - 1];
    for (int i = 0; i < per; i++) {
        int idx = b + i;
        if (idx < n) { rowptr[idx] = run; run += deg[idx]; }
    }
    if (tid == 0) rowptr[n] = ss[1023];
}

__global__ void k_scatter(const int* __restrict__ ei, const int* __restrict__ et,
                          const float* __restrict__ ea, const int* __restrict__ rowptr,
                          int* fill, int* csr_pack, float* csr_ae, int nedges) {
    int e = blockIdx.x * blockDim.x + threadIdx.x;
    if (e >= nedges) return;
    int dst = ei[nedges + e];
    int pos = atomicAdd(&fill[dst], 1);
    int slot = rowptr[dst] + pos;
    csr_pack[slot] = (ei[e] << 2) | (et[e] & 3);
    csr_ae[slot] = ea[e];
}

// ---- packed-layout conversions ---------------------------------------------
// MFMA 16x16x32 fragment layouts (m89/m120-verified): lane = q*16+m holds
// A[m][k=kb*32+q*8+j] / B[k][c=ct*16+m] for j=0..7. We pre-pack operands so
// each wave fragment is ONE contiguous 1KB load: addr = ((tile*KB+kb)*64+lane)*8+j.

// layer-1 x (K=32) -> packed split-bf16 A
__global__ void k_packa(const float* __restrict__ x, unsigned short* __restrict__ hi,
                        unsigned short* __restrict__ lo, int nnodes) {
    int i = blockIdx.x * 256 + threadIdx.x;   // n*32 + k
    if (i >= nnodes * 32) return;
    int n = i >> 5, k = i & 31;
    float f = x[i];
    unsigned short h = f2bf(f);
    int ntile = n >> 4, m = n & 15;
    int q = (k >> 3) & 3, j = k & 7;          // kb = 0 (K=32)
    size_t o = ((size_t)ntile * 64 + q * 16 + m) * 8 + j;
    hi[o] = h;
    lo[o] = f2bf(f - bf2f(h));
}

// W [r][k][c] fp32 -> packed split-bf16 B: [r][ct][kb][lane][8]
__global__ void k_cvtw(const float* __restrict__ w, unsigned short* __restrict__ whi,
                       unsigned short* __restrict__ wlo, int K) {
    int b = blockIdx.x;       // r*K + k
    int r = b / K, k = b - r * K;
    int c = threadIdx.x;
    float f = w[((size_t)r * K + k) * HC + c];
    unsigned short h = f2bf(f);
    int ct = c >> 4, mc = c & 15;
    int kb = k >> 5, q = (k >> 3) & 3, j = k & 7;
    size_t o = ((((size_t)r * (HC / 16) + ct) * (K / 32) + kb) * 64 + q * 16 + mc) * 8 + j;
    whi[o] = h;
    wlo[o] = f2bf(f - bf2f(h));
}

// ---- per-layer small precompute --------------------------------------------
__global__ void k_prep(const float* __restrict__ w, const float* __restrict__ q,
                       const float* __restrict__ kk, const float* __restrict__ e,
                       const float* __restrict__ we, float* wqk, float* wee, int IN) {
    int tid = threadIdx.x;
    int ri = blockIdx.x;  // r*IN + i
    int r = ri / IN, i = ri % IN;
    int h = tid >> 5, lane = tid & 31;
    const float* wrow = w + (size_t)ri * HC;
    float p = 0.f;
    for (int o = lane; o < HC; o += 32) p += wrow[o] * q[o * HEADS + h];
    p = warp32_reduce(p);
    if (lane == 0) wqk[i * 48 + r * 8 + h] = p;
    p = 0.f;
    for (int o = lane; o < HC; o += 32) p += wrow[o] * kk[o * HEADS + h];
    p = warp32_reduce(p);
    if (lane == 0) wqk[i * 48 + 24 + r * 8 + h] = p;
    if (blockIdx.x == 0 && tid < HEADS) {
        float s = 0.f;
        for (int o = 0; o < HC; o++) s += we[o] * e[o * HEADS + tid];
        wee[tid] = s;
    }
}

// ---- skinny GEMM for qdot/kdot: [nnodes x K] @ [K x 48] --------------------
template <int K>
__global__ __launch_bounds__(256) void k_qk(const float* __restrict__ xin,
                                            const float* __restrict__ wqk,
                                            float* __restrict__ qdot,
                                            float* __restrict__ kdot, int nnodes) {
    constexpr int BM = 128, BK = 32;
    __shared__ float xs[BK][BM];   // transposed x tile
    __shared__ float wt[BK][48];
    int n0 = blockIdx.x * BM;
    int t = threadIdx.x;
    int tx = t & 15, ty = t >> 4;
    int m0 = ty * 8, c0 = tx * 3;
    float acc[8][3];
#pragma unroll
    for (int i = 0; i < 8; i++)
#pragma unroll
        for (int j = 0; j < 3; j++) acc[i][j] = 0.f;
    int sm = t >> 1;
    int skq = (t & 1) * 16;
    for (int k0 = 0; k0 < K; k0 += BK) {
        int gn = n0 + sm;
        const float* xrow = xin + (size_t)gn * K + k0 + skq;
#pragma unroll
        for (int j = 0; j < 4; ++j) {
            float4 v = (gn < nnodes) ? *(const float4*)(xrow + 4 * j)
                                     : make_float4(0.f, 0.f, 0.f, 0.f);
            xs[skq + 4 * j + 0][sm] = v.x;
            xs[skq + 4 * j + 1][sm] = v.y;
            xs[skq + 4 * j + 2][sm] = v.z;
            xs[skq + 4 * j + 3][sm] = v.w;
        }
        for (int idx = t; idx < BK * 48; idx += 256) {
            int kk = idx / 48, c = idx % 48;
            wt[kk][c] = wqk[(size_t)(k0 + kk) * 48 + c];
        }
        __syncthreads();
#pragma unroll
        for (int kk = 0; kk < BK; ++kk) {
            float b0 = wt[kk][c0], b1 = wt[kk][c0 + 1], b2 = wt[kk][c0 + 2];
            float4 a0 = *(const float4*)&xs[kk][m0];
            float4 a1 = *(const float4*)&xs[kk][m0 + 4];
            float am[8] = {a0.x, a0.y, a0.z, a0.w, a1.x, a1.y, a1.z, a1.w};
#pragma unroll
            for (int i = 0; i < 8; i++) {
                acc[i][0] += am[i] * b0;
                acc[i][1] += am[i] * b1;
                acc[i][2] += am[i] * b2;
            }
        }
        __syncthreads();
    }
#pragma unroll
    for (int i = 0; i < 8; ++i) {
        int n = n0 + m0 + i;
        if (n < nnodes) {
#pragma unroll
            for (int j = 0; j < 3; ++j) {
                int c = c0 + j;
                if (c < 24) qdot[n * 24 + c] = acc[i][j];
                else        kdot[n * 24 + (c - 24)] = acc[i][j];
            }
        }
    }
}

// ---- split-bf16 MFMA GEMM on packed operands -------------------------------
// All A/B fragment loads are contiguous 1KB wave-loads (lane*16B). No LDS, no
// barriers. hi*hi + lo*hi + hi*lo (lo*lo dropped, ~2^-18 rel).
template <int K>
__global__ __launch_bounds__(256) void k_mfma(const unsigned short* __restrict__ pahi,
                                              const unsigned short* __restrict__ palo,
                                              const unsigned short* __restrict__ pbhi,
                                              const unsigned short* __restrict__ pblo,
                                              float* __restrict__ xw, int nnodes) {
    constexpr int KB = K / 32;
    int nt = blockIdx.x;           // 16-node tile
    int r = blockIdx.y;
    int t = threadIdx.x;
    int wv = t >> 6, lane = t & 63;
    int q = lane >> 4, m = lane & 15;
    const unsigned short* pa_hi = pahi + ((size_t)nt * KB * 64 + lane) * 8;
    const unsigned short* pa_lo = palo + ((size_t)nt * KB * 64 + lane) * 8;
    const unsigned short* pb_hi = pbhi + (((size_t)r * (HC / 16) + wv * 4) * KB * 64 + lane) * 8;
    const unsigned short* pb_lo = pblo + (((size_t)r * (HC / 16) + wv * 4) * KB * 64 + lane) * 8;
    f32x4 acc[4] = {};
    for (int kb = 0; kb < KB; ++kb) {
        b16x8 ah = *(const b16x8*)(pa_hi + (size_t)kb * 512);
        b16x8 al = *(const b16x8*)(pa_lo + (size_t)kb * 512);
#pragma unroll
        for (int s = 0; s < 4; ++s) {
            b16x8 vbh = *(const b16x8*)(pb_hi + (size_t)(s * KB + kb) * 512);
            b16x8 vbl = *(const b16x8*)(pb_lo + (size_t)(s * KB + kb) * 512);
            acc[s] = __builtin_amdgcn_mfma_f32_16x16x32_bf16(ah, vbh, acc[s], 0, 0, 0);
            acc[s] = __builtin_amdgcn_mfma_f32_16x16x32_bf16(al, vbh, acc[s], 0, 0, 0);
            acc[s] = __builtin_amdgcn_mfma_f32_16x16x32_bf16(ah, vbl, acc[s], 0, 0, 0);
        }
    }
    int n0 = nt * 16;
    int c0 = wv * 64;
#pragma unroll
    for (int s = 0; s < 4; ++s) {
        int c = c0 + s * 16 + m;
#pragma unroll
        for (int g = 0; g < 4; ++g) {
            int n = n0 + q * 4 + g;
            if (n < nnodes) xw[((size_t)n * NREL + r) * HC + c] = acc[s][g];
        }
    }
}

// ---- per-dst-node attention softmax + aggregation + bias + relu ----
// Phase 3: wave-per-edge gather — one wave loads one full 1KB xw row per
// instruction (lane l reads float4 at col 4l; head = l>>3). 4 waves stride the
// edge list, x2 unroll -> 2 outstanding 1KB loads/wave. LDS cross-wave combine.
__global__ void k_agg(const float* __restrict__ xw, const float* __restrict__ qdot,
                      const float* __restrict__ kdot, const int* __restrict__ rowptr,
                      const int* __restrict__ csr_pack, const float* __restrict__ csr_ae,
                      const float* __restrict__ wee, const float* __restrict__ bias,
                      float* __restrict__ hout, unsigned short* __restrict__ houthi,
                      unsigned short* __restrict__ houtlo, int nnodes) {
    __shared__ float salpha[MAXDEG * HEADS];
    __shared__ int spack[MAXDEG];
    __shared__ float sqd[NREL * HEADS];
    __shared__ float sinv[HEADS];
    __shared__ float swee[HEADS];
    __shared__ float sacc[4][HC];
    int n = blockIdx.x;
    int tid = threadIdx.x;
    int beg = rowptr[n];
    int deg = rowptr[n + 1] - beg;
    if (deg > MAXDEG) deg = MAXDEG;
    if (tid < NREL * HEADS) sqd[tid] = qdot[n * 24 + tid];
    if (tid < HEADS) swee[tid] = wee[tid];
    __syncthreads();
    for (int base = 0; base < deg; base += 32) {
        int d = base + (tid >> 3);
        int h = tid & 7;
        if (d < deg) {
            int pk = csr_pack[beg + d];
            float ae = csr_ae[beg + d];
            int s = pk >> 2, t = pk & 3;
            if (h == 0) spack[d] = pk;
            float a = sqd[t * 8 + h] + kdot[s * 24 + t * 8 + h] + ae * swee[h];
            salpha[d * 8 + h] = (a > 0.f) ? a : NEG * a;
        }
    }
    __syncthreads();
    if (tid < HEADS) {
        int h = tid;
        float m = -INFINITY;
        for (int d = 0; d < deg; d++) m = fmaxf(m, salpha[d * 8 + h]);
        float s = 0.f;
        for (int d = 0; d < deg; d++) {
            float ex = expf(salpha[d * 8 + h] - m);
            salpha[d * 8 + h] = ex;
            s += ex;
        }
        sinv[h] = 1.f / (s + 1e-16f);
    }
    __syncthreads();
    // phase 3: wave-per-edge full-row float4 gather
    int wv = tid >> 6, lane = tid & 63;
    int hsel = lane >> 3;   // head owning cols 4*lane..4*lane+3
    float4 acc4 = make_float4(0.f, 0.f, 0.f, 0.f);
    int d = wv;
    for (; d + 4 < deg; d += 8) {
        int pk0 = spack[d], pk1 = spack[d + 4];
        const float4* r0 = (const float4*)(xw + ((size_t)(pk0 >> 2) * NREL + (pk0 & 3)) * HC);
        const float4* r1 = (const float4*)(xw + ((size_t)(pk1 >> 2) * NREL + (pk1 & 3)) * HC);
        float4 v0 = r0[lane];
        float4 v1 = r1[lane];
        float a0 = salpha[d * 8 + hsel];
        float a1 = salpha[(d + 4) * 8 + hsel];
        acc4.x += a0 * v0.x + a1 * v1.x;
        acc4.y += a0 * v0.y + a1 * v1.y;
        acc4.z += a0 * v0.z + a1 * v1.z;
        acc4.w += a0 * v0.w + a1 * v1.w;
    }
    if (d < deg) {
        int pk = spack[d];
        const float4* r0 = (const float4*)(xw + ((size_t)(pk >> 2) * NREL + (pk & 3)) * HC);
        float4 v0 = r0[lane];
        float a0 = salpha[d * 8 + hsel];
        acc4.x += a0 * v0.x;
        acc4.y += a0 * v0.y;
        acc4.z += a0 * v0.z;
        acc4.w += a0 * v0.w;
    }
    *(float4*)&sacc[wv][lane * 4] = acc4;
    __syncthreads();
    float accv = sacc[0][tid] + sacc[1][tid] + sacc[2][tid] + sacc[3][tid];
    int h = tid >> 5;
    accv *= sinv[h];
    float v = accv + bias[tid];
    v = (v > 0.f) ? v : 0.f;
    hout[(size_t)n * HC + tid] = v;
    // packed split-bf16 A write for next layer (K=256 -> KB=8)
    unsigned short hh = f2bf(v);
    int ntile = n >> 4, mm = n & 15;
    int kb = tid >> 5, q = (tid >> 3) & 3, j = tid & 7;
    size_t o2 = ((((size_t)ntile * 8 + kb) * 64) + q * 16 + mm) * 8 + j;
    houthi[o2] = hh;
    houtlo[o2] = f2bf(v - bf2f(hh));
}

// ---- final linear + tanh + mean-pool (atomic-free) -------------------------
__global__ __launch_bounds__(256) void k_pool2(const float* __restrict__ h3,
                                               const float* __restrict__ wlin,
                                               const float* __restrict__ blin,
                                               const int* __restrict__ batch,
                                               float* __restrict__ partials,
                                               int* __restrict__ gcnt, int nnodes) {
    int g = blockIdx.x / PCHUNK, chunk = blockIdx.x % PCHUNK;
    __shared__ int sb[2];
    if (threadIdx.x < 2) {
        int target = g + threadIdx.x;
        int lo = 0, hi = nnodes;
        while (lo < hi) { int mid = (lo + hi) >> 1; if (batch[mid] < target) lo = mid + 1; else hi = mid; }
        sb[threadIdx.x] = lo;
    }
    __syncthreads();
    int beg = sb[0], end = sb[1];
    int t = threadIdx.x;
    int w = t >> 6, lane = t & 63;
    int h = lane & 7, grp = lane >> 3;
    float rw[32];
#pragma unroll
    for (int k = 0; k < 8; ++k)
#pragma unroll
        for (int j = 0; j < 4; ++j)
            rw[k * 4 + j] = wlin[(grp * 4 + j + 32 * k) * HEADS + h];
    float bl = blin[h];
    float acc = 0.f;
    int wg = chunk * 4 + w;   // 0..31
    for (int n = beg + wg; n < end; n += PCHUNK * 4) {
        const float* row = h3 + (size_t)n * HC;
        float dot = 0.f;
#pragma unroll
        for (int k = 0; k < 8; ++k) {
            float4 v = *(const float4*)&row[grp * 4 + 32 * k];
            dot += v.x * rw[k * 4] + v.y * rw[k * 4 + 1] + v.z * rw[k * 4 + 2] + v.w * rw[k * 4 + 3];
        }
        dot += __shfl_xor(dot, 8, 64);
        dot += __shfl_xor(dot, 16, 64);
        dot += __shfl_xor(dot, 32, 64);
        acc += tanhf(dot + bl);
    }
    __shared__ float sacc[4][HEADS];
    if (lane < HEADS) sacc[w][h] = acc;
    __syncthreads();
    if (t < HEADS) {
        float s = sacc[0][t] + sacc[1][t] + sacc[2][t] + sacc[3][t];
        partials[(size_t)blockIdx.x * HEADS + t] = s;
    }
    if (t == 0 && chunk == 0) gcnt[g] = end - beg;
}

__global__ void k_div(const float* __restrict__ partials, const int* __restrict__ gcnt,
                      float* __restrict__ out, int ngraph) {
    int t = threadIdx.x;
    if (t < ngraph * HEADS) {
        int g = t >> 3, h = t & 7;
        float s = 0.f;
        for (int c = 0; c < PCHUNK; ++c) s += partials[(size_t)(g * PCHUNK + c) * HEADS + h];
        out[t] = s / fmaxf((float)gcnt[g], 1.f);
    }
}

// ---------------------------------------------------------------------------

extern "C" void kernel_launch(void* const* d_in, const int* in_sizes, int n_in,
                              void* d_out, int out_size, void* d_ws, size_t ws_size,
                              hipStream_t stream) {
    const float* x    = (const float*)d_in[0];
    const int*   ei   = (const int*)d_in[1];
    const int*   et   = (const int*)d_in[2];
    const float* ea   = (const float*)d_in[3];
    const int*   batch = (const int*)d_in[4];
    const float* W[3]  = {(const float*)d_in[5],  (const float*)d_in[11], (const float*)d_in[17]};
    const float* Q[3]  = {(const float*)d_in[6],  (const float*)d_in[12], (const float*)d_in[18]};
    const float* K[3]  = {(const float*)d_in[7],  (const float*)d_in[13], (const float*)d_in[19]};
    const float* Em[3] = {(const float*)d_in[8],  (const float*)d_in[14], (const float*)d_in[20]};
    const float* WE[3] = {(const float*)d_in[9],  (const float*)d_in[15], (const float*)d_in[21]};
    const float* B[3]  = {(const float*)d_in[10], (const float*)d_in[16], (const float*)d_in[22]};
    const float* wlin = (const float*)d_in[23];
    const float* blin = (const float*)d_in[24];

    int nnodes = in_sizes[0] / 32;
    int nedges = in_sizes[2];
    int ngraph = 16;
    int npad = (nnodes + 15) & ~15;

    char* ws = (char*)d_ws;
    size_t off = 0;
    auto alloc = [&](size_t bytes) -> void* {
        void* p = ws + off;
        off = (off + bytes + 255) & ~(size_t)255;
        return p;
    };
    int*   deg      = (int*)alloc((size_t)nnodes * 4);
    int*   fill     = (int*)alloc((size_t)nnodes * 4);
    int*   rowptr   = (int*)alloc((size_t)(nnodes + 1) * 4);
    int*   csr_pack = (int*)alloc((size_t)nedges * 4);
    float* csr_ae   = (float*)alloc((size_t)nedges * 4);
    float* xw       = (float*)alloc((size_t)npad * NREL * HC * 4);
    float* qdot     = (float*)alloc((size_t)nnodes * NREL * HEADS * 4);
    float* kdot     = (float*)alloc((size_t)nnodes * NREL * HEADS * 4);
    float* ha       = (float*)alloc((size_t)nnodes * HC * 4);
    float* hb       = (float*)alloc((size_t)nnodes * HC * 4);
    float* wqk      = (float*)alloc((size_t)HC * 48 * 4);
    float* wee      = (float*)alloc((size_t)HEADS * 4);
    float* partials = (float*)alloc((size_t)ngraph * PCHUNK * HEADS * 4);
    int*   gcnt     = (int*)alloc((size_t)ngraph * 4);
    unsigned short* x1hi = (unsigned short*)alloc((size_t)npad * 32 * 2);
    unsigned short* x1lo = (unsigned short*)alloc((size_t)npad * 32 * 2);
    unsigned short* hahi = (unsigned short*)alloc((size_t)npad * HC * 2);
    unsigned short* halo = (unsigned short*)alloc((size_t)npad * HC * 2);
    unsigned short* hbhi = (unsigned short*)alloc((size_t)npad * HC * 2);
    unsigned short* hblo = (unsigned short*)alloc((size_t)npad * HC * 2);
    unsigned short* wt1hi = (unsigned short*)alloc((size_t)NREL * HC * 32 * 2);
    unsigned short* wt1lo = (unsigned short*)alloc((size_t)NREL * HC * 32 * 2);
    unsigned short* wt2hi = (unsigned short*)alloc((size_t)NREL * HC * HC * 2);
    unsigned short* wt2lo = (unsigned short*)alloc((size_t)NREL * HC * HC * 2);
    unsigned short* wt3hi = (unsigned short*)alloc((size_t)NREL * HC * HC * 2);
    unsigned short* wt3lo = (unsigned short*)alloc((size_t)NREL * HC * HC * 2);
    (void)ws_size; (void)n_in; (void)out_size;

    // CSR build (edges are fixed across layers)
    k_init<<<(nnodes + 255) / 256, 256, 0, stream>>>(deg, fill, nnodes);
    k_deg<<<(nedges + 255) / 256, 256, 0, stream>>>(ei, deg, nedges);
    k_scan<<<1, 1024, 0, stream>>>(deg, rowptr, nnodes);
    k_scatter<<<(nedges + 255) / 256, 256, 0, stream>>>(ei, et, ea, rowptr, fill, csr_pack, csr_ae, nedges);

    // packed split-bf16 conversions (x once; W once per layer)
    k_packa<<<(nnodes * 32 + 255) / 256, 256, 0, stream>>>(x, x1hi, x1lo, nnodes);
    k_cvtw<<<NREL * 32, 256, 0, stream>>>(W[0], wt1hi, wt1lo, 32);
    k_cvtw<<<NREL * HC, 256, 0, stream>>>(W[1], wt2hi, wt2lo, HC);
    k_cvtw<<<NREL * HC, 256, 0, stream>>>(W[2], wt3hi, wt3lo, HC);

    dim3 gmfma((nnodes + 15) / 16, NREL);
    int gqk = (nnodes + 127) / 128;

    // ---- layer 1 (IN=32): x -> ha ----
    k_prep<<<NREL * 32, 256, 0, stream>>>(W[0], Q[0], K[0], Em[0], WE[0], wqk, wee, 32);
    k_qk<32><<<gqk, 256, 0, stream>>>(x, wqk, qdot, kdot, nnodes);
    k_mfma<32><<<gmfma, 256, 0, stream>>>(x1hi, x1lo, wt1hi, wt1lo, xw, nnodes);
    k_agg<<<nnodes, 256, 0, stream>>>(xw, qdot, kdot, rowptr, csr_pack, csr_ae, wee, B[0], ha, hahi, halo, nnodes);

    // ---- layer 2 (IN=256): ha -> hb ----
    k_prep<<<NREL * HC, 256, 0, stream>>>(W[1], Q[1], K[1], Em[1], WE[1], wqk, wee, HC);
    k_qk<HC><<<gqk, 256, 0, stream>>>(ha, wqk, qdot, kdot, nnodes);
    k_mfma<HC><<<gmfma, 256, 0, stream>>>(hahi, halo, wt2hi, wt2lo, xw, nnodes);
    k_agg<<<nnodes, 256, 0, stream>>>(xw, qdot, kdot, rowptr, csr_pack, csr_ae, wee, B[1], hb, hbhi, hblo, nnodes);

    // ---- layer 3 (IN=256): hb -> ha ----
    k_prep<<<NREL * HC, 256, 0, stream>>>(W[2], Q[2], K[2], Em[2], WE[2], wqk, wee, HC);
    k_qk<HC><<<gqk, 256, 0, stream>>>(hb, wqk, qdot, kdot, nnodes);
    k_mfma<HC><<<gmfma, 256, 0, stream>>>(hbhi, hblo, wt3hi, wt3lo, xw, nnodes);
    k_agg<<<nnodes, 256, 0, stream>>>(xw, qdot, kdot, rowptr, csr_pack, csr_ae, wee, B[2], ha, hahi, halo, nnodes);

    // ---- head: linear + tanh + mean pool (atomic-free) ----
    k_pool2<<<ngraph * PCHUNK, 256, 0, stream>>>(ha, wlin, blin, batch, partials, gcnt, nnodes);
    k_div<<<1, 128, 0, stream>>>(partials, gcnt, (float*)d_out, ngraph);
}

// Round 14
// 389.490 us; speedup vs baseline: 2.3694x; 1.2049x over previous
//
#include <hip/hip_runtime.h>
#include <math.h>

#define HEADS 8
#define HC 256
#define NREL 3
#define NEG 0.2f
#define MAXDEG 128   // max in-degree; E=160k over N=10k dst -> mean 16, max ~45. 128 is hugely safe.
#define PCHUNK 8     // chunk-blocks per graph in the pool kernel
#define NCT 17       // packed-B ctiles per relation: 16 W-tiles + 1 qk-tile

typedef float vfloat4 __attribute__((ext_vector_type(4)));
typedef short b16x8 __attribute__((ext_vector_type(8)));    // 8 bf16 (4 VGPRs) MFMA A/B frag
typedef float f32x4 __attribute__((ext_vector_type(4)));    // MFMA C/D frag

__device__ __forceinline__ float warp32_reduce(float p) {
#pragma unroll
    for (int off = 16; off > 0; off >>= 1) p += __shfl_down(p, off, 32);
    return p;
}

// fp32 -> bf16 split helpers (round-to-nearest-even)
__device__ __forceinline__ unsigned short f2bf(float f) {
    unsigned u = __float_as_uint(f);
    unsigned r = (u + 0x7FFFu + ((u >> 16) & 1u)) >> 16;
    return (unsigned short)r;
}
__device__ __forceinline__ float bf2f(unsigned short b) {
    return __uint_as_float(((unsigned)b) << 16);
}

// ---- CSR build -------------------------------------------------------------

__global__ void k_init(int* deg, int* fill, int nnodes) {
    int i = blockIdx.x * blockDim.x + threadIdx.x;
    if (i < nnodes) { deg[i] = 0; fill[i] = 0; }
}

__global__ void k_deg(const int* __restrict__ ei, int* deg, int nedges) {
    int e = blockIdx.x * blockDim.x + threadIdx.x;
    if (e < nedges) atomicAdd(&deg[ei[nedges + e]], 1);
}

__global__ void k_scan(const int* __restrict__ deg, int* rowptr, int n) {
    __shared__ int ss[1024];
    int tid = threadIdx.x;
    int per = (n + 1023) >> 10;
    int b = tid * per;
    int s = 0;
    for (int i = 0; i < per; i++) { int idx = b + i; if (idx < n) s += deg[idx]; }
    ss[tid] = s;
    __syncthreads();
    for (int off = 1; off < 1024; off <<= 1) {
        int v = (tid >= off) ? ss[tid - off] : 0;
        __syncthreads();
        ss[tid] += v;
        __syncthreads();
    }
    int run = (tid == 0) ? 0 : ss[tid - 1];
    for (int i = 0; i < per; i++) {
        int idx = b + i;
        if (idx < n) { rowptr[idx] = run; run += deg[idx]; }
    }
    if (tid == 0) rowptr[n] = ss[1023];
}

__global__ void k_scatter(const int* __restrict__ ei, const int* __restrict__ et,
                          const float* __restrict__ ea, const int* __restrict__ rowptr,
                          int* fill, int* csr_pack, float* csr_ae, int nedges) {
    int e = blockIdx.x * blockDim.x + threadIdx.x;
    if (e >= nedges) return;
    int dst = ei[nedges + e];
    int pos = atomicAdd(&fill[dst], 1);
    int slot = rowptr[dst] + pos;
    csr_pack[slot] = (ei[e] << 2) | (et[e] & 3);
    csr_ae[slot] = ea[e];
}

// ---- packed-layout conversions ---------------------------------------------
// Packed operand layouts (m89/m120-verified): lane=q*16+m holds
// A[m][k=kb*32+q*8+j]; B[k=kb*32+q*8+j][col=ct*16+m]. Offset formula:
//   A: ((ntile*KB + kb)*64 + lane)*8 + j
//   B: (((r*NCT + ct)*KB + kb)*64 + lane)*8 + j

// layer-1 x (K=32) -> packed split-bf16 A
__global__ void k_packa(const float* __restrict__ x, unsigned short* __restrict__ hi,
                        unsigned short* __restrict__ lo, int nnodes) {
    int i = blockIdx.x * 256 + threadIdx.x;   // n*32 + k
    if (i >= nnodes * 32) return;
    int n = i >> 5, k = i & 31;
    float f = x[i];
    unsigned short h = f2bf(f);
    int ntile = n >> 4, m = n & 15;
    int q = (k >> 3) & 3, j = k & 7;          // kb = 0 (K=32)
    size_t o = ((size_t)ntile * 64 + q * 16 + m) * 8 + j;
    hi[o] = h;
    lo[o] = f2bf(f - bf2f(h));
}

// all 3 layers' W -> packed split-bf16 B (ct 0..15), one dispatch.
// blocks: [0,96) layer1 (K=32), [96,864) layer2, [864,1632) layer3 (K=256).
__global__ void k_cvtw_all(const float* __restrict__ w1, const float* __restrict__ w2,
                           const float* __restrict__ w3,
                           unsigned short* __restrict__ b1hi, unsigned short* __restrict__ b1lo,
                           unsigned short* __restrict__ b2hi, unsigned short* __restrict__ b2lo,
                           unsigned short* __restrict__ b3hi, unsigned short* __restrict__ b3lo) {
    int bi = blockIdx.x;
    const float* w;
    unsigned short *bhi, *blo;
    int K;
    if (bi < NREL * 32) { w = w1; bhi = b1hi; blo = b1lo; K = 32; }
    else if (bi < NREL * 32 + NREL * HC) { bi -= NREL * 32; w = w2; bhi = b2hi; blo = b2lo; K = HC; }
    else { bi -= NREL * 32 + NREL * HC; w = w3; bhi = b3hi; blo = b3lo; K = HC; }
    int r = bi / K, k = bi - r * K;
    int c = threadIdx.x;
    float f = w[((size_t)r * K + k) * HC + c];
    unsigned short h = f2bf(f);
    int ct = c >> 4, mc = c & 15;
    int KB = K / 32;
    int kb = k >> 5, q = (k >> 3) & 3, j = k & 7;
    size_t o = ((((size_t)r * NCT + ct) * KB + kb) * 64 + q * 16 + mc) * 8 + j;
    bhi[o] = h;
    blo[o] = f2bf(f - bf2f(h));
}

// all 3 layers' q/k projections -> packed split-bf16 B ct16, + wee[3][8].
// ct16 cols: m=h -> q-dot col, m=8+h -> k-dot col (for relation r).
__global__ void k_prep_all(
    const float* __restrict__ W1, const float* __restrict__ Q1, const float* __restrict__ K1,
    const float* __restrict__ E1, const float* __restrict__ WE1,
    const float* __restrict__ W2, const float* __restrict__ Q2, const float* __restrict__ K2,
    const float* __restrict__ E2, const float* __restrict__ WE2,
    const float* __restrict__ W3, const float* __restrict__ Q3, const float* __restrict__ K3,
    const float* __restrict__ E3, const float* __restrict__ WE3,
    unsigned short* __restrict__ b1hi, unsigned short* __restrict__ b1lo,
    unsigned short* __restrict__ b2hi, unsigned short* __restrict__ b2lo,
    unsigned short* __restrict__ b3hi, unsigned short* __restrict__ b3lo,
    float* __restrict__ wee) {
    int bi = blockIdx.x;
    const float *w, *qm, *km, *em, *wem;
    unsigned short *bhi, *blo;
    int K, layer, lbi;
    if (bi < NREL * 32) {
        layer = 0; lbi = bi; K = 32;
        w = W1; qm = Q1; km = K1; em = E1; wem = WE1; bhi = b1hi; blo = b1lo;
    } else if (bi < NREL * 32 + NREL * HC) {
        layer = 1; lbi = bi - NREL * 32; K = HC;
        w = W2; qm = Q2; km = K2; em = E2; wem = WE2; bhi = b2hi; blo = b2lo;
    } else {
        layer = 2; lbi = bi - NREL * 32 - NREL * HC; K = HC;
        w = W3; qm = Q3; km = K3; em = E3; wem = WE3; bhi = b3hi; blo = b3lo;
    }
    int r = lbi / K, i = lbi - r * K;
    int tid = threadIdx.x;
    int h = tid >> 5, lane = tid & 31;
    const float* wrow = w + (size_t)lbi * HC;
    int KB = K / 32;
    int kb = i >> 5, qq = (i >> 3) & 3, j = i & 7;
    size_t base = (((size_t)r * NCT + 16) * KB + kb) * 512 + j;
    float p = 0.f;
    for (int o = lane; o < HC; o += 32) p += wrow[o] * qm[o * HEADS + h];
    p = warp32_reduce(p);
    if (lane == 0) {
        size_t o = base + (size_t)(qq * 16 + h) * 8;
        unsigned short hh = f2bf(p);
        bhi[o] = hh;
        blo[o] = f2bf(p - bf2f(hh));
    }
    p = 0.f;
    for (int o = lane; o < HC; o += 32) p += wrow[o] * km[o * HEADS + h];
    p = warp32_reduce(p);
    if (lane == 0) {
        size_t o = base + (size_t)(qq * 16 + 8 + h) * 8;
        unsigned short hh = f2bf(p);
        bhi[o] = hh;
        blo[o] = f2bf(p - bf2f(hh));
    }
    if (lbi == 0 && tid < HEADS) {
        float s = 0.f;
        for (int o = 0; o < HC; o++) s += wem[o] * em[o * HEADS + tid];
        wee[layer * HEADS + tid] = s;
    }
}

// ---- split-bf16 MFMA GEMM on packed operands (W cols + fused q/k dots) -----
// All fragment loads are contiguous 1KB wave-loads. No LDS, no barriers.
// hi*hi + lo*hi + hi*lo. Wave wv covers ctiles {wv, wv+4, wv+8, wv+12} (+ct16
// for wv==0). ct<16 -> xw; ct==16 -> qdot (m<8) / kdot (m>=8).
template <int K>
__global__ __launch_bounds__(256) void k_mfma(const unsigned short* __restrict__ pahi,
                                              const unsigned short* __restrict__ palo,
                                              const unsigned short* __restrict__ pbhi,
                                              const unsigned short* __restrict__ pblo,
                                              float* __restrict__ xw,
                                              float* __restrict__ qdot,
                                              float* __restrict__ kdot, int nnodes) {
    constexpr int KB = K / 32;
    int nt = blockIdx.x;           // 16-node tile
    int r = blockIdx.y;
    int t = threadIdx.x;
    int wv = t >> 6, lane = t & 63;
    int q = lane >> 4, m = lane & 15;
    const unsigned short* pa_hi = pahi + ((size_t)nt * KB * 64 + lane) * 8;
    const unsigned short* pa_lo = palo + ((size_t)nt * KB * 64 + lane) * 8;
    f32x4 acc[5] = {};
    for (int kb = 0; kb < KB; ++kb) {
        b16x8 ah = *(const b16x8*)(pa_hi + (size_t)kb * 512);
        b16x8 al = *(const b16x8*)(pa_lo + (size_t)kb * 512);
#pragma unroll
        for (int s = 0; s < 5; ++s) {
            int ct = wv + 4 * s;
            if (ct >= NCT) continue;   // wave-uniform
            size_t o = (((size_t)r * NCT + ct) * KB + kb) * 512 + (size_t)lane * 8;
            b16x8 vbh = *(const b16x8*)(pbhi + o);
            b16x8 vbl = *(const b16x8*)(pblo + o);
            acc[s] = __builtin_amdgcn_mfma_f32_16x16x32_bf16(ah, vbh, acc[s], 0, 0, 0);
            acc[s] = __builtin_amdgcn_mfma_f32_16x16x32_bf16(al, vbh, acc[s], 0, 0, 0);
            acc[s] = __builtin_amdgcn_mfma_f32_16x16x32_bf16(ah, vbl, acc[s], 0, 0, 0);
        }
    }
    int n0 = nt * 16;
#pragma unroll
    for (int s = 0; s < 5; ++s) {
        int ct = wv + 4 * s;
        if (ct >= NCT) continue;
        if (ct < 16) {
            int c = ct * 16 + m;
#pragma unroll
            for (int g = 0; g < 4; ++g) {
                int n = n0 + q * 4 + g;
                if (n < nnodes) xw[((size_t)n * NREL + r) * HC + c] = acc[s][g];
            }
        } else {
#pragma unroll
            for (int g = 0; g < 4; ++g) {
                int n = n0 + q * 4 + g;
                if (n < nnodes) {
                    if (m < 8) qdot[n * 24 + r * 8 + m] = acc[s][g];
                    else       kdot[n * 24 + r * 8 + (m - 8)] = acc[s][g];
                }
            }
        }
    }
}

// ---- per-dst-node attention softmax + aggregation + bias + relu ----
__global__ void k_agg(const float* __restrict__ xw, const float* __restrict__ qdot,
                      const float* __restrict__ kdot, const int* __restrict__ rowptr,
                      const int* __restrict__ csr_pack, const float* __restrict__ csr_ae,
                      const float* __restrict__ wee, const float* __restrict__ bias,
                      float* __restrict__ hout, unsigned short* __restrict__ houthi,
                      unsigned short* __restrict__ houtlo, int nnodes) {
    __shared__ float salpha[MAXDEG * HEADS];
    __shared__ int spack[MAXDEG];
    __shared__ float sqd[NREL * HEADS];
    __shared__ float sinv[HEADS];
    __shared__ float swee[HEADS];
    __shared__ float sacc[4][HC];
    int n = blockIdx.x;
    int tid = threadIdx.x;
    int beg = rowptr[n];
    int deg = rowptr[n + 1] - beg;
    if (deg > MAXDEG) deg = MAXDEG;
    if (tid < NREL * HEADS) sqd[tid] = qdot[n * 24 + tid];
    if (tid < HEADS) swee[tid] = wee[tid];
    __syncthreads();
    for (int base = 0; base < deg; base += 32) {
        int d = base + (tid >> 3);
        int h = tid & 7;
        if (d < deg) {
            int pk = csr_pack[beg + d];
            float ae = csr_ae[beg + d];
            int s = pk >> 2, t = pk & 3;
            if (h == 0) spack[d] = pk;
            float a = sqd[t * 8 + h] + kdot[s * 24 + t * 8 + h] + ae * swee[h];
            salpha[d * 8 + h] = (a > 0.f) ? a : NEG * a;
        }
    }
    __syncthreads();
    if (tid < HEADS) {
        int h = tid;
        float m = -INFINITY;
        for (int d = 0; d < deg; d++) m = fmaxf(m, salpha[d * 8 + h]);
        float s = 0.f;
        for (int d = 0; d < deg; d++) {
            float ex = expf(salpha[d * 8 + h] - m);
            salpha[d * 8 + h] = ex;
            s += ex;
        }
        sinv[h] = 1.f / (s + 1e-16f);
    }
    __syncthreads();
    // phase 3: wave-per-edge full-row float4 gather
    int wv = tid >> 6, lane = tid & 63;
    int hsel = lane >> 3;
    float4 acc4 = make_float4(0.f, 0.f, 0.f, 0.f);
    int d = wv;
    for (; d + 4 < deg; d += 8) {
        int pk0 = spack[d], pk1 = spack[d + 4];
        const float4* r0 = (const float4*)(xw + ((size_t)(pk0 >> 2) * NREL + (pk0 & 3)) * HC);
        const float4* r1 = (const float4*)(xw + ((size_t)(pk1 >> 2) * NREL + (pk1 & 3)) * HC);
        float4 v0 = r0[lane];
        float4 v1 = r1[lane];
        float a0 = salpha[d * 8 + hsel];
        float a1 = salpha[(d + 4) * 8 + hsel];
        acc4.x += a0 * v0.x + a1 * v1.x;
        acc4.y += a0 * v0.y + a1 * v1.y;
        acc4.z += a0 * v0.z + a1 * v1.z;
        acc4.w += a0 * v0.w + a1 * v1.w;
    }
    if (d < deg) {
        int pk = spack[d];
        const float4* r0 = (const float4*)(xw + ((size_t)(pk >> 2) * NREL + (pk & 3)) * HC);
        float4 v0 = r0[lane];
        float a0 = salpha[d * 8 + hsel];
        acc4.x += a0 * v0.x;
        acc4.y += a0 * v0.y;
        acc4.z += a0 * v0.z;
        acc4.w += a0 * v0.w;
    }
    *(float4*)&sacc[wv][lane * 4] = acc4;
    __syncthreads();
    float accv = sacc[0][tid] + sacc[1][tid] + sacc[2][tid] + sacc[3][tid];
    int h = tid >> 5;
    accv *= sinv[h];
    float v = accv + bias[tid];
    v = (v > 0.f) ? v : 0.f;
    hout[(size_t)n * HC + tid] = v;
    // packed split-bf16 A write for next layer (K=256 -> KB=8)
    unsigned short hh = f2bf(v);
    int ntile = n >> 4, mm = n & 15;
    int kb = tid >> 5, q = (tid >> 3) & 3, j = tid & 7;
    size_t o2 = ((((size_t)ntile * 8 + kb) * 64) + q * 16 + mm) * 8 + j;
    houthi[o2] = hh;
    houtlo[o2] = f2bf(v - bf2f(hh));
}

// ---- final linear + tanh + mean-pool (atomic-free) -------------------------
__global__ __launch_bounds__(256) void k_pool2(const float* __restrict__ h3,
                                               const float* __restrict__ wlin,
                                               const float* __restrict__ blin,
                                               const int* __restrict__ batch,
                                               float* __restrict__ partials,
                                               int* __restrict__ gcnt, int nnodes) {
    int g = blockIdx.x / PCHUNK, chunk = blockIdx.x % PCHUNK;
    __shared__ int sb[2];
    if (threadIdx.x < 2) {
        int target = g + threadIdx.x;
        int lo = 0, hi = nnodes;
        while (lo < hi) { int mid = (lo + hi) >> 1; if (batch[mid] < target) lo = mid + 1; else hi = mid; }
        sb[threadIdx.x] = lo;
    }
    __syncthreads();
    int beg = sb[0], end = sb[1];
    int t = threadIdx.x;
    int w = t >> 6, lane = t & 63;
    int h = lane & 7, grp = lane >> 3;
    float rw[32];
#pragma unroll
    for (int k = 0; k < 8; ++k)
#pragma unroll
        for (int j = 0; j < 4; ++j)
            rw[k * 4 + j] = wlin[(grp * 4 + j + 32 * k) * HEADS + h];
    float bl = blin[h];
    float acc = 0.f;
    int wg = chunk * 4 + w;   // 0..31
    for (int n = beg + wg; n < end; n += PCHUNK * 4) {
        const float* row = h3 + (size_t)n * HC;
        float dot = 0.f;
#pragma unroll
        for (int k = 0; k < 8; ++k) {
            float4 v = *(const float4*)&row[grp * 4 + 32 * k];
            dot += v.x * rw[k * 4] + v.y * rw[k * 4 + 1] + v.z * rw[k * 4 + 2] + v.w * rw[k * 4 + 3];
        }
        dot += __shfl_xor(dot, 8, 64);
        dot += __shfl_xor(dot, 16, 64);
        dot += __shfl_xor(dot, 32, 64);
        acc += tanhf(dot + bl);
    }
    __shared__ float sacc[4][HEADS];
    if (lane < HEADS) sacc[w][h] = acc;
    __syncthreads();
    if (t < HEADS) {
        float s = sacc[0][t] + sacc[1][t] + sacc[2][t] + sacc[3][t];
        partials[(size_t)blockIdx.x * HEADS + t] = s;
    }
    if (t == 0 && chunk == 0) gcnt[g] = end - beg;
}

__global__ void k_div(const float* __restrict__ partials, const int* __restrict__ gcnt,
                      float* __restrict__ out, int ngraph) {
    int t = threadIdx.x;
    if (t < ngraph * HEADS) {
        int g = t >> 3, h = t & 7;
        float s = 0.f;
        for (int c = 0; c < PCHUNK; ++c) s += partials[(size_t)(g * PCHUNK + c) * HEADS + h];
        out[t] = s / fmaxf((float)gcnt[g], 1.f);
    }
}

// ---------------------------------------------------------------------------

extern "C" void kernel_launch(void* const* d_in, const int* in_sizes, int n_in,
                              void* d_out, int out_size, void* d_ws, size_t ws_size,
                              hipStream_t stream) {
    const float* x    = (const float*)d_in[0];
    const int*   ei   = (const int*)d_in[1];
    const int*   et   = (const int*)d_in[2];
    const float* ea   = (const float*)d_in[3];
    const int*   batch = (const int*)d_in[4];
    const float* W[3]  = {(const float*)d_in[5],  (const float*)d_in[11], (const float*)d_in[17]};
    const float* Q[3]  = {(const float*)d_in[6],  (const float*)d_in[12], (const float*)d_in[18]};
    const float* K[3]  = {(const float*)d_in[7],  (const float*)d_in[13], (const float*)d_in[19]};
    const float* Em[3] = {(const float*)d_in[8],  (const float*)d_in[14], (const float*)d_in[20]};
    const float* WE[3] = {(const float*)d_in[9],  (const float*)d_in[15], (const float*)d_in[21]};
    const float* B[3]  = {(const float*)d_in[10], (const float*)d_in[16], (const float*)d_in[22]};
    const float* wlin = (const float*)d_in[23];
    const float* blin = (const float*)d_in[24];

    int nnodes = in_sizes[0] / 32;
    int nedges = in_sizes[2];
    int ngraph = 16;
    int npad = (nnodes + 15) & ~15;

    char* ws = (char*)d_ws;
    size_t off = 0;
    auto alloc = [&](size_t bytes) -> void* {
        void* p = ws + off;
        off = (off + bytes + 255) & ~(size_t)255;
        return p;
    };
    int*   deg      = (int*)alloc((size_t)nnodes * 4);
    int*   fill     = (int*)alloc((size_t)nnodes * 4);
    int*   rowptr   = (int*)alloc((size_t)(nnodes + 1) * 4);
    int*   csr_pack = (int*)alloc((size_t)nedges * 4);
    float* csr_ae   = (float*)alloc((size_t)nedges * 4);
    float* xw       = (float*)alloc((size_t)npad * NREL * HC * 4);
    float* qdot     = (float*)alloc((size_t)npad * NREL * HEADS * 4);
    float* kdot     = (float*)alloc((size_t)npad * NREL * HEADS * 4);
    float* ha       = (float*)alloc((size_t)nnodes * HC * 4);
    float* hb       = (float*)alloc((size_t)nnodes * HC * 4);
    float* wee      = (float*)alloc((size_t)NREL * HEADS * 4);
    float* partials = (float*)alloc((size_t)ngraph * PCHUNK * HEADS * 4);
    int*   gcnt     = (int*)alloc((size_t)ngraph * 4);
    unsigned short* x1hi = (unsigned short*)alloc((size_t)npad * 32 * 2);
    unsigned short* x1lo = (unsigned short*)alloc((size_t)npad * 32 * 2);
    unsigned short* hahi = (unsigned short*)alloc((size_t)npad * HC * 2);
    unsigned short* halo = (unsigned short*)alloc((size_t)npad * HC * 2);
    unsigned short* hbhi = (unsigned short*)alloc((size_t)npad * HC * 2);
    unsigned short* hblo = (unsigned short*)alloc((size_t)npad * HC * 2);
    unsigned short* wt1hi = (unsigned short*)alloc((size_t)NREL * NCT * 1 * 512 * 2);
    unsigned short* wt1lo = (unsigned short*)alloc((size_t)NREL * NCT * 1 * 512 * 2);
    unsigned short* wt2hi = (unsigned short*)alloc((size_t)NREL * NCT * 8 * 512 * 2);
    unsigned short* wt2lo = (unsigned short*)alloc((size_t)NREL * NCT * 8 * 512 * 2);
    unsigned short* wt3hi = (unsigned short*)alloc((size_t)NREL * NCT * 8 * 512 * 2);
    unsigned short* wt3lo = (unsigned short*)alloc((size_t)NREL * NCT * 8 * 512 * 2);
    (void)ws_size; (void)n_in; (void)out_size;

    int nprep = NREL * 32 + 2 * NREL * HC;   // 1632

    // CSR build (edges are fixed across layers)
    k_init<<<(nnodes + 255) / 256, 256, 0, stream>>>(deg, fill, nnodes);
    k_deg<<<(nedges + 255) / 256, 256, 0, stream>>>(ei, deg, nedges);
    k_scan<<<1, 1024, 0, stream>>>(deg, rowptr, nnodes);
    k_scatter<<<(nedges + 255) / 256, 256, 0, stream>>>(ei, et, ea, rowptr, fill, csr_pack, csr_ae, nedges);

    // all weight prep upfront (packed split-bf16 B with fused qk ctile)
    k_packa<<<(nnodes * 32 + 255) / 256, 256, 0, stream>>>(x, x1hi, x1lo, nnodes);
    k_cvtw_all<<<nprep, 256, 0, stream>>>(W[0], W[1], W[2], wt1hi, wt1lo, wt2hi, wt2lo, wt3hi, wt3lo);
    k_prep_all<<<nprep, 256, 0, stream>>>(W[0], Q[0], K[0], Em[0], WE[0],
                                          W[1], Q[1], K[1], Em[1], WE[1],
                                          W[2], Q[2], K[2], Em[2], WE[2],
                                          wt1hi, wt1lo, wt2hi, wt2lo, wt3hi, wt3lo, wee);

    dim3 gmfma((nnodes + 15) / 16, NREL);

    // ---- layer 1 (IN=32): x -> ha ----
    k_mfma<32><<<gmfma, 256, 0, stream>>>(x1hi, x1lo, wt1hi, wt1lo, xw, qdot, kdot, nnodes);
    k_agg<<<nnodes, 256, 0, stream>>>(xw, qdot, kdot, rowptr, csr_pack, csr_ae, wee + 0, B[0], ha, hahi, halo, nnodes);

    // ---- layer 2 (IN=256): ha -> hb ----
    k_mfma<HC><<<gmfma, 256, 0, stream>>>(hahi, halo, wt2hi, wt2lo, xw, qdot, kdot, nnodes);
    k_agg<<<nnodes, 256, 0, stream>>>(xw, qdot, kdot, rowptr, csr_pack, csr_ae, wee + 8, B[1], hb, hbhi, hblo, nnodes);

    // ---- layer 3 (IN=256): hb -> ha ----
    k_mfma<HC><<<gmfma, 256, 0, stream>>>(hbhi, hblo, wt3hi, wt3lo, xw, qdot, kdot, nnodes);
    k_agg<<<nnodes, 256, 0, stream>>>(xw, qdot, kdot, rowptr, csr_pack, csr_ae, wee + 16, B[2], ha, hahi, halo, nnodes);

    // ---- head: linear + tanh + mean pool (atomic-free) ----
    k_pool2<<<ngraph * PCHUNK, 256, 0, stream>>>(ha, wlin, blin, batch, partials, gcnt, nnodes);
    k_div<<<1, 128, 0, stream>>>(partials, gcnt, (float*)d_out, ngraph);
}

// Round 15
// 364.068 us; speedup vs baseline: 2.5349x; 1.0698x over previous
//
#include <hip/hip_runtime.h>
#include <math.h>

#define HEADS 8
#define HC 256
#define NREL 3
#define NEG 0.2f
#define MAXDEG 128   // max in-degree; E=160k over N=10k dst -> mean 16, max ~45. 128 is hugely safe.
#define PCHUNK 8     // chunk-blocks per graph in the pool kernel
#define NCT 17       // packed-B ctiles per relation: 16 W-tiles + 1 qk-tile

typedef float vfloat4 __attribute__((ext_vector_type(4)));
typedef short b16x8 __attribute__((ext_vector_type(8)));    // 8 bf16 (4 VGPRs) MFMA A/B frag
typedef float f32x4 __attribute__((ext_vector_type(4)));    // MFMA C/D frag

__device__ __forceinline__ float warp32_reduce(float p) {
#pragma unroll
    for (int off = 16; off > 0; off >>= 1) p += __shfl_down(p, off, 32);
    return p;
}

// fp32 -> bf16 split helpers (round-to-nearest-even)
__device__ __forceinline__ unsigned short f2bf(float f) {
    unsigned u = __float_as_uint(f);
    unsigned r = (u + 0x7FFFu + ((u >> 16) & 1u)) >> 16;
    return (unsigned short)r;
}
__device__ __forceinline__ float bf2f(unsigned short b) {
    return __uint_as_float(((unsigned)b) << 16);
}

// ---- CSR build -------------------------------------------------------------

__global__ void k_init(int* deg, int* fill, int* ctr, int nnodes) {
    int i = blockIdx.x * blockDim.x + threadIdx.x;
    if (i < nnodes) { deg[i] = 0; fill[i] = 0; }
    if (i == 0) *ctr = 0;
}

__global__ void k_deg(const int* __restrict__ ei, int* deg, int nedges) {
    int e = blockIdx.x * blockDim.x + threadIdx.x;
    if (e < nedges) atomicAdd(&deg[ei[nedges + e]], 1);
}

__global__ void k_scan(const int* __restrict__ deg, int* rowptr, int n) {
    __shared__ int ss[1024];
    int tid = threadIdx.x;
    int per = (n + 1023) >> 10;
    int b = tid * per;
    int s = 0;
    for (int i = 0; i < per; i++) { int idx = b + i; if (idx < n) s += deg[idx]; }
    ss[tid] = s;
    __syncthreads();
    for (int off = 1; off < 1024; off <<= 1) {
        int v = (tid >= off) ? ss[tid - off] : 0;
        __syncthreads();
        ss[tid] += v;
        __syncthreads();
    }
    int run = (tid == 0) ? 0 : ss[tid - 1];
    for (int i = 0; i < per; i++) {
        int idx = b + i;
        if (idx < n) { rowptr[idx] = run; run += deg[idx]; }
    }
    if (tid == 0) rowptr[n] = ss[1023];
}

__global__ void k_scatter(const int* __restrict__ ei, const int* __restrict__ et,
                          const float* __restrict__ ea, const int* __restrict__ rowptr,
                          int* fill, int* csr_pack, float* csr_ae, int nedges) {
    int e = blockIdx.x * blockDim.x + threadIdx.x;
    if (e >= nedges) return;
    int dst = ei[nedges + e];
    int pos = atomicAdd(&fill[dst], 1);
    int slot = rowptr[dst] + pos;
    csr_pack[slot] = (ei[e] << 2) | (et[e] & 3);
    csr_ae[slot] = ea[e];
}

// ---- fused prep: pack x (A), convert all W (B ct0..15), q/k dots (B ct16) --
// Packed operand layouts (m89/m120-verified): lane=q*16+m holds
// A[m][k=kb*32+q*8+j]; B[k=kb*32+q*8+j][col=ct*16+m].
//   A offset: ((ntile*KB + kb)*64 + lane)*8 + j
//   B offset: (((r*NCT + ct)*KB + kb)*64 + lane)*8 + j
// blocks [0, nprep): W conversion + qk dots; [nprep, nprep+npacka): x packing.
__global__ void k_wprep(
    const float* __restrict__ W1, const float* __restrict__ Q1, const float* __restrict__ K1,
    const float* __restrict__ E1, const float* __restrict__ WE1,
    const float* __restrict__ W2, const float* __restrict__ Q2, const float* __restrict__ K2,
    const float* __restrict__ E2, const float* __restrict__ WE2,
    const float* __restrict__ W3, const float* __restrict__ Q3, const float* __restrict__ K3,
    const float* __restrict__ E3, const float* __restrict__ WE3,
    unsigned short* __restrict__ b1hi, unsigned short* __restrict__ b1lo,
    unsigned short* __restrict__ b2hi, unsigned short* __restrict__ b2lo,
    unsigned short* __restrict__ b3hi, unsigned short* __restrict__ b3lo,
    float* __restrict__ wee,
    const float* __restrict__ x, unsigned short* __restrict__ x1hi,
    unsigned short* __restrict__ x1lo, int nnodes, int nprep) {
    int bi = blockIdx.x;
    int tid = threadIdx.x;
    if (bi >= nprep) {
        // ---- packa part: layer-1 x (K=32) -> packed split-bf16 A ----
        int i = (bi - nprep) * 256 + tid;   // n*32 + k
        if (i < nnodes * 32) {
            int n = i >> 5, k = i & 31;
            float f = x[i];
            unsigned short h = f2bf(f);
            int ntile = n >> 4, m = n & 15;
            int q = (k >> 3) & 3, j = k & 7;      // kb = 0
            size_t o = ((size_t)ntile * 64 + q * 16 + m) * 8 + j;
            x1hi[o] = h;
            x1lo[o] = f2bf(f - bf2f(h));
        }
        return;
    }
    const float *w, *qm, *km, *em, *wem;
    unsigned short *bhi, *blo;
    int K, layer, lbi;
    if (bi < NREL * 32) {
        layer = 0; lbi = bi; K = 32;
        w = W1; qm = Q1; km = K1; em = E1; wem = WE1; bhi = b1hi; blo = b1lo;
    } else if (bi < NREL * 32 + NREL * HC) {
        layer = 1; lbi = bi - NREL * 32; K = HC;
        w = W2; qm = Q2; km = K2; em = E2; wem = WE2; bhi = b2hi; blo = b2lo;
    } else {
        layer = 2; lbi = bi - NREL * 32 - NREL * HC; K = HC;
        w = W3; qm = Q3; km = K3; em = E3; wem = WE3; bhi = b3hi; blo = b3lo;
    }
    int r = lbi / K, i = lbi - r * K;
    int KB = K / 32;
    int kb = i >> 5, qq = (i >> 3) & 3, j = i & 7;
    // ---- cvtw part: this W row -> B ct0..15 ----
    {
        int c = tid;
        float f = w[(size_t)lbi * HC + c];
        unsigned short h = f2bf(f);
        int ct = c >> 4, mc = c & 15;
        size_t o = ((((size_t)r * NCT + ct) * KB + kb) * 64 + qq * 16 + mc) * 8 + j;
        bhi[o] = h;
        blo[o] = f2bf(f - bf2f(h));
    }
    // ---- prep part: q/k dots -> B ct16 ----
    int h = tid >> 5, lane = tid & 31;
    const float* wrow = w + (size_t)lbi * HC;
    size_t base = (((size_t)r * NCT + 16) * KB + kb) * 512 + j;
    float p = 0.f;
    for (int o = lane; o < HC; o += 32) p += wrow[o] * qm[o * HEADS + h];
    p = warp32_reduce(p);
    if (lane == 0) {
        size_t o = base + (size_t)(qq * 16 + h) * 8;
        unsigned short hh = f2bf(p);
        bhi[o] = hh;
        blo[o] = f2bf(p - bf2f(hh));
    }
    p = 0.f;
    for (int o = lane; o < HC; o += 32) p += wrow[o] * km[o * HEADS + h];
    p = warp32_reduce(p);
    if (lane == 0) {
        size_t o = base + (size_t)(qq * 16 + 8 + h) * 8;
        unsigned short hh = f2bf(p);
        bhi[o] = hh;
        blo[o] = f2bf(p - bf2f(hh));
    }
    if (lbi == 0 && tid < HEADS) {
        float s = 0.f;
        for (int o = 0; o < HC; o++) s += wem[o] * em[o * HEADS + tid];
        wee[layer * HEADS + tid] = s;
    }
}

// ---- split-bf16 MFMA GEMM on packed operands (W cols + fused q/k dots) -----
template <int K>
__global__ __launch_bounds__(256) void k_mfma(const unsigned short* __restrict__ pahi,
                                              const unsigned short* __restrict__ palo,
                                              const unsigned short* __restrict__ pbhi,
                                              const unsigned short* __restrict__ pblo,
                                              float* __restrict__ xw,
                                              float* __restrict__ qdot,
                                              float* __restrict__ kdot, int nnodes) {
    constexpr int KB = K / 32;
    int nt = blockIdx.x;
    int r = blockIdx.y;
    int t = threadIdx.x;
    int wv = t >> 6, lane = t & 63;
    int q = lane >> 4, m = lane & 15;
    const unsigned short* pa_hi = pahi + ((size_t)nt * KB * 64 + lane) * 8;
    const unsigned short* pa_lo = palo + ((size_t)nt * KB * 64 + lane) * 8;
    f32x4 acc[5] = {};
    for (int kb = 0; kb < KB; ++kb) {
        b16x8 ah = *(const b16x8*)(pa_hi + (size_t)kb * 512);
        b16x8 al = *(const b16x8*)(pa_lo + (size_t)kb * 512);
#pragma unroll
        for (int s = 0; s < 5; ++s) {
            int ct = wv + 4 * s;
            if (ct >= NCT) continue;   // wave-uniform
            size_t o = (((size_t)r * NCT + ct) * KB + kb) * 512 + (size_t)lane * 8;
            b16x8 vbh = *(const b16x8*)(pbhi + o);
            b16x8 vbl = *(const b16x8*)(pblo + o);
            acc[s] = __builtin_amdgcn_mfma_f32_16x16x32_bf16(ah, vbh, acc[s], 0, 0, 0);
            acc[s] = __builtin_amdgcn_mfma_f32_16x16x32_bf16(al, vbh, acc[s], 0, 0, 0);
            acc[s] = __builtin_amdgcn_mfma_f32_16x16x32_bf16(ah, vbl, acc[s], 0, 0, 0);
        }
    }
    int n0 = nt * 16;
#pragma unroll
    for (int s = 0; s < 5; ++s) {
        int ct = wv + 4 * s;
        if (ct >= NCT) continue;
        if (ct < 16) {
            int c = ct * 16 + m;
#pragma unroll
            for (int g = 0; g < 4; ++g) {
                int n = n0 + q * 4 + g;
                if (n < nnodes) xw[((size_t)n * NREL + r) * HC + c] = acc[s][g];
            }
        } else {
#pragma unroll
            for (int g = 0; g < 4; ++g) {
                int n = n0 + q * 4 + g;
                if (n < nnodes) {
                    if (m < 8) qdot[n * 24 + r * 8 + m] = acc[s][g];
                    else       kdot[n * 24 + r * 8 + (m - 8)] = acc[s][g];
                }
            }
        }
    }
}

// ---- attention: wave-per-node, no block barriers ---------------------------
// 4 waves/block, each owns one dst node end-to-end. Phase 1: 8 edges x 8 heads
// per pass. Phase 2: head=lane&7, chunk=lane>>3, xor-shuffle combine. Phase 3:
// full-row float4 wave-gather (lane l = cols 4l..4l+3). Epilogue: bias+relu,
// fp32 out + packed split-bf16 A for next layer.
__global__ __launch_bounds__(256) void k_agg(const float* __restrict__ xw,
                      const float* __restrict__ qdot, const float* __restrict__ kdot,
                      const int* __restrict__ rowptr, const int* __restrict__ csr_pack,
                      const float* __restrict__ csr_ae, const float* __restrict__ wee,
                      const float* __restrict__ bias, float* __restrict__ hout,
                      unsigned short* __restrict__ houthi, unsigned short* __restrict__ houtlo,
                      int nnodes) {
    __shared__ float salpha[4][MAXDEG * HEADS];
    __shared__ int spack[4][MAXDEG];
    int wv = threadIdx.x >> 6, lane = threadIdx.x & 63;
    int n = blockIdx.x * 4 + wv;
    if (n >= nnodes) return;
    int beg = rowptr[n];
    int deg = rowptr[n + 1] - beg;
    if (deg > MAXDEG) deg = MAXDEG;
    float* sal = salpha[wv];
    int* spk = spack[wv];
    // phase 1
    {
        int h = lane & 7;
        float weeh = wee[h];
        const float* qdn = qdot + n * 24;
        for (int base = 0; base < deg; base += 8) {
            int d = base + (lane >> 3);
            if (d < deg) {
                int pk = csr_pack[beg + d];
                float ae = csr_ae[beg + d];
                int s = pk >> 2, t = pk & 3;
                if (h == 0) spk[d] = pk;
                float a = qdn[t * 8 + h] + kdot[s * 24 + t * 8 + h] + ae * weeh;
                sal[d * 8 + h] = (a > 0.f) ? a : NEG * a;
            }
        }
    }
    // phase 2: per-head softmax; lane = chunk*8 + head
    float sinv_h;
    {
        int h = lane & 7, c = lane >> 3;
        float m = -INFINITY;
        for (int d = c; d < deg; d += 8) m = fmaxf(m, sal[d * 8 + h]);
        m = fmaxf(m, __shfl_xor(m, 8, 64));
        m = fmaxf(m, __shfl_xor(m, 16, 64));
        m = fmaxf(m, __shfl_xor(m, 32, 64));
        float s = 0.f;
        for (int d = c; d < deg; d += 8) {
            float ex = expf(sal[d * 8 + h] - m);
            sal[d * 8 + h] = ex;
            s += ex;
        }
        s += __shfl_xor(s, 8, 64);
        s += __shfl_xor(s, 16, 64);
        s += __shfl_xor(s, 32, 64);
        sinv_h = 1.f / (s + 1e-16f);
    }
    // sinv for the head owning this lane's columns (head = lane>>3; src lane
    // (lane>>3) holds that head's sinv since its (lane&7) == lane>>3)
    float sinv_sel = __shfl(sinv_h, lane >> 3, 64);
    int hsel = lane >> 3;
    // phase 3: full-row wave gather, unroll x2
    float4 acc4 = make_float4(0.f, 0.f, 0.f, 0.f);
    int d = 0;
    for (; d + 1 < deg; d += 2) {
        int pk0 = spk[d], pk1 = spk[d + 1];
        const float4* r0 = (const float4*)(xw + ((size_t)(pk0 >> 2) * NREL + (pk0 & 3)) * HC);
        const float4* r1 = (const float4*)(xw + ((size_t)(pk1 >> 2) * NREL + (pk1 & 3)) * HC);
        float4 v0 = r0[lane];
        float4 v1 = r1[lane];
        float a0 = sal[d * 8 + hsel];
        float a1 = sal[(d + 1) * 8 + hsel];
        acc4.x += a0 * v0.x + a1 * v1.x;
        acc4.y += a0 * v0.y + a1 * v1.y;
        acc4.z += a0 * v0.z + a1 * v1.z;
        acc4.w += a0 * v0.w + a1 * v1.w;
    }
    if (d < deg) {
        int pk = spk[d];
        const float4* r0 = (const float4*)(xw + ((size_t)(pk >> 2) * NREL + (pk & 3)) * HC);
        float4 v0 = r0[lane];
        float a0 = sal[d * 8 + hsel];
        acc4.x += a0 * v0.x;
        acc4.y += a0 * v0.y;
        acc4.z += a0 * v0.z;
        acc4.w += a0 * v0.w;
    }
    // epilogue: cols c = 4*lane .. 4*lane+3
    float4 bv = *(const float4*)(bias + lane * 4);
    float4 v;
    v.x = fmaxf(acc4.x * sinv_sel + bv.x, 0.f);
    v.y = fmaxf(acc4.y * sinv_sel + bv.y, 0.f);
    v.z = fmaxf(acc4.z * sinv_sel + bv.z, 0.f);
    v.w = fmaxf(acc4.w * sinv_sel + bv.w, 0.f);
    *(float4*)(hout + (size_t)n * HC + lane * 4) = v;
    // packed split-bf16 A write for next layer (K=256 -> KB=8)
    int ntile = n >> 4, mm = n & 15;
    float vv[4] = {v.x, v.y, v.z, v.w};
#pragma unroll
    for (int i = 0; i < 4; ++i) {
        int c = lane * 4 + i;
        int kb = c >> 5, q = (c >> 3) & 3, j = c & 7;
        size_t o2 = ((((size_t)ntile * 8 + kb) * 64) + q * 16 + mm) * 8 + j;
        unsigned short hh = f2bf(vv[i]);
        houthi[o2] = hh;
        houtlo[o2] = f2bf(vv[i] - bf2f(hh));
    }
}

// ---- final linear + tanh + mean-pool + last-block divide -------------------
__global__ __launch_bounds__(256) void k_pool2(const float* __restrict__ h3,
                                               const float* __restrict__ wlin,
                                               const float* __restrict__ blin,
                                               const int* __restrict__ batch,
                                               float* __restrict__ partials,
                                               int* __restrict__ gcnt, int* __restrict__ ctr,
                                               float* __restrict__ out, int nnodes, int ngraph) {
    int g = blockIdx.x / PCHUNK, chunk = blockIdx.x % PCHUNK;
    __shared__ int sb[2];
    if (threadIdx.x < 2) {
        int target = g + threadIdx.x;
        int lo = 0, hi = nnodes;
        while (lo < hi) { int mid = (lo + hi) >> 1; if (batch[mid] < target) lo = mid + 1; else hi = mid; }
        sb[threadIdx.x] = lo;
    }
    __syncthreads();
    int beg = sb[0], end = sb[1];
    int t = threadIdx.x;
    int w = t >> 6, lane = t & 63;
    int h = lane & 7, grp = lane >> 3;
    float rw[32];
#pragma unroll
    for (int k = 0; k < 8; ++k)
#pragma unroll
        for (int j = 0; j < 4; ++j)
            rw[k * 4 + j] = wlin[(grp * 4 + j + 32 * k) * HEADS + h];
    float bl = blin[h];
    float acc = 0.f;
    int wg = chunk * 4 + w;   // 0..31
    for (int n = beg + wg; n < end; n += PCHUNK * 4) {
        const float* row = h3 + (size_t)n * HC;
        float dot = 0.f;
#pragma unroll
        for (int k = 0; k < 8; ++k) {
            float4 v = *(const float4*)&row[grp * 4 + 32 * k];
            dot += v.x * rw[k * 4] + v.y * rw[k * 4 + 1] + v.z * rw[k * 4 + 2] + v.w * rw[k * 4 + 3];
        }
        dot += __shfl_xor(dot, 8, 64);
        dot += __shfl_xor(dot, 16, 64);
        dot += __shfl_xor(dot, 32, 64);
        acc += tanhf(dot + bl);
    }
    __shared__ float sacc[4][HEADS];
    __shared__ float sred[HEADS];
    __shared__ int slast;
    if (lane < HEADS) sacc[w][h] = acc;
    __syncthreads();
    if (t < HEADS) sred[t] = sacc[0][t] + sacc[1][t] + sacc[2][t] + sacc[3][t];
    __syncthreads();
    if (t == 0) {
        for (int hh = 0; hh < HEADS; ++hh)
            partials[(size_t)blockIdx.x * HEADS + hh] = sred[hh];
        if (chunk == 0) gcnt[g] = end - beg;
        __threadfence();
        slast = (atomicAdd(ctr, 1) == (int)gridDim.x - 1);
    }
    __syncthreads();
    if (slast) {
        __threadfence();   // acquire: invalidate L1 before reading other blocks' partials
        if (t < ngraph * HEADS) {
            int gg = t >> 3, hh = t & 7;
            float s = 0.f;
            for (int c = 0; c < PCHUNK; ++c)
                s += partials[(size_t)(gg * PCHUNK + c) * HEADS + hh];
            out[t] = s / fmaxf((float)gcnt[gg], 1.f);
        }
    }
}

// ---------------------------------------------------------------------------

extern "C" void kernel_launch(void* const* d_in, const int* in_sizes, int n_in,
                              void* d_out, int out_size, void* d_ws, size_t ws_size,
                              hipStream_t stream) {
    const float* x    = (const float*)d_in[0];
    const int*   ei   = (const int*)d_in[1];
    const int*   et   = (const int*)d_in[2];
    const float* ea   = (const float*)d_in[3];
    const int*   batch = (const int*)d_in[4];
    const float* W[3]  = {(const float*)d_in[5],  (const float*)d_in[11], (const float*)d_in[17]};
    const float* Q[3]  = {(const float*)d_in[6],  (const float*)d_in[12], (const float*)d_in[18]};
    const float* K[3]  = {(const float*)d_in[7],  (const float*)d_in[13], (const float*)d_in[19]};
    const float* Em[3] = {(const float*)d_in[8],  (const float*)d_in[14], (const float*)d_in[20]};
    const float* WE[3] = {(const float*)d_in[9],  (const float*)d_in[15], (const float*)d_in[21]};
    const float* B[3]  = {(const float*)d_in[10], (const float*)d_in[16], (const float*)d_in[22]};
    const float* wlin = (const float*)d_in[23];
    const float* blin = (const float*)d_in[24];

    int nnodes = in_sizes[0] / 32;
    int nedges = in_sizes[2];
    int ngraph = 16;
    int npad = (nnodes + 15) & ~15;

    char* ws = (char*)d_ws;
    size_t off = 0;
    auto alloc = [&](size_t bytes) -> void* {
        void* p = ws + off;
        off = (off + bytes + 255) & ~(size_t)255;
        return p;
    };
    int*   deg      = (int*)alloc((size_t)nnodes * 4);
    int*   fill     = (int*)alloc((size_t)nnodes * 4);
    int*   rowptr   = (int*)alloc((size_t)(nnodes + 1) * 4);
    int*   csr_pack = (int*)alloc((size_t)nedges * 4);
    float* csr_ae   = (float*)alloc((size_t)nedges * 4);
    float* xw       = (float*)alloc((size_t)npad * NREL * HC * 4);
    float* qdot     = (float*)alloc((size_t)npad * NREL * HEADS * 4);
    float* kdot     = (float*)alloc((size_t)npad * NREL * HEADS * 4);
    float* ha       = (float*)alloc((size_t)nnodes * HC * 4);
    float* hb       = (float*)alloc((size_t)nnodes * HC * 4);
    float* wee      = (float*)alloc((size_t)NREL * HEADS * 4);
    float* partials = (float*)alloc((size_t)ngraph * PCHUNK * HEADS * 4);
    int*   gcnt     = (int*)alloc((size_t)ngraph * 4);
    int*   ctr      = (int*)alloc(256);
    unsigned short* x1hi = (unsigned short*)alloc((size_t)npad * 32 * 2);
    unsigned short* x1lo = (unsigned short*)alloc((size_t)npad * 32 * 2);
    unsigned short* hahi = (unsigned short*)alloc((size_t)npad * HC * 2);
    unsigned short* halo = (unsigned short*)alloc((size_t)npad * HC * 2);
    unsigned short* hbhi = (unsigned short*)alloc((size_t)npad * HC * 2);
    unsigned short* hblo = (unsigned short*)alloc((size_t)npad * HC * 2);
    unsigned short* wt1hi = (unsigned short*)alloc((size_t)NREL * NCT * 1 * 512 * 2);
    unsigned short* wt1lo = (unsigned short*)alloc((size_t)NREL * NCT * 1 * 512 * 2);
    unsigned short* wt2hi = (unsigned short*)alloc((size_t)NREL * NCT * 8 * 512 * 2);
    unsigned short* wt2lo = (unsigned short*)alloc((size_t)NREL * NCT * 8 * 512 * 2);
    unsigned short* wt3hi = (unsigned short*)alloc((size_t)NREL * NCT * 8 * 512 * 2);
    unsigned short* wt3lo = (unsigned short*)alloc((size_t)NREL * NCT * 8 * 512 * 2);
    (void)ws_size; (void)n_in; (void)out_size;

    int nprep = NREL * 32 + 2 * NREL * HC;            // 1632
    int npacka = (nnodes * 32 + 255) / 256;           // x-pack blocks

    // CSR build (edges are fixed across layers)
    k_init<<<(nnodes + 255) / 256, 256, 0, stream>>>(deg, fill, ctr, nnodes);
    k_deg<<<(nedges + 255) / 256, 256, 0, stream>>>(ei, deg, nedges);
    k_scan<<<1, 1024, 0, stream>>>(deg, rowptr, nnodes);
    k_scatter<<<(nedges + 255) / 256, 256, 0, stream>>>(ei, et, ea, rowptr, fill, csr_pack, csr_ae, nedges);

    // fused prep: x packing + all W conversion + q/k projection ctiles
    k_wprep<<<nprep + npacka, 256, 0, stream>>>(
        W[0], Q[0], K[0], Em[0], WE[0],
        W[1], Q[1], K[1], Em[1], WE[1],
        W[2], Q[2], K[2], Em[2], WE[2],
        wt1hi, wt1lo, wt2hi, wt2lo, wt3hi, wt3lo, wee,
        x, x1hi, x1lo, nnodes, nprep);

    dim3 gmfma((nnodes + 15) / 16, NREL);
    int gagg = (nnodes + 3) / 4;

    // ---- layer 1 (IN=32): x -> ha ----
    k_mfma<32><<<gmfma, 256, 0, stream>>>(x1hi, x1lo, wt1hi, wt1lo, xw, qdot, kdot, nnodes);
    k_agg<<<gagg, 256, 0, stream>>>(xw, qdot, kdot, rowptr, csr_pack, csr_ae, wee + 0, B[0], ha, hahi, halo, nnodes);

    // ---- layer 2 (IN=256): ha -> hb ----
    k_mfma<HC><<<gmfma, 256, 0, stream>>>(hahi, halo, wt2hi, wt2lo, xw, qdot, kdot, nnodes);
    k_agg<<<gagg, 256, 0, stream>>>(xw, qdot, kdot, rowptr, csr_pack, csr_ae, wee + 8, B[1], hb, hbhi, hblo, nnodes);

    // ---- layer 3 (IN=256): hb -> ha ----
    k_mfma<HC><<<gmfma, 256, 0, stream>>>(hbhi, hblo, wt3hi, wt3lo, xw, qdot, kdot, nnodes);
    k_agg<<<gagg, 256, 0, stream>>>(xw, qdot, kdot, rowptr, csr_pack, csr_ae, wee + 16, B[2], ha, hahi, halo, nnodes);

    // ---- head: linear + tanh + mean pool + fused divide ----
    k_pool2<<<ngraph * PCHUNK, 256, 0, stream>>>(ha, wlin, blin, batch, partials, gcnt, ctr,
                                                 (float*)d_out, nnodes, ngraph);
}

// Round 16
// 335.167 us; speedup vs baseline: 2.7535x; 1.0862x over previous
//
#include <hip/hip_runtime.h>
#include <math.h>

#define HEADS 8
#define HC 256
#define NREL 3
#define NEG 0.2f
#define MAXDEG 128   // bucket capacity per dst node; E=160k/N=10k -> mean 16, max ~45.
#define PCHUNK 8     // chunk-blocks per graph in the pool kernel
#define NCT 17       // packed-B ctiles per relation: 16 W-tiles + 1 qk-tile

typedef float vfloat4 __attribute__((ext_vector_type(4)));
typedef short b16x8 __attribute__((ext_vector_type(8)));    // 8 bf16 (4 VGPRs) MFMA A/B frag
typedef float f32x4 __attribute__((ext_vector_type(4)));    // MFMA C/D frag

__device__ __forceinline__ float warp32_reduce(float p) {
#pragma unroll
    for (int off = 16; off > 0; off >>= 1) p += __shfl_down(p, off, 32);
    return p;
}

// fp32 -> bf16 split helpers (round-to-nearest-even)
__device__ __forceinline__ unsigned short f2bf(float f) {
    unsigned u = __float_as_uint(f);
    unsigned r = (u + 0x7FFFu + ((u >> 16) & 1u)) >> 16;
    return (unsigned short)r;
}
__device__ __forceinline__ float bf2f(unsigned short b) {
    return __uint_as_float(((unsigned)b) << 16);
}

// ---- fused prep: W conversion + qk ctile + x packing + edge bucket scatter --
// Packed operand layouts (m89/m120-verified): lane=q*16+m holds
// A[m][k=kb*32+q*8+j]; B[k=kb*32+q*8+j][col=ct*16+m].
//   A offset: ((ntile*KB + kb)*64 + lane)*8 + j
//   B offset: (((r*NCT + ct)*KB + kb)*64 + lane)*8 + j
// block ranges: [0,nprep) W+qk; [nprep,nprep+npacka) x pack;
//               [nprep+npacka, ...) edge scatter into per-node buckets.
__global__ void k_wprep(
    const float* __restrict__ W1, const float* __restrict__ Q1, const float* __restrict__ K1,
    const float* __restrict__ E1, const float* __restrict__ WE1,
    const float* __restrict__ W2, const float* __restrict__ Q2, const float* __restrict__ K2,
    const float* __restrict__ E2, const float* __restrict__ WE2,
    const float* __restrict__ W3, const float* __restrict__ Q3, const float* __restrict__ K3,
    const float* __restrict__ E3, const float* __restrict__ WE3,
    unsigned short* __restrict__ b1hi, unsigned short* __restrict__ b1lo,
    unsigned short* __restrict__ b2hi, unsigned short* __restrict__ b2lo,
    unsigned short* __restrict__ b3hi, unsigned short* __restrict__ b3lo,
    float* __restrict__ wee,
    const float* __restrict__ x, unsigned short* __restrict__ x1hi,
    unsigned short* __restrict__ x1lo,
    const int* __restrict__ ei, const int* __restrict__ et, const float* __restrict__ ea,
    int* __restrict__ fill, int* __restrict__ bpack, float* __restrict__ bae,
    int nnodes, int nedges, int nprep, int npacka) {
    int bi = blockIdx.x;
    int tid = threadIdx.x;
    if (bi >= nprep + npacka) {
        // ---- edge scatter into buckets ----
        int e = (bi - nprep - npacka) * 256 + tid;
        if (e < nedges) {
            int dst = ei[nedges + e];
            int pos = atomicAdd(&fill[dst], 1);
            if (pos < MAXDEG) {
                bpack[dst * MAXDEG + pos] = (ei[e] << 2) | (et[e] & 3);
                bae[dst * MAXDEG + pos] = ea[e];
            }
        }
        return;
    }
    if (bi >= nprep) {
        // ---- packa: layer-1 x (K=32) -> packed split-bf16 A ----
        int i = (bi - nprep) * 256 + tid;   // n*32 + k
        if (i < nnodes * 32) {
            int n = i >> 5, k = i & 31;
            float f = x[i];
            unsigned short h = f2bf(f);
            int ntile = n >> 4, m = n & 15;
            int q = (k >> 3) & 3, j = k & 7;      // kb = 0
            size_t o = ((size_t)ntile * 64 + q * 16 + m) * 8 + j;
            x1hi[o] = h;
            x1lo[o] = f2bf(f - bf2f(h));
        }
        return;
    }
    const float *w, *qm, *km, *em, *wem;
    unsigned short *bhi, *blo;
    int K, layer, lbi;
    if (bi < NREL * 32) {
        layer = 0; lbi = bi; K = 32;
        w = W1; qm = Q1; km = K1; em = E1; wem = WE1; bhi = b1hi; blo = b1lo;
    } else if (bi < NREL * 32 + NREL * HC) {
        layer = 1; lbi = bi - NREL * 32; K = HC;
        w = W2; qm = Q2; km = K2; em = E2; wem = WE2; bhi = b2hi; blo = b2lo;
    } else {
        layer = 2; lbi = bi - NREL * 32 - NREL * HC; K = HC;
        w = W3; qm = Q3; km = K3; em = E3; wem = WE3; bhi = b3hi; blo = b3lo;
    }
    int r = lbi / K, i = lbi - r * K;
    int KB = K / 32;
    int kb = i >> 5, qq = (i >> 3) & 3, j = i & 7;
    // ---- W row -> B ct0..15 ----
    {
        int c = tid;
        float f = w[(size_t)lbi * HC + c];
        unsigned short h = f2bf(f);
        int ct = c >> 4, mc = c & 15;
        size_t o = ((((size_t)r * NCT + ct) * KB + kb) * 64 + qq * 16 + mc) * 8 + j;
        bhi[o] = h;
        blo[o] = f2bf(f - bf2f(h));
    }
    // ---- q/k dots -> B ct16 ----
    int h = tid >> 5, lane = tid & 31;
    const float* wrow = w + (size_t)lbi * HC;
    size_t base = (((size_t)r * NCT + 16) * KB + kb) * 512 + j;
    float p = 0.f;
    for (int o = lane; o < HC; o += 32) p += wrow[o] * qm[o * HEADS + h];
    p = warp32_reduce(p);
    if (lane == 0) {
        size_t o = base + (size_t)(qq * 16 + h) * 8;
        unsigned short hh = f2bf(p);
        bhi[o] = hh;
        blo[o] = f2bf(p - bf2f(hh));
    }
    p = 0.f;
    for (int o = lane; o < HC; o += 32) p += wrow[o] * km[o * HEADS + h];
    p = warp32_reduce(p);
    if (lane == 0) {
        size_t o = base + (size_t)(qq * 16 + 8 + h) * 8;
        unsigned short hh = f2bf(p);
        bhi[o] = hh;
        blo[o] = f2bf(p - bf2f(hh));
    }
    if (lbi == 0 && tid < HEADS) {
        float s = 0.f;
        for (int o = 0; o < HC; o++) s += wem[o] * em[o * HEADS + tid];
        wee[layer * HEADS + tid] = s;
    }
}

// ---- split-bf16 MFMA GEMM on packed operands (W cols + fused q/k dots) -----
template <int K>
__global__ __launch_bounds__(256) void k_mfma(const unsigned short* __restrict__ pahi,
                                              const unsigned short* __restrict__ palo,
                                              const unsigned short* __restrict__ pbhi,
                                              const unsigned short* __restrict__ pblo,
                                              float* __restrict__ xw,
                                              float* __restrict__ qdot,
                                              float* __restrict__ kdot, int nnodes) {
    constexpr int KB = K / 32;
    int nt = blockIdx.x;
    int r = blockIdx.y;
    int t = threadIdx.x;
    int wv = t >> 6, lane = t & 63;
    int q = lane >> 4, m = lane & 15;
    const unsigned short* pa_hi = pahi + ((size_t)nt * KB * 64 + lane) * 8;
    const unsigned short* pa_lo = palo + ((size_t)nt * KB * 64 + lane) * 8;
    f32x4 acc[5] = {};
    for (int kb = 0; kb < KB; ++kb) {
        b16x8 ah = *(const b16x8*)(pa_hi + (size_t)kb * 512);
        b16x8 al = *(const b16x8*)(pa_lo + (size_t)kb * 512);
#pragma unroll
        for (int s = 0; s < 5; ++s) {
            int ct = wv + 4 * s;
            if (ct >= NCT) continue;   // wave-uniform
            size_t o = (((size_t)r * NCT + ct) * KB + kb) * 512 + (size_t)lane * 8;
            b16x8 vbh = *(const b16x8*)(pbhi + o);
            b16x8 vbl = *(const b16x8*)(pblo + o);
            acc[s] = __builtin_amdgcn_mfma_f32_16x16x32_bf16(ah, vbh, acc[s], 0, 0, 0);
            acc[s] = __builtin_amdgcn_mfma_f32_16x16x32_bf16(al, vbh, acc[s], 0, 0, 0);
            acc[s] = __builtin_amdgcn_mfma_f32_16x16x32_bf16(ah, vbl, acc[s], 0, 0, 0);
        }
    }
    int n0 = nt * 16;
#pragma unroll
    for (int s = 0; s < 5; ++s) {
        int ct = wv + 4 * s;
        if (ct >= NCT) continue;
        if (ct < 16) {
            int c = ct * 16 + m;
#pragma unroll
            for (int g = 0; g < 4; ++g) {
                int n = n0 + q * 4 + g;
                if (n < nnodes) xw[((size_t)n * NREL + r) * HC + c] = acc[s][g];
            }
        } else {
#pragma unroll
            for (int g = 0; g < 4; ++g) {
                int n = n0 + q * 4 + g;
                if (n < nnodes) {
                    if (m < 8) qdot[n * 24 + r * 8 + m] = acc[s][g];
                    else       kdot[n * 24 + r * 8 + (m - 8)] = acc[s][g];
                }
            }
        }
    }
}

// ---- attention: wave-per-node, bucket edge store, no block barriers --------
__global__ __launch_bounds__(256) void k_agg(const float* __restrict__ xw,
                      const float* __restrict__ qdot, const float* __restrict__ kdot,
                      const int* __restrict__ fill, const int* __restrict__ bpack,
                      const float* __restrict__ bae, const float* __restrict__ wee,
                      const float* __restrict__ bias, float* __restrict__ hout,
                      unsigned short* __restrict__ houthi, unsigned short* __restrict__ houtlo,
                      int nnodes) {
    __shared__ float salpha[4][MAXDEG * HEADS];
    __shared__ int spack[4][MAXDEG];
    int wv = threadIdx.x >> 6, lane = threadIdx.x & 63;
    int n = blockIdx.x * 4 + wv;
    if (n >= nnodes) return;
    int beg = n * MAXDEG;
    int deg = fill[n];
    if (deg > MAXDEG) deg = MAXDEG;
    float* sal = salpha[wv];
    int* spk = spack[wv];
    // phase 1
    {
        int h = lane & 7;
        float weeh = wee[h];
        const float* qdn = qdot + n * 24;
        for (int base = 0; base < deg; base += 8) {
            int d = base + (lane >> 3);
            if (d < deg) {
                int pk = bpack[beg + d];
                float ae = bae[beg + d];
                int s = pk >> 2, t = pk & 3;
                if (h == 0) spk[d] = pk;
                float a = qdn[t * 8 + h] + kdot[s * 24 + t * 8 + h] + ae * weeh;
                sal[d * 8 + h] = (a > 0.f) ? a : NEG * a;
            }
        }
    }
    // phase 2: per-head softmax; lane = chunk*8 + head
    float sinv_h;
    {
        int h = lane & 7, c = lane >> 3;
        float m = -INFINITY;
        for (int d = c; d < deg; d += 8) m = fmaxf(m, sal[d * 8 + h]);
        m = fmaxf(m, __shfl_xor(m, 8, 64));
        m = fmaxf(m, __shfl_xor(m, 16, 64));
        m = fmaxf(m, __shfl_xor(m, 32, 64));
        float s = 0.f;
        for (int d = c; d < deg; d += 8) {
            float ex = expf(sal[d * 8 + h] - m);
            sal[d * 8 + h] = ex;
            s += ex;
        }
        s += __shfl_xor(s, 8, 64);
        s += __shfl_xor(s, 16, 64);
        s += __shfl_xor(s, 32, 64);
        sinv_h = 1.f / (s + 1e-16f);
    }
    float sinv_sel = __shfl(sinv_h, lane >> 3, 64);
    int hsel = lane >> 3;
    // phase 3: full-row wave gather, unroll x2
    float4 acc4 = make_float4(0.f, 0.f, 0.f, 0.f);
    int d = 0;
    for (; d + 1 < deg; d += 2) {
        int pk0 = spk[d], pk1 = spk[d + 1];
        const float4* r0 = (const float4*)(xw + ((size_t)(pk0 >> 2) * NREL + (pk0 & 3)) * HC);
        const float4* r1 = (const float4*)(xw + ((size_t)(pk1 >> 2) * NREL + (pk1 & 3)) * HC);
        float4 v0 = r0[lane];
        float4 v1 = r1[lane];
        float a0 = sal[d * 8 + hsel];
        float a1 = sal[(d + 1) * 8 + hsel];
        acc4.x += a0 * v0.x + a1 * v1.x;
        acc4.y += a0 * v0.y + a1 * v1.y;
        acc4.z += a0 * v0.z + a1 * v1.z;
        acc4.w += a0 * v0.w + a1 * v1.w;
    }
    if (d < deg) {
        int pk = spk[d];
        const float4* r0 = (const float4*)(xw + ((size_t)(pk >> 2) * NREL + (pk & 3)) * HC);
        float4 v0 = r0[lane];
        float a0 = sal[d * 8 + hsel];
        acc4.x += a0 * v0.x;
        acc4.y += a0 * v0.y;
        acc4.z += a0 * v0.z;
        acc4.w += a0 * v0.w;
    }
    // epilogue: cols c = 4*lane .. 4*lane+3
    float4 bv = *(const float4*)(bias + lane * 4);
    float4 v;
    v.x = fmaxf(acc4.x * sinv_sel + bv.x, 0.f);
    v.y = fmaxf(acc4.y * sinv_sel + bv.y, 0.f);
    v.z = fmaxf(acc4.z * sinv_sel + bv.z, 0.f);
    v.w = fmaxf(acc4.w * sinv_sel + bv.w, 0.f);
    *(float4*)(hout + (size_t)n * HC + lane * 4) = v;
    // packed split-bf16 A write for next layer (K=256 -> KB=8)
    int ntile = n >> 4, mm = n & 15;
    float vv[4] = {v.x, v.y, v.z, v.w};
#pragma unroll
    for (int i = 0; i < 4; ++i) {
        int c = lane * 4 + i;
        int kb = c >> 5, q = (c >> 3) & 3, j = c & 7;
        size_t o2 = ((((size_t)ntile * 8 + kb) * 64) + q * 16 + mm) * 8 + j;
        unsigned short hh = f2bf(vv[i]);
        houthi[o2] = hh;
        houtlo[o2] = f2bf(vv[i] - bf2f(hh));
    }
}

// ---- final linear + tanh + mean-pool + last-block divide -------------------
__global__ __launch_bounds__(256) void k_pool2(const float* __restrict__ h3,
                                               const float* __restrict__ wlin,
                                               const float* __restrict__ blin,
                                               const int* __restrict__ batch,
                                               float* __restrict__ partials,
                                               int* __restrict__ gcnt, int* __restrict__ ctr,
                                               float* __restrict__ out, int nnodes, int ngraph) {
    int g = blockIdx.x / PCHUNK, chunk = blockIdx.x % PCHUNK;
    __shared__ int sb[2];
    if (threadIdx.x < 2) {
        int target = g + threadIdx.x;
        int lo = 0, hi = nnodes;
        while (lo < hi) { int mid = (lo + hi) >> 1; if (batch[mid] < target) lo = mid + 1; else hi = mid; }
        sb[threadIdx.x] = lo;
    }
    __syncthreads();
    int beg = sb[0], end = sb[1];
    int t = threadIdx.x;
    int w = t >> 6, lane = t & 63;
    int h = lane & 7, grp = lane >> 3;
    float rw[32];
#pragma unroll
    for (int k = 0; k < 8; ++k)
#pragma unroll
        for (int j = 0; j < 4; ++j)
            rw[k * 4 + j] = wlin[(grp * 4 + j + 32 * k) * HEADS + h];
    float bl = blin[h];
    float acc = 0.f;
    int wg = chunk * 4 + w;   // 0..31
    for (int n = beg + wg; n < end; n += PCHUNK * 4) {
        const float* row = h3 + (size_t)n * HC;
        float dot = 0.f;
#pragma unroll
        for (int k = 0; k < 8; ++k) {
            float4 v = *(const float4*)&row[grp * 4 + 32 * k];
            dot += v.x * rw[k * 4] + v.y * rw[k * 4 + 1] + v.z * rw[k * 4 + 2] + v.w * rw[k * 4 + 3];
        }
        dot += __shfl_xor(dot, 8, 64);
        dot += __shfl_xor(dot, 16, 64);
        dot += __shfl_xor(dot, 32, 64);
        acc += tanhf(dot + bl);
    }
    __shared__ float sacc[4][HEADS];
    __shared__ float sred[HEADS];
    __shared__ int slast;
    if (lane < HEADS) sacc[w][h] = acc;
    __syncthreads();
    if (t < HEADS) sred[t] = sacc[0][t] + sacc[1][t] + sacc[2][t] + sacc[3][t];
    __syncthreads();
    if (t == 0) {
        for (int hh = 0; hh < HEADS; ++hh)
            partials[(size_t)blockIdx.x * HEADS + hh] = sred[hh];
        if (chunk == 0) gcnt[g] = end - beg;
        __threadfence();
        slast = (atomicAdd(ctr, 1) == (int)gridDim.x - 1);
    }
    __syncthreads();
    if (slast) {
        __threadfence();
        if (t < ngraph * HEADS) {
            int gg = t >> 3, hh = t & 7;
            float s = 0.f;
            for (int c = 0; c < PCHUNK; ++c)
                s += partials[(size_t)(gg * PCHUNK + c) * HEADS + hh];
            out[t] = s / fmaxf((float)gcnt[gg], 1.f);
        }
    }
}

// ---------------------------------------------------------------------------

extern "C" void kernel_launch(void* const* d_in, const int* in_sizes, int n_in,
                              void* d_out, int out_size, void* d_ws, size_t ws_size,
                              hipStream_t stream) {
    const float* x    = (const float*)d_in[0];
    const int*   ei   = (const int*)d_in[1];
    const int*   et   = (const int*)d_in[2];
    const float* ea   = (const float*)d_in[3];
    const int*   batch = (const int*)d_in[4];
    const float* W[3]  = {(const float*)d_in[5],  (const float*)d_in[11], (const float*)d_in[17]};
    const float* Q[3]  = {(const float*)d_in[6],  (const float*)d_in[12], (const float*)d_in[18]};
    const float* K[3]  = {(const float*)d_in[7],  (const float*)d_in[13], (const float*)d_in[19]};
    const float* Em[3] = {(const float*)d_in[8],  (const float*)d_in[14], (const float*)d_in[20]};
    const float* WE[3] = {(const float*)d_in[9],  (const float*)d_in[15], (const float*)d_in[21]};
    const float* B[3]  = {(const float*)d_in[10], (const float*)d_in[16], (const float*)d_in[22]};
    const float* wlin = (const float*)d_in[23];
    const float* blin = (const float*)d_in[24];

    int nnodes = in_sizes[0] / 32;
    int nedges = in_sizes[2];
    int ngraph = 16;
    int npad = (nnodes + 15) & ~15;

    char* ws = (char*)d_ws;
    size_t off = 0;
    auto alloc = [&](size_t bytes) -> void* {
        void* p = ws + off;
        off = (off + bytes + 255) & ~(size_t)255;
        return p;
    };
    // fill[nnodes] + ctr share one zeroed region (single memsetAsync)
    int*   fill     = (int*)alloc((size_t)(nnodes + 64) * 4);
    int*   ctr      = fill + nnodes;
    int*   bpack    = (int*)alloc((size_t)nnodes * MAXDEG * 4);
    float* bae      = (float*)alloc((size_t)nnodes * MAXDEG * 4);
    float* xw       = (float*)alloc((size_t)npad * NREL * HC * 4);
    float* qdot     = (float*)alloc((size_t)npad * NREL * HEADS * 4);
    float* kdot     = (float*)alloc((size_t)npad * NREL * HEADS * 4);
    float* ha       = (float*)alloc((size_t)nnodes * HC * 4);
    float* hb       = (float*)alloc((size_t)nnodes * HC * 4);
    float* wee      = (float*)alloc((size_t)NREL * HEADS * 4);
    float* partials = (float*)alloc((size_t)ngraph * PCHUNK * HEADS * 4);
    int*   gcnt     = (int*)alloc((size_t)ngraph * 4);
    unsigned short* x1hi = (unsigned short*)alloc((size_t)npad * 32 * 2);
    unsigned short* x1lo = (unsigned short*)alloc((size_t)npad * 32 * 2);
    unsigned short* hahi = (unsigned short*)alloc((size_t)npad * HC * 2);
    unsigned short* halo = (unsigned short*)alloc((size_t)npad * HC * 2);
    unsigned short* hbhi = (unsigned short*)alloc((size_t)npad * HC * 2);
    unsigned short* hblo = (unsigned short*)alloc((size_t)npad * HC * 2);
    unsigned short* wt1hi = (unsigned short*)alloc((size_t)NREL * NCT * 1 * 512 * 2);
    unsigned short* wt1lo = (unsigned short*)alloc((size_t)NREL * NCT * 1 * 512 * 2);
    unsigned short* wt2hi = (unsigned short*)alloc((size_t)NREL * NCT * 8 * 512 * 2);
    unsigned short* wt2lo = (unsigned short*)alloc((size_t)NREL * NCT * 8 * 512 * 2);
    unsigned short* wt3hi = (unsigned short*)alloc((size_t)NREL * NCT * 8 * 512 * 2);
    unsigned short* wt3lo = (unsigned short*)alloc((size_t)NREL * NCT * 8 * 512 * 2);
    (void)ws_size; (void)n_in; (void)out_size;

    int nprep = NREL * 32 + 2 * NREL * HC;            // 1632
    int npacka = (nnodes * 32 + 255) / 256;           // x-pack blocks
    int nscat = (nedges + 255) / 256;                 // edge-scatter blocks

    // zero fill+ctr, then one fused prep dispatch (weights + x pack + scatter)
    hipMemsetAsync(fill, 0, (size_t)(nnodes + 64) * 4, stream);
    k_wprep<<<nprep + npacka + nscat, 256, 0, stream>>>(
        W[0], Q[0], K[0], Em[0], WE[0],
        W[1], Q[1], K[1], Em[1], WE[1],
        W[2], Q[2], K[2], Em[2], WE[2],
        wt1hi, wt1lo, wt2hi, wt2lo, wt3hi, wt3lo, wee,
        x, x1hi, x1lo,
        ei, et, ea, fill, bpack, bae,
        nnodes, nedges, nprep, npacka);

    dim3 gmfma((nnodes + 15) / 16, NREL);
    int gagg = (nnodes + 3) / 4;

    // ---- layer 1 (IN=32): x -> ha ----
    k_mfma<32><<<gmfma, 256, 0, stream>>>(x1hi, x1lo, wt1hi, wt1lo, xw, qdot, kdot, nnodes);
    k_agg<<<gagg, 256, 0, stream>>>(xw, qdot, kdot, fill, bpack, bae, wee + 0, B[0], ha, hahi, halo, nnodes);

    // ---- layer 2 (IN=256): ha -> hb ----
    k_mfma<HC><<<gmfma, 256, 0, stream>>>(hahi, halo, wt2hi, wt2lo, xw, qdot, kdot, nnodes);
    k_agg<<<gagg, 256, 0, stream>>>(xw, qdot, kdot, fill, bpack, bae, wee + 8, B[1], hb, hbhi, hblo, nnodes);

    // ---- layer 3 (IN=256): hb -> ha ----
    k_mfma<HC><<<gmfma, 256, 0, stream>>>(hbhi, hblo, wt3hi, wt3lo, xw, qdot, kdot, nnodes);
    k_agg<<<gagg, 256, 0, stream>>>(xw, qdot, kdot, fill, bpack, bae, wee + 16, B[2], ha, hahi, halo, nnodes);

    // ---- head: linear + tanh + mean pool + fused divide ----
    k_pool2<<<ngraph * PCHUNK, 256, 0, stream>>>(ha, wlin, blin, batch, partials, gcnt, ctr,
                                                 (float*)d_out, nnodes, ngraph);
}

// Round 17
// 312.102 us; speedup vs baseline: 2.9570x; 1.0739x over previous
//
#include <hip/hip_runtime.h>
#include <math.h>

#define HEADS 8
#define HC 256
#define NREL 3
#define NEG 0.2f
#define MAXDEG 128   // bucket capacity per dst node; E=160k/N=10k -> mean 16, max ~45.
#define PCHUNK 8     // chunk-blocks per graph in the pool kernel
#define NCT 17       // packed-B ctiles per relation: 16 W-tiles + 1 qk-tile

typedef float vfloat4 __attribute__((ext_vector_type(4)));
typedef short b16x8 __attribute__((ext_vector_type(8)));    // 8 bf16 (4 VGPRs) MFMA A/B frag
typedef float f32x4 __attribute__((ext_vector_type(4)));    // MFMA C/D frag

__device__ __forceinline__ float warp32_reduce(float p) {
#pragma unroll
    for (int off = 16; off > 0; off >>= 1) p += __shfl_down(p, off, 32);
    return p;
}

// fp32 -> bf16 split helpers (round-to-nearest-even)
__device__ __forceinline__ unsigned short f2bf(float f) {
    unsigned u = __float_as_uint(f);
    unsigned r = (u + 0x7FFFu + ((u >> 16) & 1u)) >> 16;
    return (unsigned short)r;
}
__device__ __forceinline__ float bf2f(unsigned short b) {
    return __uint_as_float(((unsigned)b) << 16);
}

// ---- fused prep: W conversion + qk ctile + x packing + edge bucket scatter --
// Packed operand layouts (m89/m120-verified): lane=q*16+m holds
// A[m][k=kb*32+q*8+j]; B[k=kb*32+q*8+j][col=ct*16+m].
//   A offset: ((ntile*KB + kb)*64 + lane)*8 + j
//   B offset: (((r*NCT + ct)*KB + kb)*64 + lane)*8 + j
__global__ void k_wprep(
    const float* __restrict__ W1, const float* __restrict__ Q1, const float* __restrict__ K1,
    const float* __restrict__ E1, const float* __restrict__ WE1,
    const float* __restrict__ W2, const float* __restrict__ Q2, const float* __restrict__ K2,
    const float* __restrict__ E2, const float* __restrict__ WE2,
    const float* __restrict__ W3, const float* __restrict__ Q3, const float* __restrict__ K3,
    const float* __restrict__ E3, const float* __restrict__ WE3,
    unsigned short* __restrict__ b1hi, unsigned short* __restrict__ b1lo,
    unsigned short* __restrict__ b2hi, unsigned short* __restrict__ b2lo,
    unsigned short* __restrict__ b3hi, unsigned short* __restrict__ b3lo,
    float* __restrict__ wee,
    const float* __restrict__ x, unsigned short* __restrict__ x1hi,
    unsigned short* __restrict__ x1lo,
    const int* __restrict__ ei, const int* __restrict__ et, const float* __restrict__ ea,
    int* __restrict__ fill, int* __restrict__ bpack, float* __restrict__ bae,
    int nnodes, int nedges, int nprep, int npacka) {
    int bi = blockIdx.x;
    int tid = threadIdx.x;
    if (bi >= nprep + npacka) {
        // ---- edge scatter into buckets ----
        int e = (bi - nprep - npacka) * 256 + tid;
        if (e < nedges) {
            int dst = ei[nedges + e];
            int pos = atomicAdd(&fill[dst], 1);
            if (pos < MAXDEG) {
                bpack[dst * MAXDEG + pos] = (ei[e] << 2) | (et[e] & 3);
                bae[dst * MAXDEG + pos] = ea[e];
            }
        }
        return;
    }
    if (bi >= nprep) {
        // ---- packa: layer-1 x (K=32) -> packed split-bf16 A ----
        int i = (bi - nprep) * 256 + tid;   // n*32 + k
        if (i < nnodes * 32) {
            int n = i >> 5, k = i & 31;
            float f = x[i];
            unsigned short h = f2bf(f);
            int ntile = n >> 4, m = n & 15;
            int q = (k >> 3) & 3, j = k & 7;      // kb = 0
            size_t o = ((size_t)ntile * 64 + q * 16 + m) * 8 + j;
            x1hi[o] = h;
            x1lo[o] = f2bf(f - bf2f(h));
        }
        return;
    }
    const float *w, *qm, *km, *em, *wem;
    unsigned short *bhi, *blo;
    int K, layer, lbi;
    if (bi < NREL * 32) {
        layer = 0; lbi = bi; K = 32;
        w = W1; qm = Q1; km = K1; em = E1; wem = WE1; bhi = b1hi; blo = b1lo;
    } else if (bi < NREL * 32 + NREL * HC) {
        layer = 1; lbi = bi - NREL * 32; K = HC;
        w = W2; qm = Q2; km = K2; em = E2; wem = WE2; bhi = b2hi; blo = b2lo;
    } else {
        layer = 2; lbi = bi - NREL * 32 - NREL * HC; K = HC;
        w = W3; qm = Q3; km = K3; em = E3; wem = WE3; bhi = b3hi; blo = b3lo;
    }
    int r = lbi / K, i = lbi - r * K;
    int KB = K / 32;
    int kb = i >> 5, qq = (i >> 3) & 3, j = i & 7;
    // ---- W row -> B ct0..15 ----
    {
        int c = tid;
        float f = w[(size_t)lbi * HC + c];
        unsigned short h = f2bf(f);
        int ct = c >> 4, mc = c & 15;
        size_t o = ((((size_t)r * NCT + ct) * KB + kb) * 64 + qq * 16 + mc) * 8 + j;
        bhi[o] = h;
        blo[o] = f2bf(f - bf2f(h));
    }
    // ---- q/k dots -> B ct16 ----
    int h = tid >> 5, lane = tid & 31;
    const float* wrow = w + (size_t)lbi * HC;
    size_t base = (((size_t)r * NCT + 16) * KB + kb) * 512 + j;
    float p = 0.f;
    for (int o = lane; o < HC; o += 32) p += wrow[o] * qm[o * HEADS + h];
    p = warp32_reduce(p);
    if (lane == 0) {
        size_t o = base + (size_t)(qq * 16 + h) * 8;
        unsigned short hh = f2bf(p);
        bhi[o] = hh;
        blo[o] = f2bf(p - bf2f(hh));
    }
    p = 0.f;
    for (int o = lane; o < HC; o += 32) p += wrow[o] * km[o * HEADS + h];
    p = warp32_reduce(p);
    if (lane == 0) {
        size_t o = base + (size_t)(qq * 16 + 8 + h) * 8;
        unsigned short hh = f2bf(p);
        bhi[o] = hh;
        blo[o] = f2bf(p - bf2f(hh));
    }
    if (lbi == 0 && tid < HEADS) {
        float s = 0.f;
        for (int o = 0; o < HC; o++) s += wem[o] * em[o * HEADS + tid];
        wee[layer * HEADS + tid] = s;
    }
}

// ---- split-bf16 MFMA GEMM on packed operands -------------------------------
// NT node-tiles per block: one B-fragment load feeds NT A-tiles (B L2 traffic
// divided by NT, NT x per-wave MFMA ILP). Wave wv owns ctiles {wv+4s}.
template <int K, int NT>
__global__ __launch_bounds__(256) void k_mfma(const unsigned short* __restrict__ pahi,
                                              const unsigned short* __restrict__ palo,
                                              const unsigned short* __restrict__ pbhi,
                                              const unsigned short* __restrict__ pblo,
                                              float* __restrict__ xw,
                                              float* __restrict__ qdot,
                                              float* __restrict__ kdot,
                                              int nnodes, int ntiles) {
    constexpr int KB = K / 32;
    int ntg = blockIdx.x;
    int r = blockIdx.y;
    int t = threadIdx.x;
    int wv = t >> 6, lane = t & 63;
    int q = lane >> 4, m = lane & 15;
    f32x4 acc[5][NT] = {};
    for (int kb = 0; kb < KB; ++kb) {
        b16x8 ah[NT], al[NT];
#pragma unroll
        for (int ti = 0; ti < NT; ++ti) {
            int nt = ntg * NT + ti;
            if (nt >= ntiles) nt = ntiles - 1;   // clamp (stores guarded)
            size_t ao = (((size_t)nt * KB + kb) * 64 + lane) * 8;
            ah[ti] = *(const b16x8*)(pahi + ao);
            al[ti] = *(const b16x8*)(palo + ao);
        }
#pragma unroll
        for (int s = 0; s < 5; ++s) {
            int ct = wv + 4 * s;
            if (ct >= NCT) continue;   // wave-uniform
            size_t o = (((size_t)r * NCT + ct) * KB + kb) * 512 + (size_t)lane * 8;
            b16x8 vbh = *(const b16x8*)(pbhi + o);
            b16x8 vbl = *(const b16x8*)(pblo + o);
#pragma unroll
            for (int ti = 0; ti < NT; ++ti) {
                acc[s][ti] = __builtin_amdgcn_mfma_f32_16x16x32_bf16(ah[ti], vbh, acc[s][ti], 0, 0, 0);
                acc[s][ti] = __builtin_amdgcn_mfma_f32_16x16x32_bf16(al[ti], vbh, acc[s][ti], 0, 0, 0);
                acc[s][ti] = __builtin_amdgcn_mfma_f32_16x16x32_bf16(ah[ti], vbl, acc[s][ti], 0, 0, 0);
            }
        }
    }
#pragma unroll
    for (int ti = 0; ti < NT; ++ti) {
        int nt = ntg * NT + ti;
        if (nt >= ntiles) continue;
        int n0 = nt * 16;
#pragma unroll
        for (int s = 0; s < 5; ++s) {
            int ct = wv + 4 * s;
            if (ct >= NCT) continue;
            if (ct < 16) {
                int c = ct * 16 + m;
#pragma unroll
                for (int g = 0; g < 4; ++g) {
                    int n = n0 + q * 4 + g;
                    if (n < nnodes) xw[((size_t)n * NREL + r) * HC + c] = acc[s][ti][g];
                }
            } else {
#pragma unroll
                for (int g = 0; g < 4; ++g) {
                    int n = n0 + q * 4 + g;
                    if (n < nnodes) {
                        if (m < 8) qdot[n * 24 + r * 8 + m] = acc[s][ti][g];
                        else       kdot[n * 24 + r * 8 + (m - 8)] = acc[s][ti][g];
                    }
                }
            }
        }
    }
}

// ---- attention: wave-per-node, bucket edge store, no block barriers --------
__global__ __launch_bounds__(256) void k_agg(const float* __restrict__ xw,
                      const float* __restrict__ qdot, const float* __restrict__ kdot,
                      const int* __restrict__ fill, const int* __restrict__ bpack,
                      const float* __restrict__ bae, const float* __restrict__ wee,
                      const float* __restrict__ bias, float* __restrict__ hout,
                      unsigned short* __restrict__ houthi, unsigned short* __restrict__ houtlo,
                      int nnodes) {
    __shared__ float salpha[4][MAXDEG * HEADS];
    __shared__ int spack[4][MAXDEG];
    int wv = threadIdx.x >> 6, lane = threadIdx.x & 63;
    int n = blockIdx.x * 4 + wv;
    if (n >= nnodes) return;
    int beg = n * MAXDEG;
    int deg = fill[n];
    if (deg > MAXDEG) deg = MAXDEG;
    float* sal = salpha[wv];
    int* spk = spack[wv];
    // phase 1
    {
        int h = lane & 7;
        float weeh = wee[h];
        const float* qdn = qdot + n * 24;
        for (int base = 0; base < deg; base += 8) {
            int d = base + (lane >> 3);
            if (d < deg) {
                int pk = bpack[beg + d];
                float ae = bae[beg + d];
                int s = pk >> 2, t = pk & 3;
                if (h == 0) spk[d] = pk;
                float a = qdn[t * 8 + h] + kdot[s * 24 + t * 8 + h] + ae * weeh;
                sal[d * 8 + h] = (a > 0.f) ? a : NEG * a;
            }
        }
    }
    // phase 2: per-head softmax; lane = chunk*8 + head
    float sinv_h;
    {
        int h = lane & 7, c = lane >> 3;
        float m = -INFINITY;
        for (int d = c; d < deg; d += 8) m = fmaxf(m, sal[d * 8 + h]);
        m = fmaxf(m, __shfl_xor(m, 8, 64));
        m = fmaxf(m, __shfl_xor(m, 16, 64));
        m = fmaxf(m, __shfl_xor(m, 32, 64));
        float s = 0.f;
        for (int d = c; d < deg; d += 8) {
            float ex = expf(sal[d * 8 + h] - m);
            sal[d * 8 + h] = ex;
            s += ex;
        }
        s += __shfl_xor(s, 8, 64);
        s += __shfl_xor(s, 16, 64);
        s += __shfl_xor(s, 32, 64);
        sinv_h = 1.f / (s + 1e-16f);
    }
    float sinv_sel = __shfl(sinv_h, lane >> 3, 64);
    int hsel = lane >> 3;
    // phase 3: full-row wave gather, unroll x4 (4 outstanding 1KB loads)
    float4 acc4 = make_float4(0.f, 0.f, 0.f, 0.f);
    int d = 0;
    for (; d + 3 < deg; d += 4) {
        int pk0 = spk[d], pk1 = spk[d + 1], pk2 = spk[d + 2], pk3 = spk[d + 3];
        const float4* r0 = (const float4*)(xw + ((size_t)(pk0 >> 2) * NREL + (pk0 & 3)) * HC);
        const float4* r1 = (const float4*)(xw + ((size_t)(pk1 >> 2) * NREL + (pk1 & 3)) * HC);
        const float4* r2 = (const float4*)(xw + ((size_t)(pk2 >> 2) * NREL + (pk2 & 3)) * HC);
        const float4* r3 = (const float4*)(xw + ((size_t)(pk3 >> 2) * NREL + (pk3 & 3)) * HC);
        float4 v0 = r0[lane], v1 = r1[lane], v2 = r2[lane], v3 = r3[lane];
        float a0 = sal[d * 8 + hsel];
        float a1 = sal[(d + 1) * 8 + hsel];
        float a2 = sal[(d + 2) * 8 + hsel];
        float a3 = sal[(d + 3) * 8 + hsel];
        acc4.x += a0 * v0.x + a1 * v1.x + a2 * v2.x + a3 * v3.x;
        acc4.y += a0 * v0.y + a1 * v1.y + a2 * v2.y + a3 * v3.y;
        acc4.z += a0 * v0.z + a1 * v1.z + a2 * v2.z + a3 * v3.z;
        acc4.w += a0 * v0.w + a1 * v1.w + a2 * v2.w + a3 * v3.w;
    }
    for (; d < deg; ++d) {
        int pk = spk[d];
        const float4* r0 = (const float4*)(xw + ((size_t)(pk >> 2) * NREL + (pk & 3)) * HC);
        float4 v0 = r0[lane];
        float a0 = sal[d * 8 + hsel];
        acc4.x += a0 * v0.x;
        acc4.y += a0 * v0.y;
        acc4.z += a0 * v0.z;
        acc4.w += a0 * v0.w;
    }
    // epilogue: cols c = 4*lane .. 4*lane+3
    float4 bv = *(const float4*)(bias + lane * 4);
    float4 v;
    v.x = fmaxf(acc4.x * sinv_sel + bv.x, 0.f);
    v.y = fmaxf(acc4.y * sinv_sel + bv.y, 0.f);
    v.z = fmaxf(acc4.z * sinv_sel + bv.z, 0.f);
    v.w = fmaxf(acc4.w * sinv_sel + bv.w, 0.f);
    *(float4*)(hout + (size_t)n * HC + lane * 4) = v;
    // packed split-bf16 A write for next layer (K=256 -> KB=8)
    int ntile = n >> 4, mm = n & 15;
    float vv[4] = {v.x, v.y, v.z, v.w};
#pragma unroll
    for (int i = 0; i < 4; ++i) {
        int c = lane * 4 + i;
        int kb = c >> 5, q = (c >> 3) & 3, j = c & 7;
        size_t o2 = ((((size_t)ntile * 8 + kb) * 64) + q * 16 + mm) * 8 + j;
        unsigned short hh = f2bf(vv[i]);
        houthi[o2] = hh;
        houtlo[o2] = f2bf(vv[i] - bf2f(hh));
    }
}

// ---- final linear + tanh + mean-pool + last-block divide -------------------
__global__ __launch_bounds__(256) void k_pool2(const float* __restrict__ h3,
                                               const float* __restrict__ wlin,
                                               const float* __restrict__ blin,
                                               const int* __restrict__ batch,
                                               float* __restrict__ partials,
                                               int* __restrict__ gcnt, int* __restrict__ ctr,
                                               float* __restrict__ out, int nnodes, int ngraph) {
    int g = blockIdx.x / PCHUNK, chunk = blockIdx.x % PCHUNK;
    __shared__ int sb[2];
    if (threadIdx.x < 2) {
        int target = g + threadIdx.x;
        int lo = 0, hi = nnodes;
        while (lo < hi) { int mid = (lo + hi) >> 1; if (batch[mid] < target) lo = mid + 1; else hi = mid; }
        sb[threadIdx.x] = lo;
    }
    __syncthreads();
    int beg = sb[0], end = sb[1];
    int t = threadIdx.x;
    int w = t >> 6, lane = t & 63;
    int h = lane & 7, grp = lane >> 3;
    float rw[32];
#pragma unroll
    for (int k = 0; k < 8; ++k)
#pragma unroll
        for (int j = 0; j < 4; ++j)
            rw[k * 4 + j] = wlin[(grp * 4 + j + 32 * k) * HEADS + h];
    float bl = blin[h];
    float acc = 0.f;
    int wg = chunk * 4 + w;   // 0..31
    for (int n = beg + wg; n < end; n += PCHUNK * 4) {
        const float* row = h3 + (size_t)n * HC;
        float dot = 0.f;
#pragma unroll
        for (int k = 0; k < 8; ++k) {
            float4 v = *(const float4*)&row[grp * 4 + 32 * k];
            dot += v.x * rw[k * 4] + v.y * rw[k * 4 + 1] + v.z * rw[k * 4 + 2] + v.w * rw[k * 4 + 3];
        }
        dot += __shfl_xor(dot, 8, 64);
        dot += __shfl_xor(dot, 16, 64);
        dot += __shfl_xor(dot, 32, 64);
        acc += tanhf(dot + bl);
    }
    __shared__ float sacc[4][HEADS];
    __shared__ float sred[HEADS];
    __shared__ int slast;
    if (lane < HEADS) sacc[w][h] = acc;
    __syncthreads();
    if (t < HEADS) sred[t] = sacc[0][t] + sacc[1][t] + sacc[2][t] + sacc[3][t];
    __syncthreads();
    if (t == 0) {
        for (int hh = 0; hh < HEADS; ++hh)
            partials[(size_t)blockIdx.x * HEADS + hh] = sred[hh];
        if (chunk == 0) gcnt[g] = end - beg;
        __threadfence();
        slast = (atomicAdd(ctr, 1) == (int)gridDim.x - 1);
    }
    __syncthreads();
    if (slast) {
        __threadfence();
        if (t < ngraph * HEADS) {
            int gg = t >> 3, hh = t & 7;
            float s = 0.f;
            for (int c = 0; c < PCHUNK; ++c)
                s += partials[(size_t)(gg * PCHUNK + c) * HEADS + hh];
            out[t] = s / fmaxf((float)gcnt[gg], 1.f);
        }
    }
}

// ---------------------------------------------------------------------------

extern "C" void kernel_launch(void* const* d_in, const int* in_sizes, int n_in,
                              void* d_out, int out_size, void* d_ws, size_t ws_size,
                              hipStream_t stream) {
    const float* x    = (const float*)d_in[0];
    const int*   ei   = (const int*)d_in[1];
    const int*   et   = (const int*)d_in[2];
    const float* ea   = (const float*)d_in[3];
    const int*   batch = (const int*)d_in[4];
    const float* W[3]  = {(const float*)d_in[5],  (const float*)d_in[11], (const float*)d_in[17]};
    const float* Q[3]  = {(const float*)d_in[6],  (const float*)d_in[12], (const float*)d_in[18]};
    const float* K[3]  = {(const float*)d_in[7],  (const float*)d_in[13], (const float*)d_in[19]};
    const float* Em[3] = {(const float*)d_in[8],  (const float*)d_in[14], (const float*)d_in[20]};
    const float* WE[3] = {(const float*)d_in[9],  (const float*)d_in[15], (const float*)d_in[21]};
    const float* B[3]  = {(const float*)d_in[10], (const float*)d_in[16], (const float*)d_in[22]};
    const float* wlin = (const float*)d_in[23];
    const float* blin = (const float*)d_in[24];

    int nnodes = in_sizes[0] / 32;
    int nedges = in_sizes[2];
    int ngraph = 16;
    int npad = (nnodes + 15) & ~15;
    int ntiles = npad / 16;

    char* ws = (char*)d_ws;
    size_t off = 0;
    auto alloc = [&](size_t bytes) -> void* {
        void* p = ws + off;
        off = (off + bytes + 255) & ~(size_t)255;
        return p;
    };
    // fill[nnodes] + ctr share one zeroed region (single memsetAsync)
    int*   fill     = (int*)alloc((size_t)(nnodes + 64) * 4);
    int*   ctr      = fill + nnodes;
    int*   bpack    = (int*)alloc((size_t)nnodes * MAXDEG * 4);
    float* bae      = (float*)alloc((size_t)nnodes * MAXDEG * 4);
    float* xw       = (float*)alloc((size_t)npad * NREL * HC * 4);
    float* qdot     = (float*)alloc((size_t)npad * NREL * HEADS * 4);
    float* kdot     = (float*)alloc((size_t)npad * NREL * HEADS * 4);
    float* ha       = (float*)alloc((size_t)nnodes * HC * 4);
    float* hb       = (float*)alloc((size_t)nnodes * HC * 4);
    float* wee      = (float*)alloc((size_t)NREL * HEADS * 4);
    float* partials = (float*)alloc((size_t)ngraph * PCHUNK * HEADS * 4);
    int*   gcnt     = (int*)alloc((size_t)ngraph * 4);
    unsigned short* x1hi = (unsigned short*)alloc((size_t)npad * 32 * 2);
    unsigned short* x1lo = (unsigned short*)alloc((size_t)npad * 32 * 2);
    unsigned short* hahi = (unsigned short*)alloc((size_t)npad * HC * 2);
    unsigned short* halo = (unsigned short*)alloc((size_t)npad * HC * 2);
    unsigned short* hbhi = (unsigned short*)alloc((size_t)npad * HC * 2);
    unsigned short* hblo = (unsigned short*)alloc((size_t)npad * HC * 2);
    unsigned short* wt1hi = (unsigned short*)alloc((size_t)NREL * NCT * 1 * 512 * 2);
    unsigned short* wt1lo = (unsigned short*)alloc((size_t)NREL * NCT * 1 * 512 * 2);
    unsigned short* wt2hi = (unsigned short*)alloc((size_t)NREL * NCT * 8 * 512 * 2);
    unsigned short* wt2lo = (unsigned short*)alloc((size_t)NREL * NCT * 8 * 512 * 2);
    unsigned short* wt3hi = (unsigned short*)alloc((size_t)NREL * NCT * 8 * 512 * 2);
    unsigned short* wt3lo = (unsigned short*)alloc((size_t)NREL * NCT * 8 * 512 * 2);
    (void)ws_size; (void)n_in; (void)out_size;

    int nprep = NREL * 32 + 2 * NREL * HC;            // 1632
    int npacka = (nnodes * 32 + 255) / 256;           // x-pack blocks
    int nscat = (nedges + 255) / 256;                 // edge-scatter blocks

    // zero fill+ctr, then one fused prep dispatch (weights + x pack + scatter)
    hipMemsetAsync(fill, 0, (size_t)(nnodes + 64) * 4, stream);
    k_wprep<<<nprep + npacka + nscat, 256, 0, stream>>>(
        W[0], Q[0], K[0], Em[0], WE[0],
        W[1], Q[1], K[1], Em[1], WE[1],
        W[2], Q[2], K[2], Em[2], WE[2],
        wt1hi, wt1lo, wt2hi, wt2lo, wt3hi, wt3lo, wee,
        x, x1hi, x1lo,
        ei, et, ea, fill, bpack, bae,
        nnodes, nedges, nprep, npacka);

    dim3 gmfma1(ntiles, NREL);                 // K=32: NT=1
    dim3 gmfma2((ntiles + 1) / 2, NREL);       // K=256: NT=2
    int gagg = (nnodes + 3) / 4;

    // ---- layer 1 (IN=32): x -> ha ----
    k_mfma<32, 1><<<gmfma1, 256, 0, stream>>>(x1hi, x1lo, wt1hi, wt1lo, xw, qdot, kdot, nnodes, ntiles);
    k_agg<<<gagg, 256, 0, stream>>>(xw, qdot, kdot, fill, bpack, bae, wee + 0, B[0], ha, hahi, halo, nnodes);

    // ---- layer 2 (IN=256): ha -> hb ----
    k_mfma<HC, 2><<<gmfma2, 256, 0, stream>>>(hahi, halo, wt2hi, wt2lo, xw, qdot, kdot, nnodes, ntiles);
    k_agg<<<gagg, 256, 0, stream>>>(xw, qdot, kdot, fill, bpack, bae, wee + 8, B[1], hb, hbhi, hblo, nnodes);

    // ---- layer 3 (IN=256): hb -> ha ----
    k_mfma<HC, 2><<<gmfma2, 256, 0, stream>>>(hbhi, hblo, wt3hi, wt3lo, xw, qdot, kdot, nnodes, ntiles);
    k_agg<<<gagg, 256, 0, stream>>>(xw, qdot, kdot, fill, bpack, bae, wee + 16, B[2], ha, hahi, halo, nnodes);

    // ---- head: linear + tanh + mean pool + fused divide ----
    k_pool2<<<ngraph * PCHUNK, 256, 0, stream>>>(ha, wlin, blin, batch, partials, gcnt, ctr,
                                                 (float*)d_out, nnodes, ngraph);
}

// Round 18
// 307.905 us; speedup vs baseline: 2.9973x; 1.0136x over previous
//
#include <hip/hip_runtime.h>
#include <math.h>

#define HEADS 8
#define HC 256
#define NREL 3
#define NEG 0.2f
#define MAXDEG 128   // bucket capacity per dst node; E=160k/N=10k -> mean 16, max ~45.
#define PCHUNK 8     // chunk-blocks per graph in the pool kernel
#define NCT 17       // packed-B ctiles per relation: 16 W-tiles + 1 qk-tile

typedef float vfloat4 __attribute__((ext_vector_type(4)));
typedef short b16x8 __attribute__((ext_vector_type(8)));    // 8 bf16 (4 VGPRs) MFMA A/B frag
typedef float f32x4 __attribute__((ext_vector_type(4)));    // MFMA C/D frag
typedef unsigned short u16x8 __attribute__((ext_vector_type(8)));

__device__ __forceinline__ float warp32_reduce(float p) {
#pragma unroll
    for (int off = 16; off > 0; off >>= 1) p += __shfl_down(p, off, 32);
    return p;
}

// fp32 -> bf16 split helpers (round-to-nearest-even)
__device__ __forceinline__ unsigned short f2bf(float f) {
    unsigned u = __float_as_uint(f);
    unsigned r = (u + 0x7FFFu + ((u >> 16) & 1u)) >> 16;
    return (unsigned short)r;
}
__device__ __forceinline__ float bf2f(unsigned short b) {
    return __uint_as_float(((unsigned)b) << 16);
}

// ---- fused prep ------------------------------------------------------------
// Packed operand layouts (m89/m120-verified): lane=q*16+m holds
// A[m][k=kb*32+q*8+j]; B[k=kb*32+q*8+j][col=ct*16+m].
//   A offset: ((ntile*KB + kb)*64 + lane)*8 + j
//   B offset: (((r*NCT + ct)*KB + kb)*64 + lane)*8 + j
// block ranges: [0,nwcv) vectorized W conversion (51 tile-blocks);
//               [nwcv, nwcv+nprep) qk-dot rows; then x-pack; then edge scatter.
__global__ void k_wprep(
    const float* __restrict__ W1, const float* __restrict__ Q1, const float* __restrict__ K1,
    const float* __restrict__ E1, const float* __restrict__ WE1,
    const float* __restrict__ W2, const float* __restrict__ Q2, const float* __restrict__ K2,
    const float* __restrict__ E2, const float* __restrict__ WE2,
    const float* __restrict__ W3, const float* __restrict__ Q3, const float* __restrict__ K3,
    const float* __restrict__ E3, const float* __restrict__ WE3,
    unsigned short* __restrict__ b1hi, unsigned short* __restrict__ b1lo,
    unsigned short* __restrict__ b2hi, unsigned short* __restrict__ b2lo,
    unsigned short* __restrict__ b3hi, unsigned short* __restrict__ b3lo,
    float* __restrict__ wee,
    const float* __restrict__ x, unsigned short* __restrict__ x1hi,
    unsigned short* __restrict__ x1lo,
    const int* __restrict__ ei, const int* __restrict__ et, const float* __restrict__ ea,
    int* __restrict__ fill, int2* __restrict__ bkt,
    int nnodes, int nedges, int nwcv, int nprep, int npacka) {
    int bi = blockIdx.x;
    int tid = threadIdx.x;
    if (bi < nwcv) {
        // ---- vectorized W conversion: one block = one (layer, r, kb) tile ----
        const float* w;
        unsigned short *bhi, *blo;
        int K, r, kb;
        if (bi < NREL) { w = W1; bhi = b1hi; blo = b1lo; K = 32; r = bi; kb = 0; }
        else if (bi < NREL + NREL * 8) {
            int idx = bi - NREL; w = W2; bhi = b2hi; blo = b2lo; K = HC; r = idx >> 3; kb = idx & 7;
        } else {
            int idx = bi - NREL - NREL * 8; w = W3; bhi = b3hi; blo = b3lo; K = HC; r = idx >> 3; kb = idx & 7;
        }
        int KB = K / 32;
        int ct = tid >> 4, mc = tid & 15;
        int c = ct * 16 + mc;
#pragma unroll
        for (int q = 0; q < 4; ++q) {
            u16x8 hv, lv;
#pragma unroll
            for (int j = 0; j < 8; ++j) {
                float f = w[(size_t)(r * K + kb * 32 + q * 8 + j) * HC + c];
                unsigned short h = f2bf(f);
                hv[j] = h;
                lv[j] = f2bf(f - bf2f(h));
            }
            size_t base = ((((size_t)r * NCT + ct) * KB + kb) * 64 + q * 16 + mc) * 8;
            *(u16x8*)(bhi + base) = hv;
            *(u16x8*)(blo + base) = lv;
        }
        return;
    }
    bi -= nwcv;
    if (bi >= nprep + npacka) {
        // ---- edge scatter into buckets ----
        int e = (bi - nprep - npacka) * 256 + tid;
        if (e < nedges) {
            int dst = ei[nedges + e];
            int pos = atomicAdd(&fill[dst], 1);
            if (pos < MAXDEG)
                bkt[dst * MAXDEG + pos] = make_int2((ei[e] << 2) | (et[e] & 3),
                                                    __float_as_int(ea[e]));
        }
        return;
    }
    if (bi >= nprep) {
        // ---- packa: layer-1 x (K=32) -> packed split-bf16 A ----
        int i = (bi - nprep) * 256 + tid;   // n*32 + k
        if (i < nnodes * 32) {
            int n = i >> 5, k = i & 31;
            float f = x[i];
            unsigned short h = f2bf(f);
            int ntile = n >> 4, m = n & 15;
            int q = (k >> 3) & 3, j = k & 7;      // kb = 0
            size_t o = ((size_t)ntile * 64 + q * 16 + m) * 8 + j;
            x1hi[o] = h;
            x1lo[o] = f2bf(f - bf2f(h));
        }
        return;
    }
    // ---- qk-dot rows -> B ct16, + wee ----
    const float *w, *qm, *km, *em, *wem;
    unsigned short *bhi, *blo;
    int K, layer, lbi;
    if (bi < NREL * 32) {
        layer = 0; lbi = bi; K = 32;
        w = W1; qm = Q1; km = K1; em = E1; wem = WE1; bhi = b1hi; blo = b1lo;
    } else if (bi < NREL * 32 + NREL * HC) {
        layer = 1; lbi = bi - NREL * 32; K = HC;
        w = W2; qm = Q2; km = K2; em = E2; wem = WE2; bhi = b2hi; blo = b2lo;
    } else {
        layer = 2; lbi = bi - NREL * 32 - NREL * HC; K = HC;
        w = W3; qm = Q3; km = K3; em = E3; wem = WE3; bhi = b3hi; blo = b3lo;
    }
    int r = lbi / K, i = lbi - r * K;
    int KB = K / 32;
    int kb = i >> 5, qq = (i >> 3) & 3, j = i & 7;
    int h = tid >> 5, lane = tid & 31;
    const float* wrow = w + (size_t)lbi * HC;
    size_t base = (((size_t)r * NCT + 16) * KB + kb) * 512 + j;
    float p = 0.f;
    for (int o = lane; o < HC; o += 32) p += wrow[o] * qm[o * HEADS + h];
    p = warp32_reduce(p);
    if (lane == 0) {
        size_t o = base + (size_t)(qq * 16 + h) * 8;
        unsigned short hh = f2bf(p);
        bhi[o] = hh;
        blo[o] = f2bf(p - bf2f(hh));
    }
    p = 0.f;
    for (int o = lane; o < HC; o += 32) p += wrow[o] * km[o * HEADS + h];
    p = warp32_reduce(p);
    if (lane == 0) {
        size_t o = base + (size_t)(qq * 16 + 8 + h) * 8;
        unsigned short hh = f2bf(p);
        bhi[o] = hh;
        blo[o] = f2bf(p - bf2f(hh));
    }
    if (lbi == 0 && tid < HEADS) {
        float s = 0.f;
        for (int o = 0; o < HC; o++) s += wem[o] * em[o * HEADS + tid];
        wee[layer * HEADS + tid] = s;
    }
}

// ---- split-bf16 MFMA GEMM on packed operands -------------------------------
// NT node-tiles per block: one B-fragment load feeds NT A-tiles.
template <int K, int NT>
__global__ __launch_bounds__(256) void k_mfma(const unsigned short* __restrict__ pahi,
                                              const unsigned short* __restrict__ palo,
                                              const unsigned short* __restrict__ pbhi,
                                              const unsigned short* __restrict__ pblo,
                                              float* __restrict__ xw,
                                              float* __restrict__ qdot,
                                              float* __restrict__ kdot,
                                              int nnodes, int ntiles) {
    constexpr int KB = K / 32;
    int ntg = blockIdx.x;
    int r = blockIdx.y;
    int t = threadIdx.x;
    int wv = t >> 6, lane = t & 63;
    int q = lane >> 4, m = lane & 15;
    f32x4 acc[5][NT] = {};
    for (int kb = 0; kb < KB; ++kb) {
        b16x8 ah[NT], al[NT];
#pragma unroll
        for (int ti = 0; ti < NT; ++ti) {
            int nt = ntg * NT + ti;
            if (nt >= ntiles) nt = ntiles - 1;   // clamp (stores guarded)
            size_t ao = (((size_t)nt * KB + kb) * 64 + lane) * 8;
            ah[ti] = *(const b16x8*)(pahi + ao);
            al[ti] = *(const b16x8*)(palo + ao);
        }
#pragma unroll
        for (int s = 0; s < 5; ++s) {
            int ct = wv + 4 * s;
            if (ct >= NCT) continue;   // wave-uniform
            size_t o = (((size_t)r * NCT + ct) * KB + kb) * 512 + (size_t)lane * 8;
            b16x8 vbh = *(const b16x8*)(pbhi + o);
            b16x8 vbl = *(const b16x8*)(pblo + o);
#pragma unroll
            for (int ti = 0; ti < NT; ++ti) {
                acc[s][ti] = __builtin_amdgcn_mfma_f32_16x16x32_bf16(ah[ti], vbh, acc[s][ti], 0, 0, 0);
                acc[s][ti] = __builtin_amdgcn_mfma_f32_16x16x32_bf16(al[ti], vbh, acc[s][ti], 0, 0, 0);
                acc[s][ti] = __builtin_amdgcn_mfma_f32_16x16x32_bf16(ah[ti], vbl, acc[s][ti], 0, 0, 0);
            }
        }
    }
#pragma unroll
    for (int ti = 0; ti < NT; ++ti) {
        int nt = ntg * NT + ti;
        if (nt >= ntiles) continue;
        int n0 = nt * 16;
#pragma unroll
        for (int s = 0; s < 5; ++s) {
            int ct = wv + 4 * s;
            if (ct >= NCT) continue;
            if (ct < 16) {
                int c = ct * 16 + m;
#pragma unroll
                for (int g = 0; g < 4; ++g) {
                    int n = n0 + q * 4 + g;
                    if (n < nnodes) xw[((size_t)n * NREL + r) * HC + c] = acc[s][ti][g];
                }
            } else {
#pragma unroll
                for (int g = 0; g < 4; ++g) {
                    int n = n0 + q * 4 + g;
                    if (n < nnodes) {
                        if (m < 8) qdot[n * 24 + r * 8 + m] = acc[s][ti][g];
                        else       kdot[n * 24 + r * 8 + (m - 8)] = acc[s][ti][g];
                    }
                }
            }
        }
    }
}

// ---- attention: wave-per-node, int2 bucket, no block barriers --------------
// hout / houthi may be null (dead outputs skipped).
__global__ __launch_bounds__(256) void k_agg(const float* __restrict__ xw,
                      const float* __restrict__ qdot, const float* __restrict__ kdot,
                      const int* __restrict__ fill, const int2* __restrict__ bkt,
                      const float* __restrict__ wee,
                      const float* __restrict__ bias, float* __restrict__ hout,
                      unsigned short* __restrict__ houthi, unsigned short* __restrict__ houtlo,
                      int nnodes) {
    __shared__ float salpha[4][MAXDEG * HEADS];
    __shared__ int spack[4][MAXDEG];
    int wv = threadIdx.x >> 6, lane = threadIdx.x & 63;
    int n = blockIdx.x * 4 + wv;
    if (n >= nnodes) return;
    int beg = n * MAXDEG;
    int deg = fill[n];
    if (deg > MAXDEG) deg = MAXDEG;
    float* sal = salpha[wv];
    int* spk = spack[wv];
    // phase 1
    {
        int h = lane & 7;
        float weeh = wee[h];
        const float* qdn = qdot + n * 24;
        for (int base = 0; base < deg; base += 8) {
            int d = base + (lane >> 3);
            if (d < deg) {
                int2 pa = bkt[beg + d];
                int pk = pa.x;
                float ae = __int_as_float(pa.y);
                int s = pk >> 2, t = pk & 3;
                if (h == 0) spk[d] = pk;
                float a = qdn[t * 8 + h] + kdot[s * 24 + t * 8 + h] + ae * weeh;
                sal[d * 8 + h] = (a > 0.f) ? a : NEG * a;
            }
        }
    }
    // phase 2: per-head softmax; lane = chunk*8 + head
    float sinv_h;
    {
        int h = lane & 7, c = lane >> 3;
        float m = -INFINITY;
        for (int d = c; d < deg; d += 8) m = fmaxf(m, sal[d * 8 + h]);
        m = fmaxf(m, __shfl_xor(m, 8, 64));
        m = fmaxf(m, __shfl_xor(m, 16, 64));
        m = fmaxf(m, __shfl_xor(m, 32, 64));
        float s = 0.f;
        for (int d = c; d < deg; d += 8) {
            float ex = expf(sal[d * 8 + h] - m);
            sal[d * 8 + h] = ex;
            s += ex;
        }
        s += __shfl_xor(s, 8, 64);
        s += __shfl_xor(s, 16, 64);
        s += __shfl_xor(s, 32, 64);
        sinv_h = 1.f / (s + 1e-16f);
    }
    float sinv_sel = __shfl(sinv_h, lane >> 3, 64);
    int hsel = lane >> 3;
    // phase 3: full-row wave gather, unroll x4 (4 outstanding 1KB loads)
    float4 acc4 = make_float4(0.f, 0.f, 0.f, 0.f);
    int d = 0;
    for (; d + 3 < deg; d += 4) {
        int pk0 = spk[d], pk1 = spk[d + 1], pk2 = spk[d + 2], pk3 = spk[d + 3];
        const float4* r0 = (const float4*)(xw + ((size_t)(pk0 >> 2) * NREL + (pk0 & 3)) * HC);
        const float4* r1 = (const float4*)(xw + ((size_t)(pk1 >> 2) * NREL + (pk1 & 3)) * HC);
        const float4* r2 = (const float4*)(xw + ((size_t)(pk2 >> 2) * NREL + (pk2 & 3)) * HC);
        const float4* r3 = (const float4*)(xw + ((size_t)(pk3 >> 2) * NREL + (pk3 & 3)) * HC);
        float4 v0 = r0[lane], v1 = r1[lane], v2 = r2[lane], v3 = r3[lane];
        float a0 = sal[d * 8 + hsel];
        float a1 = sal[(d + 1) * 8 + hsel];
        float a2 = sal[(d + 2) * 8 + hsel];
        float a3 = sal[(d + 3) * 8 + hsel];
        acc4.x += a0 * v0.x + a1 * v1.x + a2 * v2.x + a3 * v3.x;
        acc4.y += a0 * v0.y + a1 * v1.y + a2 * v2.y + a3 * v3.y;
        acc4.z += a0 * v0.z + a1 * v1.z + a2 * v2.z + a3 * v3.z;
        acc4.w += a0 * v0.w + a1 * v1.w + a2 * v2.w + a3 * v3.w;
    }
    for (; d < deg; ++d) {
        int pk = spk[d];
        const float4* r0 = (const float4*)(xw + ((size_t)(pk >> 2) * NREL + (pk & 3)) * HC);
        float4 v0 = r0[lane];
        float a0 = sal[d * 8 + hsel];
        acc4.x += a0 * v0.x;
        acc4.y += a0 * v0.y;
        acc4.z += a0 * v0.z;
        acc4.w += a0 * v0.w;
    }
    // epilogue: cols c = 4*lane .. 4*lane+3
    float4 bv = *(const float4*)(bias + lane * 4);
    float4 v;
    v.x = fmaxf(acc4.x * sinv_sel + bv.x, 0.f);
    v.y = fmaxf(acc4.y * sinv_sel + bv.y, 0.f);
    v.z = fmaxf(acc4.z * sinv_sel + bv.z, 0.f);
    v.w = fmaxf(acc4.w * sinv_sel + bv.w, 0.f);
    if (hout) *(float4*)(hout + (size_t)n * HC + lane * 4) = v;
    if (houthi) {
        // packed split-bf16 A write for next layer (K=256 -> KB=8)
        int ntile = n >> 4, mm = n & 15;
        float vv[4] = {v.x, v.y, v.z, v.w};
#pragma unroll
        for (int i = 0; i < 4; ++i) {
            int c = lane * 4 + i;
            int kb = c >> 5, q = (c >> 3) & 3, j = c & 7;
            size_t o2 = ((((size_t)ntile * 8 + kb) * 64) + q * 16 + mm) * 8 + j;
            unsigned short hh = f2bf(vv[i]);
            houthi[o2] = hh;
            houtlo[o2] = f2bf(vv[i] - bf2f(hh));
        }
    }
}

// ---- final linear + tanh + mean-pool + last-block divide -------------------
__global__ __launch_bounds__(256) void k_pool2(const float* __restrict__ h3,
                                               const float* __restrict__ wlin,
                                               const float* __restrict__ blin,
                                               const int* __restrict__ batch,
                                               float* __restrict__ partials,
                                               int* __restrict__ gcnt, int* __restrict__ ctr,
                                               float* __restrict__ out, int nnodes, int ngraph) {
    int g = blockIdx.x / PCHUNK, chunk = blockIdx.x % PCHUNK;
    __shared__ int sb[2];
    if (threadIdx.x < 2) {
        int target = g + threadIdx.x;
        int lo = 0, hi = nnodes;
        while (lo < hi) { int mid = (lo + hi) >> 1; if (batch[mid] < target) lo = mid + 1; else hi = mid; }
        sb[threadIdx.x] = lo;
    }
    __syncthreads();
    int beg = sb[0], end = sb[1];
    int t = threadIdx.x;
    int w = t >> 6, lane = t & 63;
    int h = lane & 7, grp = lane >> 3;
    float rw[32];
#pragma unroll
    for (int k = 0; k < 8; ++k)
#pragma unroll
        for (int j = 0; j < 4; ++j)
            rw[k * 4 + j] = wlin[(grp * 4 + j + 32 * k) * HEADS + h];
    float bl = blin[h];
    float acc = 0.f;
    int wg = chunk * 4 + w;   // 0..31
    for (int n = beg + wg; n < end; n += PCHUNK * 4) {
        const float* row = h3 + (size_t)n * HC;
        float dot = 0.f;
#pragma unroll
        for (int k = 0; k < 8; ++k) {
            float4 v = *(const float4*)&row[grp * 4 + 32 * k];
            dot += v.x * rw[k * 4] + v.y * rw[k * 4 + 1] + v.z * rw[k * 4 + 2] + v.w * rw[k * 4 + 3];
        }
        dot += __shfl_xor(dot, 8, 64);
        dot += __shfl_xor(dot, 16, 64);
        dot += __shfl_xor(dot, 32, 64);
        acc += tanhf(dot + bl);
    }
    __shared__ float sacc[4][HEADS];
    __shared__ float sred[HEADS];
    __shared__ int slast;
    if (lane < HEADS) sacc[w][h] = acc;
    __syncthreads();
    if (t < HEADS) sred[t] = sacc[0][t] + sacc[1][t] + sacc[2][t] + sacc[3][t];
    __syncthreads();
    if (t == 0) {
        for (int hh = 0; hh < HEADS; ++hh)
            partials[(size_t)blockIdx.x * HEADS + hh] = sred[hh];
        if (chunk == 0) gcnt[g] = end - beg;
        __threadfence();
        slast = (atomicAdd(ctr, 1) == (int)gridDim.x - 1);
    }
    __syncthreads();
    if (slast) {
        __threadfence();
        if (t < ngraph * HEADS) {
            int gg = t >> 3, hh = t & 7;
            float s = 0.f;
            for (int c = 0; c < PCHUNK; ++c)
                s += partials[(size_t)(gg * PCHUNK + c) * HEADS + hh];
            out[t] = s / fmaxf((float)gcnt[gg], 1.f);
        }
    }
}

// ---------------------------------------------------------------------------

extern "C" void kernel_launch(void* const* d_in, const int* in_sizes, int n_in,
                              void* d_out, int out_size, void* d_ws, size_t ws_size,
                              hipStream_t stream) {
    const float* x    = (const float*)d_in[0];
    const int*   ei   = (const int*)d_in[1];
    const int*   et   = (const int*)d_in[2];
    const float* ea   = (const float*)d_in[3];
    const int*   batch = (const int*)d_in[4];
    const float* W[3]  = {(const float*)d_in[5],  (const float*)d_in[11], (const float*)d_in[17]};
    const float* Q[3]  = {(const float*)d_in[6],  (const float*)d_in[12], (const float*)d_in[18]};
    const float* K[3]  = {(const float*)d_in[7],  (const float*)d_in[13], (const float*)d_in[19]};
    const float* Em[3] = {(const float*)d_in[8],  (const float*)d_in[14], (const float*)d_in[20]};
    const float* WE[3] = {(const float*)d_in[9],  (const float*)d_in[15], (const float*)d_in[21]};
    const float* B[3]  = {(const float*)d_in[10], (const float*)d_in[16], (const float*)d_in[22]};
    const float* wlin = (const float*)d_in[23];
    const float* blin = (const float*)d_in[24];

    int nnodes = in_sizes[0] / 32;
    int nedges = in_sizes[2];
    int ngraph = 16;
    int npad = (nnodes + 15) & ~15;
    int ntiles = npad / 16;

    char* ws = (char*)d_ws;
    size_t off = 0;
    auto alloc = [&](size_t bytes) -> void* {
        void* p = ws + off;
        off = (off + bytes + 255) & ~(size_t)255;
        return p;
    };
    // fill[nnodes] + ctr share one zeroed region (single memsetAsync)
    int*   fill     = (int*)alloc((size_t)(nnodes + 64) * 4);
    int*   ctr      = fill + nnodes;
    int2*  bkt      = (int2*)alloc((size_t)nnodes * MAXDEG * 8);
    float* xw       = (float*)alloc((size_t)npad * NREL * HC * 4);
    float* qdot     = (float*)alloc((size_t)npad * NREL * HEADS * 4);
    float* kdot     = (float*)alloc((size_t)npad * NREL * HEADS * 4);
    float* ha       = (float*)alloc((size_t)nnodes * HC * 4);
    float* wee      = (float*)alloc((size_t)NREL * HEADS * 4);
    float* partials = (float*)alloc((size_t)ngraph * PCHUNK * HEADS * 4);
    int*   gcnt     = (int*)alloc((size_t)ngraph * 4);
    unsigned short* x1hi = (unsigned short*)alloc((size_t)npad * 32 * 2);
    unsigned short* x1lo = (unsigned short*)alloc((size_t)npad * 32 * 2);
    unsigned short* hahi = (unsigned short*)alloc((size_t)npad * HC * 2);
    unsigned short* halo = (unsigned short*)alloc((size_t)npad * HC * 2);
    unsigned short* hbhi = (unsigned short*)alloc((size_t)npad * HC * 2);
    unsigned short* hblo = (unsigned short*)alloc((size_t)npad * HC * 2);
    unsigned short* wt1hi = (unsigned short*)alloc((size_t)NREL * NCT * 1 * 512 * 2);
    unsigned short* wt1lo = (unsigned short*)alloc((size_t)NREL * NCT * 1 * 512 * 2);
    unsigned short* wt2hi = (unsigned short*)alloc((size_t)NREL * NCT * 8 * 512 * 2);
    unsigned short* wt2lo = (unsigned short*)alloc((size_t)NREL * NCT * 8 * 512 * 2);
    unsigned short* wt3hi = (unsigned short*)alloc((size_t)NREL * NCT * 8 * 512 * 2);
    unsigned short* wt3lo = (unsigned short*)alloc((size_t)NREL * NCT * 8 * 512 * 2);
    (void)ws_size; (void)n_in; (void)out_size;

    int nwcv = NREL * (1 + 8 + 8);                    // 51 vectorized W tile-blocks
    int nprep = NREL * 32 + 2 * NREL * HC;            // 1632 qk-dot rows
    int npacka = (nnodes * 32 + 255) / 256;           // x-pack blocks
    int nscat = (nedges + 255) / 256;                 // edge-scatter blocks

    // zero fill+ctr, then one fused prep dispatch
    hipMemsetAsync(fill, 0, (size_t)(nnodes + 64) * 4, stream);
    k_wprep<<<nwcv + nprep + npacka + nscat, 256, 0, stream>>>(
        W[0], Q[0], K[0], Em[0], WE[0],
        W[1], Q[1], K[1], Em[1], WE[1],
        W[2], Q[2], K[2], Em[2], WE[2],
        wt1hi, wt1lo, wt2hi, wt2lo, wt3hi, wt3lo, wee,
        x, x1hi, x1lo,
        ei, et, ea, fill, bkt,
        nnodes, nedges, nwcv, nprep, npacka);

    dim3 gmfma((ntiles + 1) / 2, NREL);        // NT=2 everywhere
    int gagg = (nnodes + 3) / 4;

    // ---- layer 1 (IN=32): x -> (packed ha) ----
    k_mfma<32, 2><<<gmfma, 256, 0, stream>>>(x1hi, x1lo, wt1hi, wt1lo, xw, qdot, kdot, nnodes, ntiles);
    k_agg<<<gagg, 256, 0, stream>>>(xw, qdot, kdot, fill, bkt, wee + 0, B[0],
                                    nullptr, hahi, halo, nnodes);

    // ---- layer 2 (IN=256): (packed ha) -> (packed hb) ----
    k_mfma<HC, 2><<<gmfma, 256, 0, stream>>>(hahi, halo, wt2hi, wt2lo, xw, qdot, kdot, nnodes, ntiles);
    k_agg<<<gagg, 256, 0, stream>>>(xw, qdot, kdot, fill, bkt, wee + 8, B[1],
                                    nullptr, hbhi, hblo, nnodes);

    // ---- layer 3 (IN=256): (packed hb) -> ha (fp32 only, for pool) ----
    k_mfma<HC, 2><<<gmfma, 256, 0, stream>>>(hbhi, hblo, wt3hi, wt3lo, xw, qdot, kdot, nnodes, ntiles);
    k_agg<<<gagg, 256, 0, stream>>>(xw, qdot, kdot, fill, bkt, wee + 16, B[2],
                                    ha, nullptr, nullptr, nnodes);

    // ---- head: linear + tanh + mean pool + fused divide ----
    k_pool2<<<ngraph * PCHUNK, 256, 0, stream>>>(ha, wlin, blin, batch, partials, gcnt, ctr,
                                                 (float*)d_out, nnodes, ngraph);
}